// Round 6
// baseline (800.432 us; speedup 1.0000x reference)
//
#include <hip/hip_runtime.h>
#include <cstdint>
#include <cstddef>

#define HID 128
#define OUTC 40
#define WTOT 139264  // Wl 49152 | Wr 49152 | W0 8192 | W1 16384 | W2 16384
#define PB 200       // blocks for edge-binning passes
#define NBK_MAX 256  // max buckets (512 nodes each)

typedef __attribute__((ext_vector_type(8))) short short8;
typedef __attribute__((ext_vector_type(4))) float floatx4;

__device__ __forceinline__ unsigned short f2b(float f) {
  unsigned int u = __float_as_uint(f);
  unsigned int r = u + 0x7FFFu + ((u >> 16) & 1u);
  return (unsigned short)(r >> 16);
}
__device__ __forceinline__ float blo(unsigned int u) { return __uint_as_float(u << 16); }
__device__ __forceinline__ float bhi(unsigned int u) { return __uint_as_float(u & 0xFFFF0000u); }
__device__ __forceinline__ unsigned int pack2(float a, float b) {
  return (unsigned int)f2b(a) | ((unsigned int)f2b(b) << 16);
}

__device__ __forceinline__ void async_cp16(const ushort* g, ushort* l) {
  __builtin_amdgcn_global_load_lds((const __attribute__((address_space(1))) void*)g,
                                   (__attribute__((address_space(3))) void*)l, 16, 0, 0);
}

// ================= device bodies =================

__device__ __forceinline__ void cvt_body(int bid, const float* __restrict__ in,
                                         ushort* __restrict__ out, int n4) {
  int i = bid * 256 + threadIdx.x;
  if (i >= n4) return;
  float4 v = ((const float4*)in)[i];
  ushort4 o;
  o.x = f2b(v.x); o.y = f2b(v.y); o.z = f2b(v.z); o.w = f2b(v.w);
  ((ushort4*)out)[i] = o;
}

__device__ __forceinline__ void cvtw_body(int bid, const float* __restrict__ Wl,
                                          const float* __restrict__ Wr, const float* __restrict__ W0,
                                          const float* __restrict__ W1, const float* __restrict__ W2,
                                          const float* __restrict__ Wc, ushort* __restrict__ wb,
                                          ushort* __restrict__ wcb, float* __restrict__ stats) {
  int gid = bid * 256 + threadIdx.x;
  if (gid < 8192) stats[gid] = 0.0f;  // 4 sets x 8 replicas x 256
  if (gid < 48 * 64) {  // wcb: 48x256 bf16, rows 40..47 zero
    int row = gid >> 6;
    ushort4 o;
    if (row < 40) {
      float4 v = *(const float4*)(Wc + (size_t)gid * 4);
      o.x = f2b(v.x); o.y = f2b(v.y); o.z = f2b(v.z); o.w = f2b(v.w);
    } else {
      o.x = 0; o.y = 0; o.z = 0; o.w = 0;
    }
    ((ushort4*)wcb)[gid] = o;
  }
  int e4 = gid * 4;
  if (e4 < WTOT) {
    const float* s; int off;
    if (e4 < 49152)       { s = Wl; off = 0; }
    else if (e4 < 98304)  { s = Wr; off = 49152; }
    else if (e4 < 106496) { s = W0; off = 98304; }
    else if (e4 < 122880) { s = W1; off = 106496; }
    else                  { s = W2; off = 122880; }
    float4 v = *(const float4*)(s + (e4 - off));
    ushort4 o;
    o.x = f2b(v.x); o.y = f2b(v.y); o.z = f2b(v.z); o.w = f2b(v.w);
    *(ushort4*)(wb + e4) = o;
  }
}

__device__ __forceinline__ void anorm2_body(int bid, const float* __restrict__ alpha,
                                            ushort* __restrict__ ab, ushort* __restrict__ anb,
                                            int n) {
  int g = (bid * 256 + threadIdx.x) >> 4;  // 16 lanes/node
  int lane = threadIdx.x & 15;
  if (g >= n) return;
  const float4 a = *(const float4*)(alpha + (size_t)g * 64 + lane * 4);
  ushort4 raw;
  raw.x = f2b(a.x); raw.y = f2b(a.y); raw.z = f2b(a.z); raw.w = f2b(a.w);
  *(ushort4*)(ab + (size_t)g * 64 + lane * 4) = raw;
  float d = a.x * a.x + a.y * a.y + a.z * a.z + a.w * a.w;
  d += __shfl_xor(d, 1); d += __shfl_xor(d, 2);
  d += __shfl_xor(d, 4); d += __shfl_xor(d, 8);
  float r = 1.0f / fmaxf(sqrtf(d), 1e-12f);
  ushort4 o;
  o.x = f2b(a.x * r); o.y = f2b(a.y * r); o.z = f2b(a.z * r); o.w = f2b(a.w * r);
  *(ushort4*)(anb + (size_t)g * 64 + lane * 4) = o;
}

__device__ __forceinline__ void binA_body(int bid, const int* __restrict__ tgt,
                                          int* __restrict__ G, int e, int chunk, int nbk) {
  __shared__ int hist[NBK_MAX];
  int tid = threadIdx.x;
  for (int b = tid; b < nbk; b += 256) hist[b] = 0;
  __syncthreads();
  int i0 = bid * chunk;
  int i1 = min(e, i0 + chunk);
  for (int j = i0 + tid; j < i1; j += 256) atomicAdd(&hist[tgt[j] >> 9], 1);
  __syncthreads();
  for (int b = tid; b < nbk; b += 256) G[b * PB + bid] = hist[b];
}

// ---- fused layer-0 aggregate + gate (1 wave / node, 8 neighbors / iter) ----
__device__ __forceinline__ void agg_gate_body(int bid, const ushort* __restrict__ h,
                                              const ushort* __restrict__ anb,
                                              const int* __restrict__ rowptr,
                                              const int* __restrict__ csr,
                                              const float* __restrict__ temp,
                                              float* __restrict__ gout,
                                              ushort* __restrict__ outb, int n) {
  int g = bid * 4 + (threadIdx.x >> 6);  // 1 wave per node
  if (g >= n) return;
  const int l = threadIdx.x & 63;
  const int js = l >> 4;   // neighbor slot 0..3
  const int c = l & 15;    // 16B chunk of the 256B h row / 8B chunk of anb row
  int beg = rowptr[g], end = rowptr[g + 1];
  int deg = end - beg;
  uint2 av = *(const uint2*)(anb + (size_t)g * 64 + c * 4);
  float av0 = blo(av.x), av1 = bhi(av.x), av2 = blo(av.y), av3 = bhi(av.y);
  float a0=0,a1=0,a2=0,a3=0,a4=0,a5=0,a6=0,a7=0;
  float dot = 0.f;
  int j = beg;
  int jend = beg + (deg & ~7);
  for (; j < jend; j += 8) {
    int u0 = csr[j + js];
    int u1 = csr[j + js + 4];
    uint4 v0 = *(const uint4*)(h + (size_t)u0 * HID + c * 8);
    uint4 v1 = *(const uint4*)(h + (size_t)u1 * HID + c * 8);
    uint2 w0 = *(const uint2*)(anb + (size_t)u0 * 64 + c * 4);
    uint2 w1 = *(const uint2*)(anb + (size_t)u1 * 64 + c * 4);
    a0 += blo(v0.x) + blo(v1.x); a1 += bhi(v0.x) + bhi(v1.x);
    a2 += blo(v0.y) + blo(v1.y); a3 += bhi(v0.y) + bhi(v1.y);
    a4 += blo(v0.z) + blo(v1.z); a5 += bhi(v0.z) + bhi(v1.z);
    a6 += blo(v0.w) + blo(v1.w); a7 += bhi(v0.w) + bhi(v1.w);
    dot += av0 * (blo(w0.x) + blo(w1.x)) + av1 * (bhi(w0.x) + bhi(w1.x))
         + av2 * (blo(w0.y) + blo(w1.y)) + av3 * (bhi(w0.y) + bhi(w1.y));
  }
  int rem = end - j;  // 0..7
  if (js < rem) {
    int u0 = csr[j + js];
    uint4 v0 = *(const uint4*)(h + (size_t)u0 * HID + c * 8);
    uint2 w0 = *(const uint2*)(anb + (size_t)u0 * 64 + c * 4);
    a0 += blo(v0.x); a1 += bhi(v0.x); a2 += blo(v0.y); a3 += bhi(v0.y);
    a4 += blo(v0.z); a5 += bhi(v0.z); a6 += blo(v0.w); a7 += bhi(v0.w);
    dot += av0 * blo(w0.x) + av1 * bhi(w0.x) + av2 * blo(w0.y) + av3 * bhi(w0.y);
  }
  if (js + 4 < rem) {
    int u0 = csr[j + js + 4];
    uint4 v0 = *(const uint4*)(h + (size_t)u0 * HID + c * 8);
    uint2 w0 = *(const uint2*)(anb + (size_t)u0 * 64 + c * 4);
    a0 += blo(v0.x); a1 += bhi(v0.x); a2 += blo(v0.y); a3 += bhi(v0.y);
    a4 += blo(v0.z); a5 += bhi(v0.z); a6 += blo(v0.w); a7 += bhi(v0.w);
    dot += av0 * blo(w0.x) + av1 * bhi(w0.x) + av2 * blo(w0.y) + av3 * bhi(w0.y);
  }
  a0 += __shfl_xor(a0, 16); a0 += __shfl_xor(a0, 32);
  a1 += __shfl_xor(a1, 16); a1 += __shfl_xor(a1, 32);
  a2 += __shfl_xor(a2, 16); a2 += __shfl_xor(a2, 32);
  a3 += __shfl_xor(a3, 16); a3 += __shfl_xor(a3, 32);
  a4 += __shfl_xor(a4, 16); a4 += __shfl_xor(a4, 32);
  a5 += __shfl_xor(a5, 16); a5 += __shfl_xor(a5, 32);
  a6 += __shfl_xor(a6, 16); a6 += __shfl_xor(a6, 32);
  a7 += __shfl_xor(a7, 16); a7 += __shfl_xor(a7, 32);
  dot += __shfl_xor(dot, 1); dot += __shfl_xor(dot, 2);
  dot += __shfl_xor(dot, 4); dot += __shfl_xor(dot, 8);
  dot += __shfl_xor(dot, 16); dot += __shfl_xor(dot, 32);
  if (l < 16) {
    float r = (deg > 0) ? 1.0f / (float)deg : 0.0f;
    uint4 o;
    o.x = pack2(a0 * r, a1 * r); o.y = pack2(a2 * r, a3 * r);
    o.z = pack2(a4 * r, a5 * r); o.w = pack2(a6 * r, a7 * r);
    *(uint4*)(outb + (size_t)g * HID + c * 8) = o;
  }
  if (l == 0) {
    float m = (1.0f + dot) / (float)(deg + 1);  // self-loop dot = 1
    gout[g] = 1.0f / (1.0f + expf(-temp[0] * m));
  }
}

// ---- SAGE mean aggregation (1 wave / node, 8 neighbors / iter) ----
__device__ __forceinline__ void agg_b_body(int bid, int goff, const ushort* __restrict__ h,
                                           const int* __restrict__ rowptr,
                                           const int* __restrict__ csr,
                                           ushort* __restrict__ outb, int n) {
  int g = goff + bid * 4 + (threadIdx.x >> 6);
  if (g >= n) return;
  const int l = threadIdx.x & 63;
  const int js = l >> 4;
  const int c = l & 15;
  int beg = rowptr[g], end = rowptr[g + 1];
  int deg = end - beg;
  float a0=0,a1=0,a2=0,a3=0,a4=0,a5=0,a6=0,a7=0;
  int j = beg;
  int jend = beg + (deg & ~7);
  for (; j < jend; j += 8) {
    int u0 = csr[j + js];
    int u1 = csr[j + js + 4];
    uint4 v0 = *(const uint4*)(h + (size_t)u0 * HID + c * 8);
    uint4 v1 = *(const uint4*)(h + (size_t)u1 * HID + c * 8);
    a0 += blo(v0.x) + blo(v1.x); a1 += bhi(v0.x) + bhi(v1.x);
    a2 += blo(v0.y) + blo(v1.y); a3 += bhi(v0.y) + bhi(v1.y);
    a4 += blo(v0.z) + blo(v1.z); a5 += bhi(v0.z) + bhi(v1.z);
    a6 += blo(v0.w) + blo(v1.w); a7 += bhi(v0.w) + bhi(v1.w);
  }
  int rem = end - j;
  if (js < rem) {
    int u0 = csr[j + js];
    uint4 v0 = *(const uint4*)(h + (size_t)u0 * HID + c * 8);
    a0 += blo(v0.x); a1 += bhi(v0.x); a2 += blo(v0.y); a3 += bhi(v0.y);
    a4 += blo(v0.z); a5 += bhi(v0.z); a6 += blo(v0.w); a7 += bhi(v0.w);
  }
  if (js + 4 < rem) {
    int u0 = csr[j + js + 4];
    uint4 v0 = *(const uint4*)(h + (size_t)u0 * HID + c * 8);
    a0 += blo(v0.x); a1 += bhi(v0.x); a2 += blo(v0.y); a3 += bhi(v0.y);
    a4 += blo(v0.z); a5 += bhi(v0.z); a6 += blo(v0.w); a7 += bhi(v0.w);
  }
  a0 += __shfl_xor(a0, 16); a0 += __shfl_xor(a0, 32);
  a1 += __shfl_xor(a1, 16); a1 += __shfl_xor(a1, 32);
  a2 += __shfl_xor(a2, 16); a2 += __shfl_xor(a2, 32);
  a3 += __shfl_xor(a3, 16); a3 += __shfl_xor(a3, 32);
  a4 += __shfl_xor(a4, 16); a4 += __shfl_xor(a4, 32);
  a5 += __shfl_xor(a5, 16); a5 += __shfl_xor(a5, 32);
  a6 += __shfl_xor(a6, 16); a6 += __shfl_xor(a6, 32);
  a7 += __shfl_xor(a7, 16); a7 += __shfl_xor(a7, 32);
  if (l < 16) {
    float r = (deg > 0) ? 1.0f / (float)deg : 0.0f;
    uint4 o;
    o.x = pack2(a0 * r, a1 * r); o.y = pack2(a2 * r, a3 * r);
    o.z = pack2(a4 * r, a5 * r); o.w = pack2(a6 * r, a7 * r);
    *(uint4*)(outb + (size_t)g * HID + c * 8) = o;
  }
}

// ---- MFMA linear body: C = A1@W1^T (+ A2@W2^T) + bias, bf16 in/out ----
// stats buffer is 8-way replicated (bid&7).
template <int NPARTS, bool STATS, bool ORELU>
__device__ __forceinline__ void mlin_body(
    int bid, const ushort* __restrict__ A1, const ushort* __restrict__ A2, int K,
    const ushort* __restrict__ W1, const ushort* __restrict__ W2,
    const float* __restrict__ bias, ushort* __restrict__ C,
    float* __restrict__ stats, int M, ushort* As, ushort* Bs) {
  const int tid = threadIdx.x;
  const int w = tid >> 6, l = tid & 63;
  const int mbase = bid * 128;
  const int lm = l & 15, lq = l >> 4;
  floatx4 acc[2][8];
#pragma unroll
  for (int mt = 0; mt < 2; ++mt)
#pragma unroll
    for (int nt = 0; nt < 8; ++nt) {
      floatx4 z = {0.f, 0.f, 0.f, 0.f};
      acc[mt][nt] = z;
    }

  for (int part = 0; part < NPARTS; ++part) {
    const ushort* Ap = part ? A2 : A1;
    const ushort* Wp = part ? W2 : W1;
    for (int k0 = 0; k0 < K; k0 += 32) {
#pragma unroll
      for (int i = 0; i < 2; ++i) {
        int s = w * 2 + i;
        int rt = s * 16 + (l >> 2);
        int q = (l & 3) ^ ((rt >> 1) & 3);
        int grow = mbase + rt; grow = grow < M ? grow : M - 1;
        async_cp16(Ap + (size_t)grow * K + k0 + q * 8, &As[s * 512]);
        async_cp16(Wp + (size_t)rt * K + k0 + q * 8, &Bs[s * 512]);
      }
      __syncthreads();
      short8 b[8];
#pragma unroll
      for (int nt = 0; nt < 8; ++nt) {
        int row = nt * 16 + lm;
        int q = lq ^ ((row >> 1) & 3);
        b[nt] = *(const short8*)&Bs[row * 32 + q * 8];
      }
#pragma unroll
      for (int mt = 0; mt < 2; ++mt) {
        int row = (w * 2 + mt) * 16 + lm;
        int q = lq ^ ((row >> 1) & 3);
        short8 a = *(const short8*)&As[row * 32 + q * 8];
#pragma unroll
        for (int nt = 0; nt < 8; ++nt)
          acc[mt][nt] = __builtin_amdgcn_mfma_f32_16x16x32_bf16(a, b[nt], acc[mt][nt], 0, 0, 0);
      }
      __syncthreads();
    }
  }

  float ss[8], qq[8];
#pragma unroll
  for (int nt = 0; nt < 8; ++nt) { ss[nt] = 0.f; qq[nt] = 0.f; }
#pragma unroll
  for (int nt = 0; nt < 8; ++nt) {
    int col = nt * 16 + lm;
    float bv = bias[col];
#pragma unroll
    for (int mt = 0; mt < 2; ++mt) {
      int rbase = mbase + (w * 2 + mt) * 16 + lq * 4;
#pragma unroll
      for (int r = 0; r < 4; ++r) {
        int grow = rbase + r;
        if (grow < M) {
          float val = acc[mt][nt][r] + bv;
          if (ORELU) val = fmaxf(val, 0.f);
          C[(size_t)grow * 128 + col] = f2b(val);
          if (STATS) { ss[nt] += val; qq[nt] += val * val; }
        }
      }
    }
  }
  if (STATS) {
    float* sred = (float*)As;
    if (tid < 256) sred[tid] = 0.f;
    __syncthreads();
#pragma unroll
    for (int nt = 0; nt < 8; ++nt) {
      ss[nt] += __shfl_xor(ss[nt], 16); ss[nt] += __shfl_xor(ss[nt], 32);
      qq[nt] += __shfl_xor(qq[nt], 16); qq[nt] += __shfl_xor(qq[nt], 32);
    }
    if (lq == 0) {
#pragma unroll
      for (int nt = 0; nt < 8; ++nt) {
        int col = nt * 16 + lm;
        atomicAdd(&sred[col], ss[nt]);
        atomicAdd(&sred[128 + col], qq[nt]);
      }
    }
    __syncthreads();
    float* sbase = stats + ((bid & 7) << 8);
    if (tid < 256) atomicAdd(&sbase[tid], sred[tid]);
  }
}

// ---- BatchNorm apply body (bf16 in-place; sums 8 stats replicas) ----
template <int ACT>  // 0=relu, 1=sigmoid
__device__ __forceinline__ void bnb_body(int bid, int gB, ushort* __restrict__ buf,
                                         const float* __restrict__ stats,
                                         const float* __restrict__ gamma,
                                         const float* __restrict__ beta, int n) {
  const int S = gB * 256;
  int idx = bid * 256 + threadIdx.x;
  const int c0 = (idx & 15) * 8;
  const float inv_n = 1.0f / (float)n;
  float sc[8], sh[8];
#pragma unroll
  for (int d = 0; d < 8; ++d) {
    int c = c0 + d;
    float s0 = 0.f, s1 = 0.f;
#pragma unroll
    for (int r2 = 0; r2 < 8; ++r2) {
      s0 += stats[(r2 << 8) + c];
      s1 += stats[(r2 << 8) + 128 + c];
    }
    float mu = s0 * inv_n;
    float var = s1 * inv_n - mu * mu;
    float s = rsqrtf(var + 1e-5f) * gamma[c];
    sc[d] = s;
    sh[d] = beta[c] - mu * s;
  }
  const int n16 = n * 16;
  for (; idx < n16; idx += S) {
    uint4 v = ((const uint4*)buf)[idx];
    float x[8] = {blo(v.x), bhi(v.x), blo(v.y), bhi(v.y),
                  blo(v.z), bhi(v.z), blo(v.w), bhi(v.w)};
#pragma unroll
    for (int d = 0; d < 8; ++d) {
      float y = x[d] * sc[d] + sh[d];
      x[d] = (ACT == 0) ? fmaxf(y, 0.f) : 1.0f / (1.0f + expf(-y));
    }
    uint4 o;
    o.x = pack2(x[0], x[1]); o.y = pack2(x[2], x[3]);
    o.z = pack2(x[4], x[5]); o.w = pack2(x[6], x[7]);
    ((uint4*)buf)[idx] = o;
  }
}

// ---- classifier body: MFMA GEMM + fused log_softmax ----
__device__ __forceinline__ void clsm_body(
    int bid, const ushort* __restrict__ A1, const ushort* __restrict__ A2,
    const ushort* __restrict__ Wcb, const float* __restrict__ bias,
    float* __restrict__ C, int M, ushort* As, ushort* Bs) {
  const int tid = threadIdx.x;
  const int w = tid >> 6, l = tid & 63;
  const int mbase = bid * 128;
  const int lm = l & 15, lq = l >> 4;
  floatx4 acc[2][3];
#pragma unroll
  for (int mt = 0; mt < 2; ++mt)
#pragma unroll
    for (int nt = 0; nt < 3; ++nt) {
      floatx4 z = {0.f, 0.f, 0.f, 0.f};
      acc[mt][nt] = z;
    }

  for (int part = 0; part < 2; ++part) {
    const ushort* Ap = part ? A2 : A1;
    for (int k0 = 0; k0 < 128; k0 += 32) {
#pragma unroll
      for (int i = 0; i < 2; ++i) {
        int s = w * 2 + i;
        int rt = s * 16 + (l >> 2);
        int q = (l & 3) ^ ((rt >> 1) & 3);
        int grow = mbase + rt; grow = grow < M ? grow : M - 1;
        async_cp16(Ap + (size_t)grow * 128 + k0 + q * 8, &As[s * 512]);
      }
      if (w < 3) {
        int rt = w * 16 + (l >> 2);
        int q = (l & 3) ^ ((rt >> 1) & 3);
        async_cp16(Wcb + (size_t)rt * 256 + part * 128 + k0 + q * 8, &Bs[w * 512]);
      }
      __syncthreads();
      short8 b[3];
#pragma unroll
      for (int nt = 0; nt < 3; ++nt) {
        int row = nt * 16 + lm;
        int q = lq ^ ((row >> 1) & 3);
        b[nt] = *(const short8*)&Bs[row * 32 + q * 8];
      }
#pragma unroll
      for (int mt = 0; mt < 2; ++mt) {
        int row = (w * 2 + mt) * 16 + lm;
        int q = lq ^ ((row >> 1) & 3);
        short8 a = *(const short8*)&As[row * 32 + q * 8];
#pragma unroll
        for (int nt = 0; nt < 3; ++nt)
          acc[mt][nt] = __builtin_amdgcn_mfma_f32_16x16x32_bf16(a, b[nt], acc[mt][nt], 0, 0, 0);
      }
      __syncthreads();
    }
  }

  float b0v = bias[lm], b1v = bias[lm + 16];
  float b2v = (lm < 8) ? bias[lm + 32] : 0.f;
#pragma unroll
  for (int mt = 0; mt < 2; ++mt) {
#pragma unroll
    for (int r = 0; r < 4; ++r) {
      int grow = mbase + (w * 2 + mt) * 16 + lq * 4 + r;
      float v0 = acc[mt][0][r] + b0v;
      float v1 = acc[mt][1][r] + b1v;
      float v2 = (lm < 8) ? acc[mt][2][r] + b2v : -3.4e38f;
      float m = fmaxf(fmaxf(v0, v1), v2);
      m = fmaxf(m, __shfl_xor(m, 1)); m = fmaxf(m, __shfl_xor(m, 2));
      m = fmaxf(m, __shfl_xor(m, 4)); m = fmaxf(m, __shfl_xor(m, 8));
      float s = expf(v0 - m) + expf(v1 - m) + ((lm < 8) ? expf(v2 - m) : 0.f);
      s += __shfl_xor(s, 1); s += __shfl_xor(s, 2);
      s += __shfl_xor(s, 4); s += __shfl_xor(s, 8);
      float ls = m + logf(s);
      if (grow < M) {
        C[(size_t)grow * OUTC + lm] = v0 - ls;
        C[(size_t)grow * OUTC + lm + 16] = v1 - ls;
        if (lm < 8) C[(size_t)grow * OUTC + lm + 32] = v2 - ls;
      }
    }
  }
}

// ================= global kernels =================

// prep (cvtw | cvt | anorm2) + binA, one launch
__global__ void prep_binA_kernel(
    const float* __restrict__ x, ushort* __restrict__ xb, int n4,
    const float* __restrict__ alpha, ushort* __restrict__ ab, ushort* __restrict__ anb, int n,
    const float* __restrict__ Wl, const float* __restrict__ Wr, const float* __restrict__ W0,
    const float* __restrict__ W1, const float* __restrict__ W2, const float* __restrict__ Wc,
    ushort* __restrict__ wb, ushort* __restrict__ wcb, float* __restrict__ stats,
    const int* __restrict__ tgt, int* __restrict__ G, int e, int chunk, int nbk,
    int GW, int GC, int GA) {
  int b = blockIdx.x;
  if (b < GW) cvtw_body(b, Wl, Wr, W0, W1, W2, Wc, wb, wcb, stats);
  else if (b < GW + GC) cvt_body(b - GW, x, xb, n4);
  else if (b < GW + GC + GA) anorm2_body(b - GW - GC, alpha, ab, anb, n);
  else binA_body(b - GW - GC - GA, tgt, G, e, chunk, nbk);
}

// ---------------- exclusive scan (for the bucket table) ----------------

#define SCAN_T 256
#define SCAN_VPT 8
#define SCAN_ELEMS 2048

__global__ void scan1_kernel(const int* __restrict__ cnt, int* __restrict__ outp,
                             int* __restrict__ blksum, int n) {
  __shared__ int sh[SCAN_T];
  int t = threadIdx.x;
  int base = blockIdx.x * SCAN_ELEMS + t * SCAN_VPT;
  int v[SCAN_VPT];
  int s = 0;
#pragma unroll
  for (int i = 0; i < SCAN_VPT; ++i) {
    int idx = base + i;
    v[i] = (idx < n) ? cnt[idx] : 0;
    s += v[i];
  }
  sh[t] = s;
  __syncthreads();
  for (int d = 1; d < SCAN_T; d <<= 1) {
    int add = (t >= d) ? sh[t - d] : 0;
    __syncthreads();
    sh[t] += add;
    __syncthreads();
  }
  int p = sh[t] - s;
#pragma unroll
  for (int i = 0; i < SCAN_VPT; ++i) {
    int idx = base + i;
    if (idx < n) outp[idx] = p;
    p += v[i];
  }
  if (t == SCAN_T - 1) blksum[blockIdx.x] = sh[t];
}

__global__ void scan2_kernel(int* __restrict__ blk, int nb) {
  __shared__ int sh[SCAN_T];
  int t = threadIdx.x;
  int s = (t < nb) ? blk[t] : 0;
  sh[t] = s;
  __syncthreads();
  for (int d = 1; d < SCAN_T; d <<= 1) {
    int add = (t >= d) ? sh[t - d] : 0;
    __syncthreads();
    sh[t] += add;
    __syncthreads();
  }
  if (t < nb) blk[t] = sh[t] - s;
}

// ---------------- bucketed CSR build (no global atomics) ----------------
// Gs holds the per-(bucket,block) exclusive scan WITHOUT the cross-scan-block
// offset; consumers add blkoff[i >> 11] (SCAN_ELEMS = 2048) on the fly.

__global__ void binB_kernel(const int* __restrict__ src, const int* __restrict__ tgt,
                            const int* __restrict__ Gs, const int* __restrict__ blkoff,
                            int* __restrict__ ebuf, int e, int chunk, int nbk) {
  __shared__ int cur[NBK_MAX];
  int tid = threadIdx.x;
  for (int b = tid; b < nbk; b += 256) {
    int i = b * PB + blockIdx.x;
    cur[b] = Gs[i] + blkoff[i >> 11];
  }
  __syncthreads();
  int i0 = blockIdx.x * chunk;
  int i1 = min(e, i0 + chunk);
  for (int j = i0 + tid; j < i1; j += 256) {
    int t = tgt[j];
    int pos = atomicAdd(&cur[t >> 9], 1);
    ebuf[pos] = ((t & 511) << 17) | src[j];
  }
}

__global__ void binC_kernel(const int* __restrict__ ebuf, const int* __restrict__ Gs,
                            const int* __restrict__ blkoff,
                            int* __restrict__ rowptr, int* __restrict__ csr,
                            int n, int e, int nbk) {
  __shared__ int hist[512];
  __shared__ int scanbuf[256];
  int b = blockIdx.x, tid = threadIdx.x;
  int i0 = b * PB;
  int seg0 = Gs[i0] + blkoff[i0 >> 11];
  int seg1;
  if (b + 1 < nbk) {
    int i1 = (b + 1) * PB;
    seg1 = Gs[i1] + blkoff[i1 >> 11];
  } else {
    seg1 = e;
  }
  hist[tid] = 0; hist[tid + 256] = 0;
  __syncthreads();
  for (int j = seg0 + tid; j < seg1; j += 256)
    atomicAdd(&hist[ebuf[j] >> 17], 1);
  __syncthreads();
  int a0 = hist[2 * tid], a1 = hist[2 * tid + 1];
  int s = a0 + a1;
  scanbuf[tid] = s;
  __syncthreads();
  for (int d = 1; d < 256; d <<= 1) {
    int add = (tid >= d) ? scanbuf[tid - d] : 0;
    __syncthreads();
    scanbuf[tid] += add;
    __syncthreads();
  }
  int ex = scanbuf[tid] - s;
  hist[2 * tid] = ex;
  hist[2 * tid + 1] = ex + a0;
  int node0 = b * 512 + 2 * tid;
  if (node0 < n) rowptr[node0] = seg0 + ex;
  if (node0 + 1 < n) rowptr[node0 + 1] = seg0 + ex + a0;
  __syncthreads();
  for (int j = seg0 + tid; j < seg1; j += 256) {
    int val = ebuf[j];
    int pos = atomicAdd(&hist[val >> 17], 1);
    csr[seg0 + pos] = val & 0x1FFFF;
  }
  if (b == nbk - 1 && tid == 0) rowptr[n] = e;
}

// ---------------- combined launches (agg FIRST, small role trailing) ----------

// agg_gate (blocks [0,gAgg)) || proto W0 GEMM (trailing)
__global__ __launch_bounds__(256) void k_agg1_w0(
    const ushort* __restrict__ xb, const ushort* __restrict__ anb,
    const int* __restrict__ rowptr, const int* __restrict__ csr,
    const float* __restrict__ temp, float* __restrict__ gout, ushort* __restrict__ aggout,
    const ushort* __restrict__ ab, const ushort* __restrict__ W0b,
    const float* __restrict__ b0, ushort* __restrict__ hproto, float* __restrict__ stats,
    int n, int gAgg) {
  __shared__ ushort As[4096];
  __shared__ ushort Bs[4096];
  if ((int)blockIdx.x < gAgg)
    agg_gate_body(blockIdx.x, xb, anb, rowptr, csr, temp, gout, aggout, n);
  else
    mlin_body<1, true, false>(blockIdx.x - gAgg, ab, nullptr, 64, W0b, nullptr, b0,
                              hproto, stats, n, As, Bs);
}

// agg_b (blocks [0,gAgg)) || bnb (trailing)
template <int ACT>
__global__ __launch_bounds__(256) void k_agg_bnb(
    const ushort* __restrict__ h, const int* __restrict__ rowptr,
    const int* __restrict__ csr, ushort* __restrict__ outb, int n, int gAgg,
    ushort* __restrict__ bnbuf, const float* __restrict__ bnstats,
    const float* __restrict__ gamma, const float* __restrict__ beta, int gBn) {
  if ((int)blockIdx.x < gAgg)
    agg_b_body(blockIdx.x, 0, h, rowptr, csr, outb, n);
  else
    bnb_body<ACT>(blockIdx.x - gAgg, gBn, bnbuf, bnstats, gamma, beta, n);
}

// agg_b chunk B (blocks [0,nAgg), node offset goff) || SAGE GEMM2 rows-half1
__global__ __launch_bounds__(256) void k_agg3b_mlin(
    const ushort* __restrict__ h, const int* __restrict__ rowptr,
    const int* __restrict__ csr, ushort* __restrict__ outb, int nAgg, int goff,
    const ushort* __restrict__ A1, const ushort* __restrict__ A2,
    const ushort* __restrict__ W1, const ushort* __restrict__ W2,
    const float* __restrict__ bias, ushort* __restrict__ C, int M) {
  __shared__ ushort As[4096];
  __shared__ ushort Bs[4096];
  if ((int)blockIdx.x < nAgg)
    agg_b_body(blockIdx.x, goff, h, rowptr, csr, outb, M);
  else
    mlin_body<2, false, true>(blockIdx.x - nAgg, A1, A2, 128, W1, W2, bias, C,
                              nullptr, M, As, Bs);
}

// mlin (blocks [0,gLin)) || bnb (rest)
template <int NP, bool ST, bool OR_, int ACT>
__global__ __launch_bounds__(256) void k_mlin_bnb(
    const ushort* __restrict__ A1, const ushort* __restrict__ A2, int K,
    const ushort* __restrict__ W1, const ushort* __restrict__ W2,
    const float* __restrict__ bias, ushort* __restrict__ C, float* __restrict__ stats,
    ushort* __restrict__ bnbuf, const float* __restrict__ bnstats,
    const float* __restrict__ gamma, const float* __restrict__ beta,
    int M, int gLin, int gBn) {
  __shared__ ushort As[4096];
  __shared__ ushort Bs[4096];
  if ((int)blockIdx.x < gLin)
    mlin_body<NP, ST, OR_>(blockIdx.x, A1, A2, K, W1, W2, bias, C, stats, M, As, Bs);
  else
    bnb_body<ACT>(blockIdx.x - gLin, gBn, bnbuf, bnstats, gamma, beta, M);
}

// SAGE mlin (blocks [0,gLin)) || proto mlin (rest)
__global__ __launch_bounds__(256) void k_mlin_mlin(
    const ushort* __restrict__ A1a, const ushort* __restrict__ A2a,
    const ushort* __restrict__ W1a, const ushort* __restrict__ W2a,
    const float* __restrict__ ba, ushort* __restrict__ Ca, float* __restrict__ statsa,
    const ushort* __restrict__ A1b, const ushort* __restrict__ W1b,
    const float* __restrict__ bb, ushort* __restrict__ Cb, int M, int gLin) {
  __shared__ ushort As[4096];
  __shared__ ushort Bs[4096];
  if ((int)blockIdx.x < gLin)
    mlin_body<2, true, false>(blockIdx.x, A1a, A2a, 128, W1a, W2a, ba, Ca, statsa, M, As, Bs);
  else
    mlin_body<1, false, true>(blockIdx.x - gLin, A1b, nullptr, 128, W1b, nullptr, bb, Cb,
                              nullptr, M, As, Bs);
}

// SAGE GEMM2 rows-half2 (blocks [0,nM), rows offset moff) || clsm rows-half1 (rest)
__global__ __launch_bounds__(256) void k_mlin_clsm(
    const ushort* __restrict__ A1, const ushort* __restrict__ A2,
    const ushort* __restrict__ W1, const ushort* __restrict__ W2,
    const float* __restrict__ bias, ushort* __restrict__ C, int moff, int nM,
    const ushort* __restrict__ cA1, const ushort* __restrict__ cA2,
    const ushort* __restrict__ Wcb, const float* __restrict__ cbias,
    float* __restrict__ Cout, int M) {
  __shared__ ushort As[4096];
  __shared__ ushort Bs[4096];
  if ((int)blockIdx.x < nM)
    mlin_body<2, false, true>(blockIdx.x + moff, A1, A2, 128, W1, W2, bias, C,
                              nullptr, M, As, Bs);
  else
    clsm_body(blockIdx.x - nM, cA1, cA2, Wcb, cbias, Cout, M, As, Bs);
}

// ---------------- standalone kernels ----------------

__global__ void agg_b_kernel(const ushort* __restrict__ h, const int* __restrict__ rowptr,
                             const int* __restrict__ csr, ushort* __restrict__ outb,
                             int goff, int n) {
  agg_b_body(blockIdx.x, goff, h, rowptr, csr, outb, n);
}

template <int ACT>
__global__ __launch_bounds__(256) void bnb_kernel(
    ushort* __restrict__ buf, const float* __restrict__ stats,
    const float* __restrict__ gamma, const float* __restrict__ beta, int n) {
  bnb_body<ACT>(blockIdx.x, gridDim.x, buf, stats, gamma, beta, n);
}

__global__ __launch_bounds__(256) void clsm_kernel(
    const ushort* __restrict__ A1, const ushort* __restrict__ A2,
    const ushort* __restrict__ Wcb, const float* __restrict__ bias,
    float* __restrict__ C, int M, int boff) {
  __shared__ ushort As[4096];
  __shared__ ushort Bs[4096];
  clsm_body(blockIdx.x + boff, A1, A2, Wcb, bias, C, M, As, Bs);
}

// ---------------- launch ----------------

extern "C" void kernel_launch(void* const* d_in, const int* in_sizes, int n_in,
                              void* d_out, int out_size, void* d_ws, size_t ws_size,
                              hipStream_t stream) {
  const float* x       = (const float*)d_in[0];
  const float* alpha   = (const float*)d_in[1];
  const int*   eidx    = (const int*)d_in[2];
  const float* sage_Wl = (const float*)d_in[3];
  const float* sage_bl = (const float*)d_in[4];
  const float* sage_Wr = (const float*)d_in[5];
  const float* sage_g  = (const float*)d_in[6];
  const float* sage_b  = (const float*)d_in[7];
  const float* W0 = (const float*)d_in[8];
  const float* b0 = (const float*)d_in[9];
  const float* W1 = (const float*)d_in[10];
  const float* b1 = (const float*)d_in[11];
  const float* W2 = (const float*)d_in[12];
  const float* b2 = (const float*)d_in[13];
  const float* mg = (const float*)d_in[14];
  const float* mb = (const float*)d_in[15];
  const float* Wc = (const float*)d_in[16];
  const float* bc = (const float*)d_in[17];
  const float* temp = (const float*)d_in[18];
  float* out = (float*)d_out;

  const int n = in_sizes[0] / HID;  // 100000
  const int e = in_sizes[2] / 2;    // 1600000
  const int* src = eidx;
  const int* tgt = eidx + e;

  const int nbk = (n + 511) >> 9;
  const int glen = nbk * PB;
  const int chunk = (e + PB - 1) / PB;

  // workspace layout: 4 N×128 bf16 regions (16B aligned)
  char* p = (char*)d_ws;
  ushort* B0 = (ushort*)p; p += (size_t)n * HID * 2;
  ushort* B1 = (ushort*)p; p += (size_t)n * HID * 2;
  ushort* B2 = (ushort*)p; p += (size_t)n * HID * 2;
  ushort* B3 = (ushort*)p; p += (size_t)n * HID * 2;
  ushort* wb     = (ushort*)p; p += (size_t)WTOT * 2;
  ushort* wcb    = (ushort*)p; p += (size_t)48 * 256 * 2;
  float* stats = (float*)p; p += 8192 * 4;  // 4 sets x 8 replicas x 256 floats
  int* rowptr = (int*)p; p += ((size_t)n + 1) * 4;
  int* csr    = (int*)p; p += (size_t)e * 4;
  int* G      = (int*)p; p += (size_t)glen * 4;
  int* Gs     = (int*)p; p += (size_t)glen * 4;
  int* blks   = (int*)p;
  ushort* xb   = B0;
  ushort* anb  = B1;                       // N*64
  ushort* ab   = B1 + (size_t)n * 64;      // N*64
  ushort* hgnn = B1;                       // SAGE L2 out (B1 dead by then)
  int*    ebuf = (int*)B3;                 // e*4 <= n*256
  ushort* hproto = B3;
  ushort* Wlb = wb, *Wrb = wb + 49152, *W0b = wb + 98304, *W1b = wb + 106496, *W2b = wb + 122880;
  // stats sets (each 2048 floats: 8 replicas x 256)
  float* stSage0 = stats;
  float* stSage1 = stats + 2048;
  float* stPr0   = stats + 4096;
  float* stPr1   = stats + 6144;

  const int T = 256;
  const int nb_scan = (glen + SCAN_ELEMS - 1) / SCAN_ELEMS;

  const int gLin = (n + 127) / 128;        // 782
  const int gHalf = (gLin + 1) / 2;        // 391
  const int gLin2 = gLin - gHalf;          // 391
  const int gBn = 1024;
  const int gAgg = (n + 3) >> 2;           // 25000 (1 wave/node, 4/block)
  const int aggA_nodes = (gHalf * 128 < n) ? gHalf * 128 : n;   // 50048
  const int gAggA = (aggA_nodes + 3) >> 2;
  const int gAggB = (n - aggA_nodes + 3) >> 2;
  const int GW = WTOT / 4 / T;             // 136 blocks (exact)
  const int GC = (n * (HID / 4) + T - 1) / T;          // cvt blocks
  const int GA = (int)(((size_t)n * 16 + T - 1) / T);  // anorm2 blocks

  // 1: prep (weights cvt + x cvt + alpha norm) || binA
  prep_binA_kernel<<<GW + GC + GA + PB, T, 0, stream>>>(
      x, xb, n * (HID / 4), alpha, ab, anb, n,
      sage_Wl, sage_Wr, W0, W1, W2, Wc, wb, wcb, stats,
      tgt, G, e, chunk, nbk, GW, GC, GA);

  // 2-5: CSR build
  scan1_kernel<<<nb_scan, SCAN_T, 0, stream>>>(G, Gs, blks, glen);
  scan2_kernel<<<1, SCAN_T, 0, stream>>>(blks, nb_scan);
  binB_kernel<<<PB, T, 0, stream>>>(src, tgt, Gs, blks, ebuf, e, chunk, nbk);
  binC_kernel<<<nbk, T, 0, stream>>>(ebuf, Gs, blks, rowptr, csr, n, e, nbk);

  // 6: L0 aggregate + gate (agg first) || proto W0 GEMM (trailing)
  k_agg1_w0<<<gAgg + gLin, T, 0, stream>>>(xb, anb, rowptr, csr, temp,
                                           out + (size_t)n * OUTC, B2,
                                           ab, W0b, b0, hproto, stPr0, n, gAgg);

  // 7: SAGE L0 GEMM || proto BN0 (sigmoid)
  k_mlin_bnb<2, true, false, 1><<<gLin + gBn, T, 0, stream>>>(
      B2, B0, 128, Wlb, Wrb, sage_bl, B1, stSage0,
      hproto, stPr0, mg, mb, n, gLin, gBn);

  // 8: proto W1 GEMM || SAGE BN0 (relu)
  k_mlin_bnb<1, true, false, 0><<<gLin + gBn, T, 0, stream>>>(
      hproto, nullptr, 128, W1b, nullptr, b1, hproto, stPr1,
      B1, stSage0, sage_g, sage_b, n, gLin, gBn);

  // 9: SAGE L1 aggregate (agg first) || proto BN1 sigmoid (trailing)
  k_agg_bnb<1><<<gAgg + gBn, T, 0, stream>>>(B1, rowptr, csr, B2, n, gAgg,
                                             hproto, stPr1, mg + HID, mb + HID, gBn);

  // 10: SAGE L1 GEMM || proto W2 GEMM (relu fused)
  k_mlin_mlin<<<2 * gLin, T, 0, stream>>>(B2, B1, Wlb + 16384, Wrb + 16384,
                                          sage_bl + HID, B0, stSage1,
                                          hproto, W2b, b2, hproto, n, gLin);

  // 11: SAGE BN1 (relu)
  bnb_kernel<0><<<gBn, T, 0, stream>>>(B0, stSage1, sage_g + HID, sage_b + HID, n);

  // 12: SAGE L2 aggregate, chunk A (rows for GEMM2-half1)
  agg_b_kernel<<<gAggA, T, 0, stream>>>(B0, rowptr, csr, B2, 0, aggA_nodes);

  // 13: L2 aggregate chunk B (agg first) || SAGE GEMM2 rows-half1
  k_agg3b_mlin<<<gAggB + gHalf, T, 0, stream>>>(B0, rowptr, csr, B2, gAggB, aggA_nodes,
                                                B2, B0, Wlb + 32768, Wrb + 32768,
                                                sage_bl + 2 * HID, hgnn, n);

  // 14: SAGE GEMM2 rows-half2 || classifier rows-half1
  k_mlin_clsm<<<gLin2 + gHalf, T, 0, stream>>>(B2, B0, Wlb + 32768, Wrb + 32768,
                                               sage_bl + 2 * HID, hgnn, gHalf, gLin2,
                                               hgnn, hproto, wcb, bc, out, n);

  // 15: classifier rows-half2
  clsm_kernel<<<gLin - gHalf, T, 0, stream>>>(hgnn, hproto, wcb, bc, out, n, gHalf);
}

// Round 8
// 683.868 us; speedup vs baseline: 1.1704x; 1.1704x over previous
//
#include <hip/hip_runtime.h>
#include <cstdint>
#include <cstddef>

#define HID 128
#define OUTC 40
#define WTOT 139264  // Wl 49152 | Wr 49152 | W0 8192 | W1 16384 | W2 16384
#define PB 200       // blocks for edge-binning passes
#define NBK_MAX 256  // max buckets (512 nodes each)

typedef __attribute__((ext_vector_type(8))) short short8;
typedef __attribute__((ext_vector_type(4))) float floatx4;

__device__ __forceinline__ unsigned short f2b(float f) {
  unsigned int u = __float_as_uint(f);
  unsigned int r = u + 0x7FFFu + ((u >> 16) & 1u);
  return (unsigned short)(r >> 16);
}
__device__ __forceinline__ float blo(unsigned int u) { return __uint_as_float(u << 16); }
__device__ __forceinline__ float bhi(unsigned int u) { return __uint_as_float(u & 0xFFFF0000u); }
__device__ __forceinline__ unsigned int pack2(float a, float b) {
  return (unsigned int)f2b(a) | ((unsigned int)f2b(b) << 16);
}

__device__ __forceinline__ void async_cp16(const ushort* g, ushort* l) {
  __builtin_amdgcn_global_load_lds((const __attribute__((address_space(1))) void*)g,
                                   (__attribute__((address_space(3))) void*)l, 16, 0, 0);
}

// ================= device bodies =================

__device__ __forceinline__ void cvt_body(int bid, const float* __restrict__ in,
                                         ushort* __restrict__ out, int n4) {
  int i = bid * 256 + threadIdx.x;
  if (i >= n4) return;
  float4 v = ((const float4*)in)[i];
  ushort4 o;
  o.x = f2b(v.x); o.y = f2b(v.y); o.z = f2b(v.z); o.w = f2b(v.w);
  ((ushort4*)out)[i] = o;
}

__device__ __forceinline__ void cvtw_body(int bid, const float* __restrict__ Wl,
                                          const float* __restrict__ Wr, const float* __restrict__ W0,
                                          const float* __restrict__ W1, const float* __restrict__ W2,
                                          const float* __restrict__ Wc, ushort* __restrict__ wb,
                                          ushort* __restrict__ wcb, float* __restrict__ stats) {
  int gid = bid * 256 + threadIdx.x;
  if (gid < 8192) stats[gid] = 0.0f;  // 4 sets x 8 replicas x 256
  if (gid < 48 * 64) {  // wcb: 48x256 bf16, rows 40..47 zero
    int row = gid >> 6;
    ushort4 o;
    if (row < 40) {
      float4 v = *(const float4*)(Wc + (size_t)gid * 4);
      o.x = f2b(v.x); o.y = f2b(v.y); o.z = f2b(v.z); o.w = f2b(v.w);
    } else {
      o.x = 0; o.y = 0; o.z = 0; o.w = 0;
    }
    ((ushort4*)wcb)[gid] = o;
  }
  int e4 = gid * 4;
  if (e4 < WTOT) {
    const float* s; int off;
    if (e4 < 49152)       { s = Wl; off = 0; }
    else if (e4 < 98304)  { s = Wr; off = 49152; }
    else if (e4 < 106496) { s = W0; off = 98304; }
    else if (e4 < 122880) { s = W1; off = 106496; }
    else                  { s = W2; off = 122880; }
    float4 v = *(const float4*)(s + (e4 - off));
    ushort4 o;
    o.x = f2b(v.x); o.y = f2b(v.y); o.z = f2b(v.z); o.w = f2b(v.w);
    *(ushort4*)(wb + e4) = o;
  }
}

__device__ __forceinline__ void anorm2_body(int bid, const float* __restrict__ alpha,
                                            ushort* __restrict__ ab, ushort* __restrict__ anb,
                                            int n) {
  int g = (bid * 256 + threadIdx.x) >> 4;  // 16 lanes/node
  int lane = threadIdx.x & 15;
  if (g >= n) return;
  const float4 a = *(const float4*)(alpha + (size_t)g * 64 + lane * 4);
  ushort4 raw;
  raw.x = f2b(a.x); raw.y = f2b(a.y); raw.z = f2b(a.z); raw.w = f2b(a.w);
  *(ushort4*)(ab + (size_t)g * 64 + lane * 4) = raw;
  float d = a.x * a.x + a.y * a.y + a.z * a.z + a.w * a.w;
  d += __shfl_xor(d, 1); d += __shfl_xor(d, 2);
  d += __shfl_xor(d, 4); d += __shfl_xor(d, 8);
  float r = 1.0f / fmaxf(sqrtf(d), 1e-12f);
  ushort4 o;
  o.x = f2b(a.x * r); o.y = f2b(a.y * r); o.z = f2b(a.z * r); o.w = f2b(a.w * r);
  *(ushort4*)(anb + (size_t)g * 64 + lane * 4) = o;
}

__device__ __forceinline__ void binA_body(int bid, const int* __restrict__ tgt,
                                          int* __restrict__ G, int e, int chunk, int nbk) {
  __shared__ int hist[NBK_MAX];
  int tid = threadIdx.x;
  for (int b = tid; b < nbk; b += 256) hist[b] = 0;
  __syncthreads();
  int i0 = bid * chunk;
  int i1 = min(e, i0 + chunk);
  for (int j = i0 + tid; j < i1; j += 256) atomicAdd(&hist[tgt[j] >> 9], 1);
  __syncthreads();
  for (int b = tid; b < nbk; b += 256) G[b * PB + bid] = hist[b];
}

// ---- fused layer-0 aggregate + gate (1 wave / node, 16 neighbors / iter) ----
__device__ __forceinline__ void agg_gate_body(int bid, const ushort* __restrict__ h,
                                              const ushort* __restrict__ anb,
                                              const int* __restrict__ rowptr,
                                              const int* __restrict__ csr,
                                              const float* __restrict__ temp,
                                              float* __restrict__ gout,
                                              ushort* __restrict__ outb, int n) {
  int g = bid * 4 + (threadIdx.x >> 6);  // 1 wave per node
  if (g >= n) return;
  const int l = threadIdx.x & 63;
  const int js = l >> 4;   // neighbor slot 0..3
  const int c = l & 15;    // 16B chunk of the 256B h row / 8B chunk of anb row
  int beg = rowptr[g], end = rowptr[g + 1];
  int deg = end - beg;
  uint2 av = *(const uint2*)(anb + (size_t)g * 64 + c * 4);
  float av0 = blo(av.x), av1 = bhi(av.x), av2 = blo(av.y), av3 = bhi(av.y);
  float a0=0,a1=0,a2=0,a3=0,a4=0,a5=0,a6=0,a7=0;
  float dot = 0.f;
  int j = beg;
  int jend = beg + (deg & ~15);
  for (; j < jend; j += 16) {
    int u0 = csr[j + js];
    int u1 = csr[j + js + 4];
    int u2 = csr[j + js + 8];
    int u3 = csr[j + js + 12];
    uint4 v0 = *(const uint4*)(h + (size_t)u0 * HID + c * 8);
    uint4 v1 = *(const uint4*)(h + (size_t)u1 * HID + c * 8);
    uint4 v2 = *(const uint4*)(h + (size_t)u2 * HID + c * 8);
    uint4 v3 = *(const uint4*)(h + (size_t)u3 * HID + c * 8);
    uint2 w0 = *(const uint2*)(anb + (size_t)u0 * 64 + c * 4);
    uint2 w1 = *(const uint2*)(anb + (size_t)u1 * 64 + c * 4);
    uint2 w2 = *(const uint2*)(anb + (size_t)u2 * 64 + c * 4);
    uint2 w3 = *(const uint2*)(anb + (size_t)u3 * 64 + c * 4);
    a0 += (blo(v0.x) + blo(v1.x)) + (blo(v2.x) + blo(v3.x));
    a1 += (bhi(v0.x) + bhi(v1.x)) + (bhi(v2.x) + bhi(v3.x));
    a2 += (blo(v0.y) + blo(v1.y)) + (blo(v2.y) + blo(v3.y));
    a3 += (bhi(v0.y) + bhi(v1.y)) + (bhi(v2.y) + bhi(v3.y));
    a4 += (blo(v0.z) + blo(v1.z)) + (blo(v2.z) + blo(v3.z));
    a5 += (bhi(v0.z) + bhi(v1.z)) + (bhi(v2.z) + bhi(v3.z));
    a6 += (blo(v0.w) + blo(v1.w)) + (blo(v2.w) + blo(v3.w));
    a7 += (bhi(v0.w) + bhi(v1.w)) + (bhi(v2.w) + bhi(v3.w));
    dot += av0 * ((blo(w0.x) + blo(w1.x)) + (blo(w2.x) + blo(w3.x)))
         + av1 * ((bhi(w0.x) + bhi(w1.x)) + (bhi(w2.x) + bhi(w3.x)))
         + av2 * ((blo(w0.y) + blo(w1.y)) + (blo(w2.y) + blo(w3.y)))
         + av3 * ((bhi(w0.y) + bhi(w1.y)) + (bhi(w2.y) + bhi(w3.y)));
  }
  int rem = end - j;  // 0..15
  if (js < rem) {
    int u0 = csr[j + js];
    uint4 v0 = *(const uint4*)(h + (size_t)u0 * HID + c * 8);
    uint2 w0 = *(const uint2*)(anb + (size_t)u0 * 64 + c * 4);
    a0 += blo(v0.x); a1 += bhi(v0.x); a2 += blo(v0.y); a3 += bhi(v0.y);
    a4 += blo(v0.z); a5 += bhi(v0.z); a6 += blo(v0.w); a7 += bhi(v0.w);
    dot += av0 * blo(w0.x) + av1 * bhi(w0.x) + av2 * blo(w0.y) + av3 * bhi(w0.y);
  }
  if (js + 4 < rem) {
    int u0 = csr[j + js + 4];
    uint4 v0 = *(const uint4*)(h + (size_t)u0 * HID + c * 8);
    uint2 w0 = *(const uint2*)(anb + (size_t)u0 * 64 + c * 4);
    a0 += blo(v0.x); a1 += bhi(v0.x); a2 += blo(v0.y); a3 += bhi(v0.y);
    a4 += blo(v0.z); a5 += bhi(v0.z); a6 += blo(v0.w); a7 += bhi(v0.w);
    dot += av0 * blo(w0.x) + av1 * bhi(w0.x) + av2 * blo(w0.y) + av3 * bhi(w0.y);
  }
  if (js + 8 < rem) {
    int u0 = csr[j + js + 8];
    uint4 v0 = *(const uint4*)(h + (size_t)u0 * HID + c * 8);
    uint2 w0 = *(const uint2*)(anb + (size_t)u0 * 64 + c * 4);
    a0 += blo(v0.x); a1 += bhi(v0.x); a2 += blo(v0.y); a3 += bhi(v0.y);
    a4 += blo(v0.z); a5 += bhi(v0.z); a6 += blo(v0.w); a7 += bhi(v0.w);
    dot += av0 * blo(w0.x) + av1 * bhi(w0.x) + av2 * blo(w0.y) + av3 * bhi(w0.y);
  }
  if (js + 12 < rem) {
    int u0 = csr[j + js + 12];
    uint4 v0 = *(const uint4*)(h + (size_t)u0 * HID + c * 8);
    uint2 w0 = *(const uint2*)(anb + (size_t)u0 * 64 + c * 4);
    a0 += blo(v0.x); a1 += bhi(v0.x); a2 += blo(v0.y); a3 += bhi(v0.y);
    a4 += blo(v0.z); a5 += bhi(v0.z); a6 += blo(v0.w); a7 += bhi(v0.w);
    dot += av0 * blo(w0.x) + av1 * bhi(w0.x) + av2 * blo(w0.y) + av3 * bhi(w0.y);
  }
  a0 += __shfl_xor(a0, 16); a0 += __shfl_xor(a0, 32);
  a1 += __shfl_xor(a1, 16); a1 += __shfl_xor(a1, 32);
  a2 += __shfl_xor(a2, 16); a2 += __shfl_xor(a2, 32);
  a3 += __shfl_xor(a3, 16); a3 += __shfl_xor(a3, 32);
  a4 += __shfl_xor(a4, 16); a4 += __shfl_xor(a4, 32);
  a5 += __shfl_xor(a5, 16); a5 += __shfl_xor(a5, 32);
  a6 += __shfl_xor(a6, 16); a6 += __shfl_xor(a6, 32);
  a7 += __shfl_xor(a7, 16); a7 += __shfl_xor(a7, 32);
  dot += __shfl_xor(dot, 1); dot += __shfl_xor(dot, 2);
  dot += __shfl_xor(dot, 4); dot += __shfl_xor(dot, 8);
  dot += __shfl_xor(dot, 16); dot += __shfl_xor(dot, 32);
  if (l < 16) {
    float r = (deg > 0) ? 1.0f / (float)deg : 0.0f;
    uint4 o;
    o.x = pack2(a0 * r, a1 * r); o.y = pack2(a2 * r, a3 * r);
    o.z = pack2(a4 * r, a5 * r); o.w = pack2(a6 * r, a7 * r);
    *(uint4*)(outb + (size_t)g * HID + c * 8) = o;
  }
  if (l == 0) {
    float m = (1.0f + dot) / (float)(deg + 1);  // self-loop dot = 1
    gout[g] = 1.0f / (1.0f + expf(-temp[0] * m));
  }
}

// ---- SAGE mean aggregation (1 wave / node, 16 neighbors / iter) ----
__device__ __forceinline__ void agg_b_body(int bid, int goff, const ushort* __restrict__ h,
                                           const int* __restrict__ rowptr,
                                           const int* __restrict__ csr,
                                           ushort* __restrict__ outb, int n) {
  int g = goff + bid * 4 + (threadIdx.x >> 6);
  if (g >= n) return;
  const int l = threadIdx.x & 63;
  const int js = l >> 4;
  const int c = l & 15;
  int beg = rowptr[g], end = rowptr[g + 1];
  int deg = end - beg;
  float a0=0,a1=0,a2=0,a3=0,a4=0,a5=0,a6=0,a7=0;
  int j = beg;
  int jend = beg + (deg & ~15);
  for (; j < jend; j += 16) {
    int u0 = csr[j + js];
    int u1 = csr[j + js + 4];
    int u2 = csr[j + js + 8];
    int u3 = csr[j + js + 12];
    uint4 v0 = *(const uint4*)(h + (size_t)u0 * HID + c * 8);
    uint4 v1 = *(const uint4*)(h + (size_t)u1 * HID + c * 8);
    uint4 v2 = *(const uint4*)(h + (size_t)u2 * HID + c * 8);
    uint4 v3 = *(const uint4*)(h + (size_t)u3 * HID + c * 8);
    a0 += (blo(v0.x) + blo(v1.x)) + (blo(v2.x) + blo(v3.x));
    a1 += (bhi(v0.x) + bhi(v1.x)) + (bhi(v2.x) + bhi(v3.x));
    a2 += (blo(v0.y) + blo(v1.y)) + (blo(v2.y) + blo(v3.y));
    a3 += (bhi(v0.y) + bhi(v1.y)) + (bhi(v2.y) + bhi(v3.y));
    a4 += (blo(v0.z) + blo(v1.z)) + (blo(v2.z) + blo(v3.z));
    a5 += (bhi(v0.z) + bhi(v1.z)) + (bhi(v2.z) + bhi(v3.z));
    a6 += (blo(v0.w) + blo(v1.w)) + (blo(v2.w) + blo(v3.w));
    a7 += (bhi(v0.w) + bhi(v1.w)) + (bhi(v2.w) + bhi(v3.w));
  }
  int rem = end - j;  // 0..15
  if (js < rem) {
    int u0 = csr[j + js];
    uint4 v0 = *(const uint4*)(h + (size_t)u0 * HID + c * 8);
    a0 += blo(v0.x); a1 += bhi(v0.x); a2 += blo(v0.y); a3 += bhi(v0.y);
    a4 += blo(v0.z); a5 += bhi(v0.z); a6 += blo(v0.w); a7 += bhi(v0.w);
  }
  if (js + 4 < rem) {
    int u0 = csr[j + js + 4];
    uint4 v0 = *(const uint4*)(h + (size_t)u0 * HID + c * 8);
    a0 += blo(v0.x); a1 += bhi(v0.x); a2 += blo(v0.y); a3 += bhi(v0.y);
    a4 += blo(v0.z); a5 += bhi(v0.z); a6 += blo(v0.w); a7 += bhi(v0.w);
  }
  if (js + 8 < rem) {
    int u0 = csr[j + js + 8];
    uint4 v0 = *(const uint4*)(h + (size_t)u0 * HID + c * 8);
    a0 += blo(v0.x); a1 += bhi(v0.x); a2 += blo(v0.y); a3 += bhi(v0.y);
    a4 += blo(v0.z); a5 += bhi(v0.z); a6 += blo(v0.w); a7 += bhi(v0.w);
  }
  if (js + 12 < rem) {
    int u0 = csr[j + js + 12];
    uint4 v0 = *(const uint4*)(h + (size_t)u0 * HID + c * 8);
    a0 += blo(v0.x); a1 += bhi(v0.x); a2 += blo(v0.y); a3 += bhi(v0.y);
    a4 += blo(v0.z); a5 += bhi(v0.z); a6 += blo(v0.w); a7 += bhi(v0.w);
  }
  a0 += __shfl_xor(a0, 16); a0 += __shfl_xor(a0, 32);
  a1 += __shfl_xor(a1, 16); a1 += __shfl_xor(a1, 32);
  a2 += __shfl_xor(a2, 16); a2 += __shfl_xor(a2, 32);
  a3 += __shfl_xor(a3, 16); a3 += __shfl_xor(a3, 32);
  a4 += __shfl_xor(a4, 16); a4 += __shfl_xor(a4, 32);
  a5 += __shfl_xor(a5, 16); a5 += __shfl_xor(a5, 32);
  a6 += __shfl_xor(a6, 16); a6 += __shfl_xor(a6, 32);
  a7 += __shfl_xor(a7, 16); a7 += __shfl_xor(a7, 32);
  if (l < 16) {
    float r = (deg > 0) ? 1.0f / (float)deg : 0.0f;
    uint4 o;
    o.x = pack2(a0 * r, a1 * r); o.y = pack2(a2 * r, a3 * r);
    o.z = pack2(a4 * r, a5 * r); o.w = pack2(a6 * r, a7 * r);
    *(uint4*)(outb + (size_t)g * HID + c * 8) = o;
  }
}

// ---- MFMA linear body: C = A1@W1^T (+ A2@W2^T) + bias, bf16 in/out ----
// stats buffer is 8-way replicated (bid&7).
template <int NPARTS, bool STATS, bool ORELU>
__device__ __forceinline__ void mlin_body(
    int bid, const ushort* __restrict__ A1, const ushort* __restrict__ A2, int K,
    const ushort* __restrict__ W1, const ushort* __restrict__ W2,
    const float* __restrict__ bias, ushort* __restrict__ C,
    float* __restrict__ stats, int M, ushort* As, ushort* Bs) {
  const int tid = threadIdx.x;
  const int w = tid >> 6, l = tid & 63;
  const int mbase = bid * 128;
  const int lm = l & 15, lq = l >> 4;
  floatx4 acc[2][8];
#pragma unroll
  for (int mt = 0; mt < 2; ++mt)
#pragma unroll
    for (int nt = 0; nt < 8; ++nt) {
      floatx4 z = {0.f, 0.f, 0.f, 0.f};
      acc[mt][nt] = z;
    }

  for (int part = 0; part < NPARTS; ++part) {
    const ushort* Ap = part ? A2 : A1;
    const ushort* Wp = part ? W2 : W1;
    for (int k0 = 0; k0 < K; k0 += 32) {
#pragma unroll
      for (int i = 0; i < 2; ++i) {
        int s = w * 2 + i;
        int rt = s * 16 + (l >> 2);
        int q = (l & 3) ^ ((rt >> 1) & 3);
        int grow = mbase + rt; grow = grow < M ? grow : M - 1;
        async_cp16(Ap + (size_t)grow * K + k0 + q * 8, &As[s * 512]);
        async_cp16(Wp + (size_t)rt * K + k0 + q * 8, &Bs[s * 512]);
      }
      __syncthreads();
      short8 b[8];
#pragma unroll
      for (int nt = 0; nt < 8; ++nt) {
        int row = nt * 16 + lm;
        int q = lq ^ ((row >> 1) & 3);
        b[nt] = *(const short8*)&Bs[row * 32 + q * 8];
      }
#pragma unroll
      for (int mt = 0; mt < 2; ++mt) {
        int row = (w * 2 + mt) * 16 + lm;
        int q = lq ^ ((row >> 1) & 3);
        short8 a = *(const short8*)&As[row * 32 + q * 8];
#pragma unroll
        for (int nt = 0; nt < 8; ++nt)
          acc[mt][nt] = __builtin_amdgcn_mfma_f32_16x16x32_bf16(a, b[nt], acc[mt][nt], 0, 0, 0);
      }
      __syncthreads();
    }
  }

  float ss[8], qq[8];
#pragma unroll
  for (int nt = 0; nt < 8; ++nt) { ss[nt] = 0.f; qq[nt] = 0.f; }
#pragma unroll
  for (int nt = 0; nt < 8; ++nt) {
    int col = nt * 16 + lm;
    float bv = bias[col];
#pragma unroll
    for (int mt = 0; mt < 2; ++mt) {
      int rbase = mbase + (w * 2 + mt) * 16 + lq * 4;
#pragma unroll
      for (int r = 0; r < 4; ++r) {
        int grow = rbase + r;
        if (grow < M) {
          float val = acc[mt][nt][r] + bv;
          if (ORELU) val = fmaxf(val, 0.f);
          C[(size_t)grow * 128 + col] = f2b(val);
          if (STATS) { ss[nt] += val; qq[nt] += val * val; }
        }
      }
    }
  }
  if (STATS) {
    float* sred = (float*)As;
    if (tid < 256) sred[tid] = 0.f;
    __syncthreads();
#pragma unroll
    for (int nt = 0; nt < 8; ++nt) {
      ss[nt] += __shfl_xor(ss[nt], 16); ss[nt] += __shfl_xor(ss[nt], 32);
      qq[nt] += __shfl_xor(qq[nt], 16); qq[nt] += __shfl_xor(qq[nt], 32);
    }
    if (lq == 0) {
#pragma unroll
      for (int nt = 0; nt < 8; ++nt) {
        int col = nt * 16 + lm;
        atomicAdd(&sred[col], ss[nt]);
        atomicAdd(&sred[128 + col], qq[nt]);
      }
    }
    __syncthreads();
    float* sbase = stats + ((bid & 7) << 8);
    if (tid < 256) atomicAdd(&sbase[tid], sred[tid]);
  }
}

// ---- BatchNorm apply body (bf16 in-place; sums 8 stats replicas) ----
template <int ACT>  // 0=relu, 1=sigmoid
__device__ __forceinline__ void bnb_body(int bid, int gB, ushort* __restrict__ buf,
                                         const float* __restrict__ stats,
                                         const float* __restrict__ gamma,
                                         const float* __restrict__ beta, int n) {
  const int S = gB * 256;
  int idx = bid * 256 + threadIdx.x;
  const int c0 = (idx & 15) * 8;
  const float inv_n = 1.0f / (float)n;
  float sc[8], sh[8];
#pragma unroll
  for (int d = 0; d < 8; ++d) {
    int c = c0 + d;
    float s0 = 0.f, s1 = 0.f;
#pragma unroll
    for (int r2 = 0; r2 < 8; ++r2) {
      s0 += stats[(r2 << 8) + c];
      s1 += stats[(r2 << 8) + 128 + c];
    }
    float mu = s0 * inv_n;
    float var = s1 * inv_n - mu * mu;
    float s = rsqrtf(var + 1e-5f) * gamma[c];
    sc[d] = s;
    sh[d] = beta[c] - mu * s;
  }
  const int n16 = n * 16;
  for (; idx < n16; idx += S) {
    uint4 v = ((const uint4*)buf)[idx];
    float x[8] = {blo(v.x), bhi(v.x), blo(v.y), bhi(v.y),
                  blo(v.z), bhi(v.z), blo(v.w), bhi(v.w)};
#pragma unroll
    for (int d = 0; d < 8; ++d) {
      float y = x[d] * sc[d] + sh[d];
      x[d] = (ACT == 0) ? fmaxf(y, 0.f) : 1.0f / (1.0f + expf(-y));
    }
    uint4 o;
    o.x = pack2(x[0], x[1]); o.y = pack2(x[2], x[3]);
    o.z = pack2(x[4], x[5]); o.w = pack2(x[6], x[7]);
    ((uint4*)buf)[idx] = o;
  }
}

// ---- classifier body: MFMA GEMM + fused log_softmax ----
__device__ __forceinline__ void clsm_body(
    int bid, const ushort* __restrict__ A1, const ushort* __restrict__ A2,
    const ushort* __restrict__ Wcb, const float* __restrict__ bias,
    float* __restrict__ C, int M, ushort* As, ushort* Bs) {
  const int tid = threadIdx.x;
  const int w = tid >> 6, l = tid & 63;
  const int mbase = bid * 128;
  const int lm = l & 15, lq = l >> 4;
  floatx4 acc[2][3];
#pragma unroll
  for (int mt = 0; mt < 2; ++mt)
#pragma unroll
    for (int nt = 0; nt < 3; ++nt) {
      floatx4 z = {0.f, 0.f, 0.f, 0.f};
      acc[mt][nt] = z;
    }

  for (int part = 0; part < 2; ++part) {
    const ushort* Ap = part ? A2 : A1;
    for (int k0 = 0; k0 < 128; k0 += 32) {
#pragma unroll
      for (int i = 0; i < 2; ++i) {
        int s = w * 2 + i;
        int rt = s * 16 + (l >> 2);
        int q = (l & 3) ^ ((rt >> 1) & 3);
        int grow = mbase + rt; grow = grow < M ? grow : M - 1;
        async_cp16(Ap + (size_t)grow * 128 + k0 + q * 8, &As[s * 512]);
      }
      if (w < 3) {
        int rt = w * 16 + (l >> 2);
        int q = (l & 3) ^ ((rt >> 1) & 3);
        async_cp16(Wcb + (size_t)rt * 256 + part * 128 + k0 + q * 8, &Bs[w * 512]);
      }
      __syncthreads();
      short8 b[3];
#pragma unroll
      for (int nt = 0; nt < 3; ++nt) {
        int row = nt * 16 + lm;
        int q = lq ^ ((row >> 1) & 3);
        b[nt] = *(const short8*)&Bs[row * 32 + q * 8];
      }
#pragma unroll
      for (int mt = 0; mt < 2; ++mt) {
        int row = (w * 2 + mt) * 16 + lm;
        int q = lq ^ ((row >> 1) & 3);
        short8 a = *(const short8*)&As[row * 32 + q * 8];
#pragma unroll
        for (int nt = 0; nt < 3; ++nt)
          acc[mt][nt] = __builtin_amdgcn_mfma_f32_16x16x32_bf16(a, b[nt], acc[mt][nt], 0, 0, 0);
      }
      __syncthreads();
    }
  }

  float b0v = bias[lm], b1v = bias[lm + 16];
  float b2v = (lm < 8) ? bias[lm + 32] : 0.f;
#pragma unroll
  for (int mt = 0; mt < 2; ++mt) {
#pragma unroll
    for (int r = 0; r < 4; ++r) {
      int grow = mbase + (w * 2 + mt) * 16 + lq * 4 + r;
      float v0 = acc[mt][0][r] + b0v;
      float v1 = acc[mt][1][r] + b1v;
      float v2 = (lm < 8) ? acc[mt][2][r] + b2v : -3.4e38f;
      float m = fmaxf(fmaxf(v0, v1), v2);
      m = fmaxf(m, __shfl_xor(m, 1)); m = fmaxf(m, __shfl_xor(m, 2));
      m = fmaxf(m, __shfl_xor(m, 4)); m = fmaxf(m, __shfl_xor(m, 8));
      float s = expf(v0 - m) + expf(v1 - m) + ((lm < 8) ? expf(v2 - m) : 0.f);
      s += __shfl_xor(s, 1); s += __shfl_xor(s, 2);
      s += __shfl_xor(s, 4); s += __shfl_xor(s, 8);
      float ls = m + logf(s);
      if (grow < M) {
        C[(size_t)grow * OUTC + lm] = v0 - ls;
        C[(size_t)grow * OUTC + lm + 16] = v1 - ls;
        if (lm < 8) C[(size_t)grow * OUTC + lm + 32] = v2 - ls;
      }
    }
  }
}

// ================= global kernels =================

// prep (cvtw | cvt | anorm2) + binA, one launch
__global__ void prep_binA_kernel(
    const float* __restrict__ x, ushort* __restrict__ xb, int n4,
    const float* __restrict__ alpha, ushort* __restrict__ ab, ushort* __restrict__ anb, int n,
    const float* __restrict__ Wl, const float* __restrict__ Wr, const float* __restrict__ W0,
    const float* __restrict__ W1, const float* __restrict__ W2, const float* __restrict__ Wc,
    ushort* __restrict__ wb, ushort* __restrict__ wcb, float* __restrict__ stats,
    const int* __restrict__ tgt, int* __restrict__ G, int e, int chunk, int nbk,
    int GW, int GC, int GA) {
  int b = blockIdx.x;
  if (b < GW) cvtw_body(b, Wl, Wr, W0, W1, W2, Wc, wb, wcb, stats);
  else if (b < GW + GC) cvt_body(b - GW, x, xb, n4);
  else if (b < GW + GC + GA) anorm2_body(b - GW - GC, alpha, ab, anb, n);
  else binA_body(b - GW - GC - GA, tgt, G, e, chunk, nbk);
}

// ---------------- exclusive scan (for the bucket table) ----------------

#define SCAN_T 256
#define SCAN_VPT 8
#define SCAN_ELEMS 2048

__global__ void scan1_kernel(const int* __restrict__ cnt, int* __restrict__ outp,
                             int* __restrict__ blksum, int n) {
  __shared__ int sh[SCAN_T];
  int t = threadIdx.x;
  int base = blockIdx.x * SCAN_ELEMS + t * SCAN_VPT;
  int v[SCAN_VPT];
  int s = 0;
#pragma unroll
  for (int i = 0; i < SCAN_VPT; ++i) {
    int idx = base + i;
    v[i] = (idx < n) ? cnt[idx] : 0;
    s += v[i];
  }
  sh[t] = s;
  __syncthreads();
  for (int d = 1; d < SCAN_T; d <<= 1) {
    int add = (t >= d) ? sh[t - d] : 0;
    __syncthreads();
    sh[t] += add;
    __syncthreads();
  }
  int p = sh[t] - s;
#pragma unroll
  for (int i = 0; i < SCAN_VPT; ++i) {
    int idx = base + i;
    if (idx < n) outp[idx] = p;
    p += v[i];
  }
  if (t == SCAN_T - 1) blksum[blockIdx.x] = sh[t];
}

__global__ void scan2_kernel(int* __restrict__ blk, int nb) {
  __shared__ int sh[SCAN_T];
  int t = threadIdx.x;
  int s = (t < nb) ? blk[t] : 0;
  sh[t] = s;
  __syncthreads();
  for (int d = 1; d < SCAN_T; d <<= 1) {
    int add = (t >= d) ? sh[t - d] : 0;
    __syncthreads();
    sh[t] += add;
    __syncthreads();
  }
  if (t < nb) blk[t] = sh[t] - s;
}

// ---------------- bucketed CSR build (no global atomics) ----------------
// Gs holds the per-(bucket,block) exclusive scan WITHOUT the cross-scan-block
// offset; consumers add blkoff[i >> 11] (SCAN_ELEMS = 2048) on the fly.

__device__ __forceinline__ void binB_body(int bid, const int* __restrict__ src,
                                          const int* __restrict__ tgt,
                                          const int* __restrict__ Gs,
                                          const int* __restrict__ blkoff,
                                          int* __restrict__ ebuf, int e, int chunk, int nbk) {
  __shared__ int cur[NBK_MAX];
  int tid = threadIdx.x;
  for (int b = tid; b < nbk; b += 256) {
    int i = b * PB + bid;
    cur[b] = Gs[i] + blkoff[i >> 11];
  }
  __syncthreads();
  int i0 = bid * chunk;
  int i1 = min(e, i0 + chunk);
  for (int j = i0 + tid; j < i1; j += 256) {
    int t = tgt[j];
    int pos = atomicAdd(&cur[t >> 9], 1);
    ebuf[pos] = ((t & 511) << 17) | src[j];
  }
}

// binB (blocks [0,PB)) || proto W0 GEMM (rest). Disjoint data; W0 needs only
// prep outputs (ab, stats) and writes hproto (B3, no longer aliased by ebuf).
__global__ __launch_bounds__(256) void k_binB_w0(
    const int* __restrict__ src, const int* __restrict__ tgt,
    const int* __restrict__ Gs, const int* __restrict__ blkoff,
    int* __restrict__ ebuf, int e, int chunk, int nbk,
    const ushort* __restrict__ ab, const ushort* __restrict__ W0b,
    const float* __restrict__ b0, ushort* __restrict__ hproto,
    float* __restrict__ stats, int n) {
  __shared__ ushort As[4096];
  __shared__ ushort Bs[4096];
  if ((int)blockIdx.x < PB)
    binB_body(blockIdx.x, src, tgt, Gs, blkoff, ebuf, e, chunk, nbk);
  else
    mlin_body<1, true, false>(blockIdx.x - PB, ab, nullptr, 64, W0b, nullptr, b0,
                              hproto, stats, n, As, Bs);
}

__global__ void binC_kernel(const int* __restrict__ ebuf, const int* __restrict__ Gs,
                            const int* __restrict__ blkoff,
                            int* __restrict__ rowptr, int* __restrict__ csr,
                            int n, int e, int nbk) {
  __shared__ int hist[512];
  __shared__ int scanbuf[256];
  int b = blockIdx.x, tid = threadIdx.x;
  int i0 = b * PB;
  int seg0 = Gs[i0] + blkoff[i0 >> 11];
  int seg1;
  if (b + 1 < nbk) {
    int i1 = (b + 1) * PB;
    seg1 = Gs[i1] + blkoff[i1 >> 11];
  } else {
    seg1 = e;
  }
  hist[tid] = 0; hist[tid + 256] = 0;
  __syncthreads();
  for (int j = seg0 + tid; j < seg1; j += 256)
    atomicAdd(&hist[ebuf[j] >> 17], 1);
  __syncthreads();
  int a0 = hist[2 * tid], a1 = hist[2 * tid + 1];
  int s = a0 + a1;
  scanbuf[tid] = s;
  __syncthreads();
  for (int d = 1; d < 256; d <<= 1) {
    int add = (tid >= d) ? scanbuf[tid - d] : 0;
    __syncthreads();
    scanbuf[tid] += add;
    __syncthreads();
  }
  int ex = scanbuf[tid] - s;
  hist[2 * tid] = ex;
  hist[2 * tid + 1] = ex + a0;
  int node0 = b * 512 + 2 * tid;
  if (node0 < n) rowptr[node0] = seg0 + ex;
  if (node0 + 1 < n) rowptr[node0 + 1] = seg0 + ex + a0;
  __syncthreads();
  for (int j = seg0 + tid; j < seg1; j += 256) {
    int val = ebuf[j];
    int pos = atomicAdd(&hist[val >> 17], 1);
    csr[seg0 + pos] = val & 0x1FFFF;
  }
  if (b == nbk - 1 && tid == 0) rowptr[n] = e;
}

// ---------------- pure aggregation kernels (VGPR capped at 64) ----------------

__global__ __launch_bounds__(256, 8) void agg_gate_kernel(
    const ushort* __restrict__ h, const ushort* __restrict__ anb,
    const int* __restrict__ rowptr, const int* __restrict__ csr,
    const float* __restrict__ temp, float* __restrict__ gout,
    ushort* __restrict__ outb, int n) {
  agg_gate_body(blockIdx.x, h, anb, rowptr, csr, temp, gout, outb, n);
}

__global__ __launch_bounds__(256, 8) void agg_b_kernel(
    const ushort* __restrict__ h, const int* __restrict__ rowptr,
    const int* __restrict__ csr, ushort* __restrict__ outb, int goff, int n) {
  agg_b_body(blockIdx.x, goff, h, rowptr, csr, outb, n);
}

// agg_b (blocks [0,gAgg)) || bnb (trailing) — no mlin, footprint stays small
template <int ACT>
__global__ __launch_bounds__(256, 8) void k_agg_bnb(
    const ushort* __restrict__ h, const int* __restrict__ rowptr,
    const int* __restrict__ csr, ushort* __restrict__ outb, int n, int gAgg,
    ushort* __restrict__ bnbuf, const float* __restrict__ bnstats,
    const float* __restrict__ gamma, const float* __restrict__ beta, int gBn) {
  if ((int)blockIdx.x < gAgg)
    agg_b_body(blockIdx.x, 0, h, rowptr, csr, outb, n);
  else
    bnb_body<ACT>(blockIdx.x - gAgg, gBn, bnbuf, bnstats, gamma, beta, n);
}

// ---------------- combined launches (same-footprint roles only) --------------

// mlin (blocks [0,gLin)) || bnb (rest)
template <int NP, bool ST, bool OR_, int ACT>
__global__ __launch_bounds__(256) void k_mlin_bnb(
    const ushort* __restrict__ A1, const ushort* __restrict__ A2, int K,
    const ushort* __restrict__ W1, const ushort* __restrict__ W2,
    const float* __restrict__ bias, ushort* __restrict__ C, float* __restrict__ stats,
    ushort* __restrict__ bnbuf, const float* __restrict__ bnstats,
    const float* __restrict__ gamma, const float* __restrict__ beta,
    int M, int gLin, int gBn) {
  __shared__ ushort As[4096];
  __shared__ ushort Bs[4096];
  if ((int)blockIdx.x < gLin)
    mlin_body<NP, ST, OR_>(blockIdx.x, A1, A2, K, W1, W2, bias, C, stats, M, As, Bs);
  else
    bnb_body<ACT>(blockIdx.x - gLin, gBn, bnbuf, bnstats, gamma, beta, M);
}

// SAGE mlin (blocks [0,gLin)) || proto mlin (rest)
__global__ __launch_bounds__(256) void k_mlin_mlin(
    const ushort* __restrict__ A1a, const ushort* __restrict__ A2a,
    const ushort* __restrict__ W1a, const ushort* __restrict__ W2a,
    const float* __restrict__ ba, ushort* __restrict__ Ca, float* __restrict__ statsa,
    const ushort* __restrict__ A1b, const ushort* __restrict__ W1b,
    const float* __restrict__ bb, ushort* __restrict__ Cb, int M, int gLin) {
  __shared__ ushort As[4096];
  __shared__ ushort Bs[4096];
  if ((int)blockIdx.x < gLin)
    mlin_body<2, true, false>(blockIdx.x, A1a, A2a, 128, W1a, W2a, ba, Ca, statsa, M, As, Bs);
  else
    mlin_body<1, false, true>(blockIdx.x - gLin, A1b, nullptr, 128, W1b, nullptr, bb, Cb,
                              nullptr, M, As, Bs);
}

// SAGE GEMM2 rows-half2 (blocks [0,nM), rows offset moff) || clsm rows-half1 (rest)
__global__ __launch_bounds__(256) void k_mlin_clsm(
    const ushort* __restrict__ A1, const ushort* __restrict__ A2,
    const ushort* __restrict__ W1, const ushort* __restrict__ W2,
    const float* __restrict__ bias, ushort* __restrict__ C, int moff, int nM,
    const ushort* __restrict__ cA1, const ushort* __restrict__ cA2,
    const ushort* __restrict__ Wcb, const float* __restrict__ cbias,
    float* __restrict__ Cout, int M) {
  __shared__ ushort As[4096];
  __shared__ ushort Bs[4096];
  if ((int)blockIdx.x < nM)
    mlin_body<2, false, true>(blockIdx.x + moff, A1, A2, 128, W1, W2, bias, C,
                              nullptr, M, As, Bs);
  else
    clsm_body(blockIdx.x - nM, cA1, cA2, Wcb, cbias, Cout, M, As, Bs);
}

// ---------------- standalone kernels ----------------

template <int NPARTS, bool STATS, bool ORELU>
__global__ __launch_bounds__(256) void mlin_kernel(
    const ushort* __restrict__ A1, const ushort* __restrict__ A2, int K,
    const ushort* __restrict__ W1, const ushort* __restrict__ W2,
    const float* __restrict__ bias, ushort* __restrict__ C,
    float* __restrict__ stats, int M) {
  __shared__ ushort As[4096];
  __shared__ ushort Bs[4096];
  mlin_body<NPARTS, STATS, ORELU>(blockIdx.x, A1, A2, K, W1, W2, bias, C, stats, M, As, Bs);
}

template <int ACT>
__global__ __launch_bounds__(256) void bnb_kernel(
    ushort* __restrict__ buf, const float* __restrict__ stats,
    const float* __restrict__ gamma, const float* __restrict__ beta, int n) {
  bnb_body<ACT>(blockIdx.x, gridDim.x, buf, stats, gamma, beta, n);
}

__global__ __launch_bounds__(256) void clsm_kernel(
    const ushort* __restrict__ A1, const ushort* __restrict__ A2,
    const ushort* __restrict__ Wcb, const float* __restrict__ bias,
    float* __restrict__ C, int M, int boff) {
  __shared__ ushort As[4096];
  __shared__ ushort Bs[4096];
  clsm_body(blockIdx.x + boff, A1, A2, Wcb, bias, C, M, As, Bs);
}

// ---------------- launch ----------------

extern "C" void kernel_launch(void* const* d_in, const int* in_sizes, int n_in,
                              void* d_out, int out_size, void* d_ws, size_t ws_size,
                              hipStream_t stream) {
  const float* x       = (const float*)d_in[0];
  const float* alpha   = (const float*)d_in[1];
  const int*   eidx    = (const int*)d_in[2];
  const float* sage_Wl = (const float*)d_in[3];
  const float* sage_bl = (const float*)d_in[4];
  const float* sage_Wr = (const float*)d_in[5];
  const float* sage_g  = (const float*)d_in[6];
  const float* sage_b  = (const float*)d_in[7];
  const float* W0 = (const float*)d_in[8];
  const float* b0 = (const float*)d_in[9];
  const float* W1 = (const float*)d_in[10];
  const float* b1 = (const float*)d_in[11];
  const float* W2 = (const float*)d_in[12];
  const float* b2 = (const float*)d_in[13];
  const float* mg = (const float*)d_in[14];
  const float* mb = (const float*)d_in[15];
  const float* Wc = (const float*)d_in[16];
  const float* bc = (const float*)d_in[17];
  const float* temp = (const float*)d_in[18];
  float* out = (float*)d_out;

  const int n = in_sizes[0] / HID;  // 100000
  const int e = in_sizes[2] / 2;    // 1600000
  const int* src = eidx;
  const int* tgt = eidx + e;

  const int nbk = (n + 511) >> 9;
  const int glen = nbk * PB;
  const int chunk = (e + PB - 1) / PB;

  // workspace layout: 4 N×128 bf16 regions (16B aligned)
  // ebuf now lives in B2 (dead until agg1 output), so hproto (B3) is free
  // from the start and W0 can overlap the CSR build.
  char* p = (char*)d_ws;
  ushort* B0 = (ushort*)p; p += (size_t)n * HID * 2;
  ushort* B1 = (ushort*)p; p += (size_t)n * HID * 2;
  ushort* B2 = (ushort*)p; p += (size_t)n * HID * 2;
  ushort* B3 = (ushort*)p; p += (size_t)n * HID * 2;
  ushort* wb     = (ushort*)p; p += (size_t)WTOT * 2;
  ushort* wcb    = (ushort*)p; p += (size_t)48 * 256 * 2;
  float* stats = (float*)p; p += 8192 * 4;  // 4 sets x 8 replicas x 256 floats
  int* rowptr = (int*)p; p += ((size_t)n + 1) * 4;
  int* csr    = (int*)p; p += (size_t)e * 4;
  int* G      = (int*)p; p += (size_t)glen * 4;
  int* Gs     = (int*)p; p += (size_t)glen * 4;
  int* blks   = (int*)p;
  ushort* xb   = B0;
  ushort* anb  = B1;                       // N*64
  ushort* ab   = B1 + (size_t)n * 64;      // N*64
  ushort* hgnn = B1;                       // SAGE L2 out (B1 dead by then)
  int*    ebuf = (int*)B2;                 // e*4 <= n*256; dead after binC
  ushort* hproto = B3;
  ushort* Wlb = wb, *Wrb = wb + 49152, *W0b = wb + 98304, *W1b = wb + 106496, *W2b = wb + 122880;
  // stats sets (each 2048 floats: 8 replicas x 256)
  float* stSage0 = stats;
  float* stSage1 = stats + 2048;
  float* stPr0   = stats + 4096;
  float* stPr1   = stats + 6144;

  const int T = 256;
  const int nb_scan = (glen + SCAN_ELEMS - 1) / SCAN_ELEMS;

  const int gLin = (n + 127) / 128;        // 782
  const int gHalf = (gLin + 1) / 2;        // 391
  const int gLin2 = gLin - gHalf;          // 391
  const int gBn = 1024;
  const int gAgg = (n + 3) >> 2;           // 25000 (1 wave/node, 4/block)
  const int GW = WTOT / 4 / T;             // 136 blocks (exact)
  const int GC = (n * (HID / 4) + T - 1) / T;          // cvt blocks
  const int GA = (int)(((size_t)n * 16 + T - 1) / T);  // anorm2 blocks

  // 1: prep (weights cvt + x cvt + alpha norm) || binA
  prep_binA_kernel<<<GW + GC + GA + PB, T, 0, stream>>>(
      x, xb, n * (HID / 4), alpha, ab, anb, n,
      sage_Wl, sage_Wr, W0, W1, W2, Wc, wb, wcb, stats,
      tgt, G, e, chunk, nbk, GW, GC, GA);

  // 2-3: scan
  scan1_kernel<<<nb_scan, SCAN_T, 0, stream>>>(G, Gs, blks, glen);
  scan2_kernel<<<1, SCAN_T, 0, stream>>>(blks, nb_scan);

  // 4: binB || proto W0 GEMM (disjoint data; hides W0 entirely)
  k_binB_w0<<<PB + gLin, T, 0, stream>>>(src, tgt, Gs, blks, ebuf, e, chunk, nbk,
                                         ab, W0b, b0, hproto, stPr0, n);

  // 5: binC
  binC_kernel<<<nbk, T, 0, stream>>>(ebuf, Gs, blks, rowptr, csr, n, e, nbk);

  // 6: L0 aggregate + gate (pure, 16-deep, VGPR<=64)
  agg_gate_kernel<<<gAgg, T, 0, stream>>>(xb, anb, rowptr, csr, temp,
                                          out + (size_t)n * OUTC, B2, n);

  // 7: SAGE L0 GEMM || proto BN0 (sigmoid)
  k_mlin_bnb<2, true, false, 1><<<gLin + gBn, T, 0, stream>>>(
      B2, B0, 128, Wlb, Wrb, sage_bl, B1, stSage0,
      hproto, stPr0, mg, mb, n, gLin, gBn);

  // 8: proto W1 GEMM || SAGE BN0 (relu)
  k_mlin_bnb<1, true, false, 0><<<gLin + gBn, T, 0, stream>>>(
      hproto, nullptr, 128, W1b, nullptr, b1, hproto, stPr1,
      B1, stSage0, sage_g, sage_b, n, gLin, gBn);

  // 9: SAGE L1 aggregate (pure-footprint) || proto BN1 sigmoid (trailing)
  k_agg_bnb<1><<<gAgg + gBn, T, 0, stream>>>(B1, rowptr, csr, B2, n, gAgg,
                                             hproto, stPr1, mg + HID, mb + HID, gBn);

  // 10: SAGE L1 GEMM || proto W2 GEMM (relu fused)
  k_mlin_mlin<<<2 * gLin, T, 0, stream>>>(B2, B1, Wlb + 16384, Wrb + 16384,
                                          sage_bl + HID, B0, stSage1,
                                          hproto, W2b, b2, hproto, n, gLin);

  // 11: SAGE BN1 (relu)
  bnb_kernel<0><<<gBn, T, 0, stream>>>(B0, stSage1, sage_g + HID, sage_b + HID, n);

  // 12: SAGE L2 aggregate (pure, full)
  agg_b_kernel<<<gAgg, T, 0, stream>>>(B0, rowptr, csr, B2, 0, n);

  // 13: SAGE GEMM2 rows-half1
  mlin_kernel<2, false, true><<<gHalf, T, 0, stream>>>(B2, B0, 128, Wlb + 32768,
                                                       Wrb + 32768, sage_bl + 2 * HID,
                                                       hgnn, nullptr, n);

  // 14: SAGE GEMM2 rows-half2 || classifier rows-half1
  k_mlin_clsm<<<gLin2 + gHalf, T, 0, stream>>>(B2, B0, Wlb + 32768, Wrb + 32768,
                                               sage_bl + 2 * HID, hgnn, gHalf, gLin2,
                                               hgnn, hproto, wcb, bc, out, n);

  // 15: classifier rows-half2
  clsm_kernel<<<gLin - gHalf, T, 0, stream>>>(hgnn, hproto, wcb, bc, out, n, gHalf);
}

// Round 9
// 664.448 us; speedup vs baseline: 1.2047x; 1.0292x over previous
//
#include <hip/hip_runtime.h>
#include <cstdint>
#include <cstddef>

#define HID 128
#define OUTC 40
#define WTOT 139264  // Wl 49152 | Wr 49152 | W0 8192 | W1 16384 | W2 16384
#define PB 200       // blocks for edge-binning passes
#define NBK_MAX 256  // max buckets (512 nodes each)

typedef __attribute__((ext_vector_type(8))) short short8;
typedef __attribute__((ext_vector_type(4))) float floatx4;

__device__ __forceinline__ unsigned short f2b(float f) {
  unsigned int u = __float_as_uint(f);
  unsigned int r = u + 0x7FFFu + ((u >> 16) & 1u);
  return (unsigned short)(r >> 16);
}
__device__ __forceinline__ float blo(unsigned int u) { return __uint_as_float(u << 16); }
__device__ __forceinline__ float bhi(unsigned int u) { return __uint_as_float(u & 0xFFFF0000u); }
__device__ __forceinline__ unsigned int pack2(float a, float b) {
  return (unsigned int)f2b(a) | ((unsigned int)f2b(b) << 16);
}

__device__ __forceinline__ void async_cp16(const ushort* g, ushort* l) {
  __builtin_amdgcn_global_load_lds((const __attribute__((address_space(1))) void*)g,
                                   (__attribute__((address_space(3))) void*)l, 16, 0, 0);
}

// ================= device bodies =================

__device__ __forceinline__ void cvt_body(int bid, const float* __restrict__ in,
                                         ushort* __restrict__ out, int n4) {
  int i = bid * 256 + threadIdx.x;
  if (i >= n4) return;
  float4 v = ((const float4*)in)[i];
  ushort4 o;
  o.x = f2b(v.x); o.y = f2b(v.y); o.z = f2b(v.z); o.w = f2b(v.w);
  ((ushort4*)out)[i] = o;
}

__device__ __forceinline__ void cvtw_body(int bid, const float* __restrict__ Wl,
                                          const float* __restrict__ Wr, const float* __restrict__ W0,
                                          const float* __restrict__ W1, const float* __restrict__ W2,
                                          const float* __restrict__ Wc, ushort* __restrict__ wb,
                                          ushort* __restrict__ wcb, float* __restrict__ stats,
                                          int* __restrict__ gcnt) {
  int gid = bid * 256 + threadIdx.x;
  if (gid < 8192) stats[gid] = 0.0f;  // 4 sets x 8 replicas x 256
  if (gid < NBK_MAX) gcnt[gid] = 0;
  if (gid < 48 * 64) {  // wcb: 48x256 bf16, rows 40..47 zero
    int row = gid >> 6;
    ushort4 o;
    if (row < 40) {
      float4 v = *(const float4*)(Wc + (size_t)gid * 4);
      o.x = f2b(v.x); o.y = f2b(v.y); o.z = f2b(v.z); o.w = f2b(v.w);
    } else {
      o.x = 0; o.y = 0; o.z = 0; o.w = 0;
    }
    ((ushort4*)wcb)[gid] = o;
  }
  int e4 = gid * 4;
  if (e4 < WTOT) {
    const float* s; int off;
    if (e4 < 49152)       { s = Wl; off = 0; }
    else if (e4 < 98304)  { s = Wr; off = 49152; }
    else if (e4 < 106496) { s = W0; off = 98304; }
    else if (e4 < 122880) { s = W1; off = 106496; }
    else                  { s = W2; off = 122880; }
    float4 v = *(const float4*)(s + (e4 - off));
    ushort4 o;
    o.x = f2b(v.x); o.y = f2b(v.y); o.z = f2b(v.z); o.w = f2b(v.w);
    *(ushort4*)(wb + e4) = o;
  }
}

__device__ __forceinline__ void anorm2_body(int bid, const float* __restrict__ alpha,
                                            ushort* __restrict__ ab, ushort* __restrict__ anb,
                                            int n) {
  int g = (bid * 256 + threadIdx.x) >> 4;  // 16 lanes/node
  int lane = threadIdx.x & 15;
  if (g >= n) return;
  const float4 a = *(const float4*)(alpha + (size_t)g * 64 + lane * 4);
  ushort4 raw;
  raw.x = f2b(a.x); raw.y = f2b(a.y); raw.z = f2b(a.z); raw.w = f2b(a.w);
  *(ushort4*)(ab + (size_t)g * 64 + lane * 4) = raw;
  float d = a.x * a.x + a.y * a.y + a.z * a.z + a.w * a.w;
  d += __shfl_xor(d, 1); d += __shfl_xor(d, 2);
  d += __shfl_xor(d, 4); d += __shfl_xor(d, 8);
  float r = 1.0f / fmaxf(sqrtf(d), 1e-12f);
  ushort4 o;
  o.x = f2b(a.x * r); o.y = f2b(a.y * r); o.z = f2b(a.z * r); o.w = f2b(a.w * r);
  *(ushort4*)(anb + (size_t)g * 64 + lane * 4) = o;
}

// ---- fused layer-0 aggregate + gate (1 wave / node, 16 neighbors / iter) ----
__device__ __forceinline__ void agg_gate_body(int bid, const ushort* __restrict__ h,
                                              const ushort* __restrict__ anb,
                                              const int* __restrict__ rowptr,
                                              const int* __restrict__ rowend,
                                              const int* __restrict__ csr,
                                              const float* __restrict__ temp,
                                              float* __restrict__ gout,
                                              ushort* __restrict__ outb, int n) {
  int g = bid * 4 + (threadIdx.x >> 6);  // 1 wave per node
  if (g >= n) return;
  const int l = threadIdx.x & 63;
  const int js = l >> 4;   // neighbor slot 0..3
  const int c = l & 15;    // 16B chunk of the 256B h row / 8B chunk of anb row
  int beg = rowptr[g], end = rowend[g];
  int deg = end - beg;
  uint2 av = *(const uint2*)(anb + (size_t)g * 64 + c * 4);
  float av0 = blo(av.x), av1 = bhi(av.x), av2 = blo(av.y), av3 = bhi(av.y);
  float a0=0,a1=0,a2=0,a3=0,a4=0,a5=0,a6=0,a7=0;
  float dot = 0.f;
  int j = beg;
  int jend = beg + (deg & ~15);
  for (; j < jend; j += 16) {
    int u0 = csr[j + js];
    int u1 = csr[j + js + 4];
    int u2 = csr[j + js + 8];
    int u3 = csr[j + js + 12];
    uint4 v0 = *(const uint4*)(h + (size_t)u0 * HID + c * 8);
    uint4 v1 = *(const uint4*)(h + (size_t)u1 * HID + c * 8);
    uint4 v2 = *(const uint4*)(h + (size_t)u2 * HID + c * 8);
    uint4 v3 = *(const uint4*)(h + (size_t)u3 * HID + c * 8);
    uint2 w0 = *(const uint2*)(anb + (size_t)u0 * 64 + c * 4);
    uint2 w1 = *(const uint2*)(anb + (size_t)u1 * 64 + c * 4);
    uint2 w2 = *(const uint2*)(anb + (size_t)u2 * 64 + c * 4);
    uint2 w3 = *(const uint2*)(anb + (size_t)u3 * 64 + c * 4);
    a0 += (blo(v0.x) + blo(v1.x)) + (blo(v2.x) + blo(v3.x));
    a1 += (bhi(v0.x) + bhi(v1.x)) + (bhi(v2.x) + bhi(v3.x));
    a2 += (blo(v0.y) + blo(v1.y)) + (blo(v2.y) + blo(v3.y));
    a3 += (bhi(v0.y) + bhi(v1.y)) + (bhi(v2.y) + bhi(v3.y));
    a4 += (blo(v0.z) + blo(v1.z)) + (blo(v2.z) + blo(v3.z));
    a5 += (bhi(v0.z) + bhi(v1.z)) + (bhi(v2.z) + bhi(v3.z));
    a6 += (blo(v0.w) + blo(v1.w)) + (blo(v2.w) + blo(v3.w));
    a7 += (bhi(v0.w) + bhi(v1.w)) + (bhi(v2.w) + bhi(v3.w));
    dot += av0 * ((blo(w0.x) + blo(w1.x)) + (blo(w2.x) + blo(w3.x)))
         + av1 * ((bhi(w0.x) + bhi(w1.x)) + (bhi(w2.x) + bhi(w3.x)))
         + av2 * ((blo(w0.y) + blo(w1.y)) + (blo(w2.y) + blo(w3.y)))
         + av3 * ((bhi(w0.y) + bhi(w1.y)) + (bhi(w2.y) + bhi(w3.y)));
  }
  int rem = end - j;  // 0..15
  if (js < rem) {
    int u0 = csr[j + js];
    uint4 v0 = *(const uint4*)(h + (size_t)u0 * HID + c * 8);
    uint2 w0 = *(const uint2*)(anb + (size_t)u0 * 64 + c * 4);
    a0 += blo(v0.x); a1 += bhi(v0.x); a2 += blo(v0.y); a3 += bhi(v0.y);
    a4 += blo(v0.z); a5 += bhi(v0.z); a6 += blo(v0.w); a7 += bhi(v0.w);
    dot += av0 * blo(w0.x) + av1 * bhi(w0.x) + av2 * blo(w0.y) + av3 * bhi(w0.y);
  }
  if (js + 4 < rem) {
    int u0 = csr[j + js + 4];
    uint4 v0 = *(const uint4*)(h + (size_t)u0 * HID + c * 8);
    uint2 w0 = *(const uint2*)(anb + (size_t)u0 * 64 + c * 4);
    a0 += blo(v0.x); a1 += bhi(v0.x); a2 += blo(v0.y); a3 += bhi(v0.y);
    a4 += blo(v0.z); a5 += bhi(v0.z); a6 += blo(v0.w); a7 += bhi(v0.w);
    dot += av0 * blo(w0.x) + av1 * bhi(w0.x) + av2 * blo(w0.y) + av3 * bhi(w0.y);
  }
  if (js + 8 < rem) {
    int u0 = csr[j + js + 8];
    uint4 v0 = *(const uint4*)(h + (size_t)u0 * HID + c * 8);
    uint2 w0 = *(const uint2*)(anb + (size_t)u0 * 64 + c * 4);
    a0 += blo(v0.x); a1 += bhi(v0.x); a2 += blo(v0.y); a3 += bhi(v0.y);
    a4 += blo(v0.z); a5 += bhi(v0.z); a6 += blo(v0.w); a7 += bhi(v0.w);
    dot += av0 * blo(w0.x) + av1 * bhi(w0.x) + av2 * blo(w0.y) + av3 * bhi(w0.y);
  }
  if (js + 12 < rem) {
    int u0 = csr[j + js + 12];
    uint4 v0 = *(const uint4*)(h + (size_t)u0 * HID + c * 8);
    uint2 w0 = *(const uint2*)(anb + (size_t)u0 * 64 + c * 4);
    a0 += blo(v0.x); a1 += bhi(v0.x); a2 += blo(v0.y); a3 += bhi(v0.y);
    a4 += blo(v0.z); a5 += bhi(v0.z); a6 += blo(v0.w); a7 += bhi(v0.w);
    dot += av0 * blo(w0.x) + av1 * bhi(w0.x) + av2 * blo(w0.y) + av3 * bhi(w0.y);
  }
  a0 += __shfl_xor(a0, 16); a0 += __shfl_xor(a0, 32);
  a1 += __shfl_xor(a1, 16); a1 += __shfl_xor(a1, 32);
  a2 += __shfl_xor(a2, 16); a2 += __shfl_xor(a2, 32);
  a3 += __shfl_xor(a3, 16); a3 += __shfl_xor(a3, 32);
  a4 += __shfl_xor(a4, 16); a4 += __shfl_xor(a4, 32);
  a5 += __shfl_xor(a5, 16); a5 += __shfl_xor(a5, 32);
  a6 += __shfl_xor(a6, 16); a6 += __shfl_xor(a6, 32);
  a7 += __shfl_xor(a7, 16); a7 += __shfl_xor(a7, 32);
  dot += __shfl_xor(dot, 1); dot += __shfl_xor(dot, 2);
  dot += __shfl_xor(dot, 4); dot += __shfl_xor(dot, 8);
  dot += __shfl_xor(dot, 16); dot += __shfl_xor(dot, 32);
  if (l < 16) {
    float r = (deg > 0) ? 1.0f / (float)deg : 0.0f;
    uint4 o;
    o.x = pack2(a0 * r, a1 * r); o.y = pack2(a2 * r, a3 * r);
    o.z = pack2(a4 * r, a5 * r); o.w = pack2(a6 * r, a7 * r);
    *(uint4*)(outb + (size_t)g * HID + c * 8) = o;
  }
  if (l == 0) {
    float m = (1.0f + dot) / (float)(deg + 1);  // self-loop dot = 1
    gout[g] = 1.0f / (1.0f + expf(-temp[0] * m));
  }
}

// ---- SAGE mean aggregation (1 wave / node, 16 neighbors / iter) ----
__device__ __forceinline__ void agg_b_body(int bid, int goff, const ushort* __restrict__ h,
                                           const int* __restrict__ rowptr,
                                           const int* __restrict__ rowend,
                                           const int* __restrict__ csr,
                                           ushort* __restrict__ outb, int n) {
  int g = goff + bid * 4 + (threadIdx.x >> 6);
  if (g >= n) return;
  const int l = threadIdx.x & 63;
  const int js = l >> 4;
  const int c = l & 15;
  int beg = rowptr[g], end = rowend[g];
  int deg = end - beg;
  float a0=0,a1=0,a2=0,a3=0,a4=0,a5=0,a6=0,a7=0;
  int j = beg;
  int jend = beg + (deg & ~15);
  for (; j < jend; j += 16) {
    int u0 = csr[j + js];
    int u1 = csr[j + js + 4];
    int u2 = csr[j + js + 8];
    int u3 = csr[j + js + 12];
    uint4 v0 = *(const uint4*)(h + (size_t)u0 * HID + c * 8);
    uint4 v1 = *(const uint4*)(h + (size_t)u1 * HID + c * 8);
    uint4 v2 = *(const uint4*)(h + (size_t)u2 * HID + c * 8);
    uint4 v3 = *(const uint4*)(h + (size_t)u3 * HID + c * 8);
    a0 += (blo(v0.x) + blo(v1.x)) + (blo(v2.x) + blo(v3.x));
    a1 += (bhi(v0.x) + bhi(v1.x)) + (bhi(v2.x) + bhi(v3.x));
    a2 += (blo(v0.y) + blo(v1.y)) + (blo(v2.y) + blo(v3.y));
    a3 += (bhi(v0.y) + bhi(v1.y)) + (bhi(v2.y) + bhi(v3.y));
    a4 += (blo(v0.z) + blo(v1.z)) + (blo(v2.z) + blo(v3.z));
    a5 += (bhi(v0.z) + bhi(v1.z)) + (bhi(v2.z) + bhi(v3.z));
    a6 += (blo(v0.w) + blo(v1.w)) + (blo(v2.w) + blo(v3.w));
    a7 += (bhi(v0.w) + bhi(v1.w)) + (bhi(v2.w) + bhi(v3.w));
  }
  int rem = end - j;  // 0..15
  if (js < rem) {
    int u0 = csr[j + js];
    uint4 v0 = *(const uint4*)(h + (size_t)u0 * HID + c * 8);
    a0 += blo(v0.x); a1 += bhi(v0.x); a2 += blo(v0.y); a3 += bhi(v0.y);
    a4 += blo(v0.z); a5 += bhi(v0.z); a6 += blo(v0.w); a7 += bhi(v0.w);
  }
  if (js + 4 < rem) {
    int u0 = csr[j + js + 4];
    uint4 v0 = *(const uint4*)(h + (size_t)u0 * HID + c * 8);
    a0 += blo(v0.x); a1 += bhi(v0.x); a2 += blo(v0.y); a3 += bhi(v0.y);
    a4 += blo(v0.z); a5 += bhi(v0.z); a6 += blo(v0.w); a7 += bhi(v0.w);
  }
  if (js + 8 < rem) {
    int u0 = csr[j + js + 8];
    uint4 v0 = *(const uint4*)(h + (size_t)u0 * HID + c * 8);
    a0 += blo(v0.x); a1 += bhi(v0.x); a2 += blo(v0.y); a3 += bhi(v0.y);
    a4 += blo(v0.z); a5 += bhi(v0.z); a6 += blo(v0.w); a7 += bhi(v0.w);
  }
  if (js + 12 < rem) {
    int u0 = csr[j + js + 12];
    uint4 v0 = *(const uint4*)(h + (size_t)u0 * HID + c * 8);
    a0 += blo(v0.x); a1 += bhi(v0.x); a2 += blo(v0.y); a3 += bhi(v0.y);
    a4 += blo(v0.z); a5 += bhi(v0.z); a6 += blo(v0.w); a7 += bhi(v0.w);
  }
  a0 += __shfl_xor(a0, 16); a0 += __shfl_xor(a0, 32);
  a1 += __shfl_xor(a1, 16); a1 += __shfl_xor(a1, 32);
  a2 += __shfl_xor(a2, 16); a2 += __shfl_xor(a2, 32);
  a3 += __shfl_xor(a3, 16); a3 += __shfl_xor(a3, 32);
  a4 += __shfl_xor(a4, 16); a4 += __shfl_xor(a4, 32);
  a5 += __shfl_xor(a5, 16); a5 += __shfl_xor(a5, 32);
  a6 += __shfl_xor(a6, 16); a6 += __shfl_xor(a6, 32);
  a7 += __shfl_xor(a7, 16); a7 += __shfl_xor(a7, 32);
  if (l < 16) {
    float r = (deg > 0) ? 1.0f / (float)deg : 0.0f;
    uint4 o;
    o.x = pack2(a0 * r, a1 * r); o.y = pack2(a2 * r, a3 * r);
    o.z = pack2(a4 * r, a5 * r); o.w = pack2(a6 * r, a7 * r);
    *(uint4*)(outb + (size_t)g * HID + c * 8) = o;
  }
}

// ---- MFMA linear body: C = A1@W1^T (+ A2@W2^T) + bias, bf16 in/out ----
// stats buffer is 8-way replicated (bid&7).
template <int NPARTS, bool STATS, bool ORELU>
__device__ __forceinline__ void mlin_body(
    int bid, const ushort* __restrict__ A1, const ushort* __restrict__ A2, int K,
    const ushort* __restrict__ W1, const ushort* __restrict__ W2,
    const float* __restrict__ bias, ushort* __restrict__ C,
    float* __restrict__ stats, int M, ushort* As, ushort* Bs) {
  const int tid = threadIdx.x;
  const int w = tid >> 6, l = tid & 63;
  const int mbase = bid * 128;
  const int lm = l & 15, lq = l >> 4;
  floatx4 acc[2][8];
#pragma unroll
  for (int mt = 0; mt < 2; ++mt)
#pragma unroll
    for (int nt = 0; nt < 8; ++nt) {
      floatx4 z = {0.f, 0.f, 0.f, 0.f};
      acc[mt][nt] = z;
    }

  for (int part = 0; part < NPARTS; ++part) {
    const ushort* Ap = part ? A2 : A1;
    const ushort* Wp = part ? W2 : W1;
    for (int k0 = 0; k0 < K; k0 += 32) {
#pragma unroll
      for (int i = 0; i < 2; ++i) {
        int s = w * 2 + i;
        int rt = s * 16 + (l >> 2);
        int q = (l & 3) ^ ((rt >> 1) & 3);
        int grow = mbase + rt; grow = grow < M ? grow : M - 1;
        async_cp16(Ap + (size_t)grow * K + k0 + q * 8, &As[s * 512]);
        async_cp16(Wp + (size_t)rt * K + k0 + q * 8, &Bs[s * 512]);
      }
      __syncthreads();
      short8 b[8];
#pragma unroll
      for (int nt = 0; nt < 8; ++nt) {
        int row = nt * 16 + lm;
        int q = lq ^ ((row >> 1) & 3);
        b[nt] = *(const short8*)&Bs[row * 32 + q * 8];
      }
#pragma unroll
      for (int mt = 0; mt < 2; ++mt) {
        int row = (w * 2 + mt) * 16 + lm;
        int q = lq ^ ((row >> 1) & 3);
        short8 a = *(const short8*)&As[row * 32 + q * 8];
#pragma unroll
        for (int nt = 0; nt < 8; ++nt)
          acc[mt][nt] = __builtin_amdgcn_mfma_f32_16x16x32_bf16(a, b[nt], acc[mt][nt], 0, 0, 0);
      }
      __syncthreads();
    }
  }

  float ss[8], qq[8];
#pragma unroll
  for (int nt = 0; nt < 8; ++nt) { ss[nt] = 0.f; qq[nt] = 0.f; }
#pragma unroll
  for (int nt = 0; nt < 8; ++nt) {
    int col = nt * 16 + lm;
    float bv = bias[col];
#pragma unroll
    for (int mt = 0; mt < 2; ++mt) {
      int rbase = mbase + (w * 2 + mt) * 16 + lq * 4;
#pragma unroll
      for (int r = 0; r < 4; ++r) {
        int grow = rbase + r;
        if (grow < M) {
          float val = acc[mt][nt][r] + bv;
          if (ORELU) val = fmaxf(val, 0.f);
          C[(size_t)grow * 128 + col] = f2b(val);
          if (STATS) { ss[nt] += val; qq[nt] += val * val; }
        }
      }
    }
  }
  if (STATS) {
    float* sred = (float*)As;
    if (tid < 256) sred[tid] = 0.f;
    __syncthreads();
#pragma unroll
    for (int nt = 0; nt < 8; ++nt) {
      ss[nt] += __shfl_xor(ss[nt], 16); ss[nt] += __shfl_xor(ss[nt], 32);
      qq[nt] += __shfl_xor(qq[nt], 16); qq[nt] += __shfl_xor(qq[nt], 32);
    }
    if (lq == 0) {
#pragma unroll
      for (int nt = 0; nt < 8; ++nt) {
        int col = nt * 16 + lm;
        atomicAdd(&sred[col], ss[nt]);
        atomicAdd(&sred[128 + col], qq[nt]);
      }
    }
    __syncthreads();
    float* sbase = stats + ((bid & 7) << 8);
    if (tid < 256) atomicAdd(&sbase[tid], sred[tid]);
  }
}

// ---- BatchNorm apply body (bf16 in-place; sums 8 stats replicas) ----
template <int ACT>  // 0=relu, 1=sigmoid
__device__ __forceinline__ void bnb_body(int bid, int gB, ushort* __restrict__ buf,
                                         const float* __restrict__ stats,
                                         const float* __restrict__ gamma,
                                         const float* __restrict__ beta, int n) {
  const int S = gB * 256;
  int idx = bid * 256 + threadIdx.x;
  const int c0 = (idx & 15) * 8;
  const float inv_n = 1.0f / (float)n;
  float sc[8], sh[8];
#pragma unroll
  for (int d = 0; d < 8; ++d) {
    int c = c0 + d;
    float s0 = 0.f, s1 = 0.f;
#pragma unroll
    for (int r2 = 0; r2 < 8; ++r2) {
      s0 += stats[(r2 << 8) + c];
      s1 += stats[(r2 << 8) + 128 + c];
    }
    float mu = s0 * inv_n;
    float var = s1 * inv_n - mu * mu;
    float s = rsqrtf(var + 1e-5f) * gamma[c];
    sc[d] = s;
    sh[d] = beta[c] - mu * s;
  }
  const int n16 = n * 16;
  for (; idx < n16; idx += S) {
    uint4 v = ((const uint4*)buf)[idx];
    float x[8] = {blo(v.x), bhi(v.x), blo(v.y), bhi(v.y),
                  blo(v.z), bhi(v.z), blo(v.w), bhi(v.w)};
#pragma unroll
    for (int d = 0; d < 8; ++d) {
      float y = x[d] * sc[d] + sh[d];
      x[d] = (ACT == 0) ? fmaxf(y, 0.f) : 1.0f / (1.0f + expf(-y));
    }
    uint4 o;
    o.x = pack2(x[0], x[1]); o.y = pack2(x[2], x[3]);
    o.z = pack2(x[4], x[5]); o.w = pack2(x[6], x[7]);
    ((uint4*)buf)[idx] = o;
  }
}

// ---- classifier body: MFMA GEMM + fused log_softmax ----
__device__ __forceinline__ void clsm_body(
    int bid, const ushort* __restrict__ A1, const ushort* __restrict__ A2,
    const ushort* __restrict__ Wcb, const float* __restrict__ bias,
    float* __restrict__ C, int M, ushort* As, ushort* Bs) {
  const int tid = threadIdx.x;
  const int w = tid >> 6, l = tid & 63;
  const int mbase = bid * 128;
  const int lm = l & 15, lq = l >> 4;
  floatx4 acc[2][3];
#pragma unroll
  for (int mt = 0; mt < 2; ++mt)
#pragma unroll
    for (int nt = 0; nt < 3; ++nt) {
      floatx4 z = {0.f, 0.f, 0.f, 0.f};
      acc[mt][nt] = z;
    }

  for (int part = 0; part < 2; ++part) {
    const ushort* Ap = part ? A2 : A1;
    for (int k0 = 0; k0 < 128; k0 += 32) {
#pragma unroll
      for (int i = 0; i < 2; ++i) {
        int s = w * 2 + i;
        int rt = s * 16 + (l >> 2);
        int q = (l & 3) ^ ((rt >> 1) & 3);
        int grow = mbase + rt; grow = grow < M ? grow : M - 1;
        async_cp16(Ap + (size_t)grow * 128 + k0 + q * 8, &As[s * 512]);
      }
      if (w < 3) {
        int rt = w * 16 + (l >> 2);
        int q = (l & 3) ^ ((rt >> 1) & 3);
        async_cp16(Wcb + (size_t)rt * 256 + part * 128 + k0 + q * 8, &Bs[w * 512]);
      }
      __syncthreads();
      short8 b[3];
#pragma unroll
      for (int nt = 0; nt < 3; ++nt) {
        int row = nt * 16 + lm;
        int q = lq ^ ((row >> 1) & 3);
        b[nt] = *(const short8*)&Bs[row * 32 + q * 8];
      }
#pragma unroll
      for (int mt = 0; mt < 2; ++mt) {
        int row = (w * 2 + mt) * 16 + lm;
        int q = lq ^ ((row >> 1) & 3);
        short8 a = *(const short8*)&As[row * 32 + q * 8];
#pragma unroll
        for (int nt = 0; nt < 3; ++nt)
          acc[mt][nt] = __builtin_amdgcn_mfma_f32_16x16x32_bf16(a, b[nt], acc[mt][nt], 0, 0, 0);
      }
      __syncthreads();
    }
  }

  float b0v = bias[lm], b1v = bias[lm + 16];
  float b2v = (lm < 8) ? bias[lm + 32] : 0.f;
#pragma unroll
  for (int mt = 0; mt < 2; ++mt) {
#pragma unroll
    for (int r = 0; r < 4; ++r) {
      int grow = mbase + (w * 2 + mt) * 16 + lq * 4 + r;
      float v0 = acc[mt][0][r] + b0v;
      float v1 = acc[mt][1][r] + b1v;
      float v2 = (lm < 8) ? acc[mt][2][r] + b2v : -3.4e38f;
      float m = fmaxf(fmaxf(v0, v1), v2);
      m = fmaxf(m, __shfl_xor(m, 1)); m = fmaxf(m, __shfl_xor(m, 2));
      m = fmaxf(m, __shfl_xor(m, 4)); m = fmaxf(m, __shfl_xor(m, 8));
      float s = expf(v0 - m) + expf(v1 - m) + ((lm < 8) ? expf(v2 - m) : 0.f);
      s += __shfl_xor(s, 1); s += __shfl_xor(s, 2);
      s += __shfl_xor(s, 4); s += __shfl_xor(s, 8);
      float ls = m + logf(s);
      if (grow < M) {
        C[(size_t)grow * OUTC + lm] = v0 - ls;
        C[(size_t)grow * OUTC + lm + 16] = v1 - ls;
        if (lm < 8) C[(size_t)grow * OUTC + lm + 32] = v2 - ls;
      }
    }
  }
}

// ================= global kernels =================

// prep (cvtw | cvt | anorm2), one launch
__global__ void prep_kernel(
    const float* __restrict__ x, ushort* __restrict__ xb, int n4,
    const float* __restrict__ alpha, ushort* __restrict__ ab, ushort* __restrict__ anb, int n,
    const float* __restrict__ Wl, const float* __restrict__ Wr, const float* __restrict__ W0,
    const float* __restrict__ W1, const float* __restrict__ W2, const float* __restrict__ Wc,
    ushort* __restrict__ wb, ushort* __restrict__ wcb, float* __restrict__ stats,
    int* __restrict__ gcnt, int GW, int GC) {
  int b = blockIdx.x;
  if (b < GW) cvtw_body(b, Wl, Wr, W0, W1, W2, Wc, wb, wcb, stats, gcnt);
  else if (b < GW + GC) cvt_body(b - GW, x, xb, n4);
  else anorm2_body(b - GW - GC, alpha, ab, anb, n);
}

// ---------------- bucketed CSR build (atomic range reservation, no scans) ----
// ebuf/csr are bucketed with fixed capacity `cap` per 512-node bucket; per-node
// extents live in rowptr[] (begin) and rowend[] (end). Gaps between buckets.

__device__ __forceinline__ void binAB_body(int bid, const int* __restrict__ src,
                                           const int* __restrict__ tgt,
                                           int* __restrict__ gcnt,
                                           int* __restrict__ ebuf,
                                           int e, int chunk, int nbk, int cap) {
  __shared__ int hist[NBK_MAX];
  int tid = threadIdx.x;
  for (int b = tid; b < nbk; b += 256) hist[b] = 0;
  __syncthreads();
  int i0 = bid * chunk;
  int i1 = min(e, i0 + chunk);
  for (int j = i0 + tid; j < i1; j += 256) atomicAdd(&hist[tgt[j] >> 9], 1);
  __syncthreads();
  // reserve a contiguous range in each bucket for this block's edges
  for (int b = tid; b < nbk; b += 256) {
    int c = hist[b];
    hist[b] = c ? atomicAdd(&gcnt[b], c) : 0;
  }
  __syncthreads();
  for (int j = i0 + tid; j < i1; j += 256) {
    int t = tgt[j];
    int b = t >> 9;
    int pos = atomicAdd(&hist[b], 1);
    if (pos < cap) ebuf[(size_t)b * cap + pos] = ((t & 511) << 17) | src[j];
  }
}

// binAB (blocks [0,PB)) || proto W0 GEMM (rest). Disjoint data; binAB is
// grid-limited (200 blocks) so W0 rides nearly free.
__global__ __launch_bounds__(256) void k_binAB_w0(
    const int* __restrict__ src, const int* __restrict__ tgt,
    int* __restrict__ gcnt, int* __restrict__ ebuf, int e, int chunk, int nbk, int cap,
    const ushort* __restrict__ ab, const ushort* __restrict__ W0b,
    const float* __restrict__ b0, ushort* __restrict__ hproto,
    float* __restrict__ stats, int n) {
  __shared__ ushort As[4096];
  __shared__ ushort Bs[4096];
  if ((int)blockIdx.x < PB)
    binAB_body(blockIdx.x, src, tgt, gcnt, ebuf, e, chunk, nbk, cap);
  else
    mlin_body<1, true, false>(blockIdx.x - PB, ab, nullptr, 64, W0b, nullptr, b0,
                              hproto, stats, n, As, Bs);
}

__global__ void binC_kernel(const int* __restrict__ ebuf, const int* __restrict__ gcnt,
                            int* __restrict__ rowptr, int* __restrict__ rowend,
                            int* __restrict__ csr, int n, int cap, int nbk) {
  __shared__ int hist[512];
  __shared__ int scanbuf[256];
  int b = blockIdx.x, tid = threadIdx.x;
  int seg0 = b * cap;
  int cnt = gcnt[b]; if (cnt > cap) cnt = cap;
  int seg1 = seg0 + cnt;
  hist[tid] = 0; hist[tid + 256] = 0;
  __syncthreads();
  for (int j = seg0 + tid; j < seg1; j += 256)
    atomicAdd(&hist[ebuf[j] >> 17], 1);
  __syncthreads();
  int a0 = hist[2 * tid], a1 = hist[2 * tid + 1];
  int s = a0 + a1;
  scanbuf[tid] = s;
  __syncthreads();
  for (int d = 1; d < 256; d <<= 1) {
    int add = (tid >= d) ? scanbuf[tid - d] : 0;
    __syncthreads();
    scanbuf[tid] += add;
    __syncthreads();
  }
  int ex = scanbuf[tid] - s;
  hist[2 * tid] = ex;
  hist[2 * tid + 1] = ex + a0;
  int node0 = b * 512 + 2 * tid;
  if (node0 < n) { rowptr[node0] = seg0 + ex; rowend[node0] = seg0 + ex + a0; }
  if (node0 + 1 < n) { rowptr[node0 + 1] = seg0 + ex + a0; rowend[node0 + 1] = seg0 + ex + a0 + a1; }
  __syncthreads();
  for (int j = seg0 + tid; j < seg1; j += 256) {
    int val = ebuf[j];
    int pos = atomicAdd(&hist[val >> 17], 1);
    csr[seg0 + pos] = val & 0x1FFFF;
  }
}

// ---------------- pure aggregation kernels (VGPR capped at 64) ----------------

__global__ __launch_bounds__(256, 8) void agg_gate_kernel(
    const ushort* __restrict__ h, const ushort* __restrict__ anb,
    const int* __restrict__ rowptr, const int* __restrict__ rowend,
    const int* __restrict__ csr,
    const float* __restrict__ temp, float* __restrict__ gout,
    ushort* __restrict__ outb, int n) {
  agg_gate_body(blockIdx.x, h, anb, rowptr, rowend, csr, temp, gout, outb, n);
}

__global__ __launch_bounds__(256, 8) void agg_b_kernel(
    const ushort* __restrict__ h, const int* __restrict__ rowptr,
    const int* __restrict__ rowend, const int* __restrict__ csr,
    ushort* __restrict__ outb, int goff, int n) {
  agg_b_body(blockIdx.x, goff, h, rowptr, rowend, csr, outb, n);
}

// agg_b (blocks [0,gAgg)) || bnb (trailing) — no mlin, footprint stays small
template <int ACT>
__global__ __launch_bounds__(256, 8) void k_agg_bnb(
    const ushort* __restrict__ h, const int* __restrict__ rowptr,
    const int* __restrict__ rowend, const int* __restrict__ csr,
    ushort* __restrict__ outb, int n, int gAgg,
    ushort* __restrict__ bnbuf, const float* __restrict__ bnstats,
    const float* __restrict__ gamma, const float* __restrict__ beta, int gBn) {
  if ((int)blockIdx.x < gAgg)
    agg_b_body(blockIdx.x, 0, h, rowptr, rowend, csr, outb, n);
  else
    bnb_body<ACT>(blockIdx.x - gAgg, gBn, bnbuf, bnstats, gamma, beta, n);
}

// ---------------- combined launches (same-footprint roles only) --------------

// mlin (blocks [0,gLin)) || bnb (rest)
template <int NP, bool ST, bool OR_, int ACT>
__global__ __launch_bounds__(256) void k_mlin_bnb(
    const ushort* __restrict__ A1, const ushort* __restrict__ A2, int K,
    const ushort* __restrict__ W1, const ushort* __restrict__ W2,
    const float* __restrict__ bias, ushort* __restrict__ C, float* __restrict__ stats,
    ushort* __restrict__ bnbuf, const float* __restrict__ bnstats,
    const float* __restrict__ gamma, const float* __restrict__ beta,
    int M, int gLin, int gBn) {
  __shared__ ushort As[4096];
  __shared__ ushort Bs[4096];
  if ((int)blockIdx.x < gLin)
    mlin_body<NP, ST, OR_>(blockIdx.x, A1, A2, K, W1, W2, bias, C, stats, M, As, Bs);
  else
    bnb_body<ACT>(blockIdx.x - gLin, gBn, bnbuf, bnstats, gamma, beta, M);
}

// SAGE mlin (blocks [0,gLin)) || proto mlin (rest)
__global__ __launch_bounds__(256) void k_mlin_mlin(
    const ushort* __restrict__ A1a, const ushort* __restrict__ A2a,
    const ushort* __restrict__ W1a, const ushort* __restrict__ W2a,
    const float* __restrict__ ba, ushort* __restrict__ Ca, float* __restrict__ statsa,
    const ushort* __restrict__ A1b, const ushort* __restrict__ W1b,
    const float* __restrict__ bb, ushort* __restrict__ Cb, int M, int gLin) {
  __shared__ ushort As[4096];
  __shared__ ushort Bs[4096];
  if ((int)blockIdx.x < gLin)
    mlin_body<2, true, false>(blockIdx.x, A1a, A2a, 128, W1a, W2a, ba, Ca, statsa, M, As, Bs);
  else
    mlin_body<1, false, true>(blockIdx.x - gLin, A1b, nullptr, 128, W1b, nullptr, bb, Cb,
                              nullptr, M, As, Bs);
}

// SAGE GEMM2 rows-half2 (blocks [0,nM), rows offset moff) || clsm rows-half1 (rest)
__global__ __launch_bounds__(256) void k_mlin_clsm(
    const ushort* __restrict__ A1, const ushort* __restrict__ A2,
    const ushort* __restrict__ W1, const ushort* __restrict__ W2,
    const float* __restrict__ bias, ushort* __restrict__ C, int moff, int nM,
    const ushort* __restrict__ cA1, const ushort* __restrict__ cA2,
    const ushort* __restrict__ Wcb, const float* __restrict__ cbias,
    float* __restrict__ Cout, int M) {
  __shared__ ushort As[4096];
  __shared__ ushort Bs[4096];
  if ((int)blockIdx.x < nM)
    mlin_body<2, false, true>(blockIdx.x + moff, A1, A2, 128, W1, W2, bias, C,
                              nullptr, M, As, Bs);
  else
    clsm_body(blockIdx.x - nM, cA1, cA2, Wcb, cbias, Cout, M, As, Bs);
}

// ---------------- standalone kernels ----------------

template <int NPARTS, bool STATS, bool ORELU>
__global__ __launch_bounds__(256) void mlin_kernel(
    const ushort* __restrict__ A1, const ushort* __restrict__ A2, int K,
    const ushort* __restrict__ W1, const ushort* __restrict__ W2,
    const float* __restrict__ bias, ushort* __restrict__ C,
    float* __restrict__ stats, int M) {
  __shared__ ushort As[4096];
  __shared__ ushort Bs[4096];
  mlin_body<NPARTS, STATS, ORELU>(blockIdx.x, A1, A2, K, W1, W2, bias, C, stats, M, As, Bs);
}

template <int ACT>
__global__ __launch_bounds__(256) void bnb_kernel(
    ushort* __restrict__ buf, const float* __restrict__ stats,
    const float* __restrict__ gamma, const float* __restrict__ beta, int n) {
  bnb_body<ACT>(blockIdx.x, gridDim.x, buf, stats, gamma, beta, n);
}

__global__ __launch_bounds__(256) void clsm_kernel(
    const ushort* __restrict__ A1, const ushort* __restrict__ A2,
    const ushort* __restrict__ Wcb, const float* __restrict__ bias,
    float* __restrict__ C, int M, int boff) {
  __shared__ ushort As[4096];
  __shared__ ushort Bs[4096];
  clsm_body(blockIdx.x + boff, A1, A2, Wcb, bias, C, M, As, Bs);
}

// ---------------- launch ----------------

extern "C" void kernel_launch(void* const* d_in, const int* in_sizes, int n_in,
                              void* d_out, int out_size, void* d_ws, size_t ws_size,
                              hipStream_t stream) {
  const float* x       = (const float*)d_in[0];
  const float* alpha   = (const float*)d_in[1];
  const int*   eidx    = (const int*)d_in[2];
  const float* sage_Wl = (const float*)d_in[3];
  const float* sage_bl = (const float*)d_in[4];
  const float* sage_Wr = (const float*)d_in[5];
  const float* sage_g  = (const float*)d_in[6];
  const float* sage_b  = (const float*)d_in[7];
  const float* W0 = (const float*)d_in[8];
  const float* b0 = (const float*)d_in[9];
  const float* W1 = (const float*)d_in[10];
  const float* b1 = (const float*)d_in[11];
  const float* W2 = (const float*)d_in[12];
  const float* b2 = (const float*)d_in[13];
  const float* mg = (const float*)d_in[14];
  const float* mb = (const float*)d_in[15];
  const float* Wc = (const float*)d_in[16];
  const float* bc = (const float*)d_in[17];
  const float* temp = (const float*)d_in[18];
  float* out = (float*)d_out;

  const int n = in_sizes[0] / HID;  // 100000
  const int e = in_sizes[2] / 2;    // 1600000
  const int* src = eidx;
  const int* tgt = eidx + e;

  const int nbk = (n + 511) >> 9;
  const int chunk = (e + PB - 1) / PB;
  // bucket capacity: 1.5x mean, rounded up to 64 (45-sigma slack for random graphs)
  const int cap = (int)((((long long)e * 512 / n) * 3 / 2 + 63) & ~63LL);

  // workspace layout: 4 N×128 bf16 regions (16B aligned)
  // ebuf (bucketed, nbk*cap ints) lives in B2 (dead until agg1 writes it);
  // hproto (B3) is free from the start so W0 can overlap the CSR build.
  char* p = (char*)d_ws;
  ushort* B0 = (ushort*)p; p += (size_t)n * HID * 2;
  ushort* B1 = (ushort*)p; p += (size_t)n * HID * 2;
  ushort* B2 = (ushort*)p; p += (size_t)n * HID * 2;
  ushort* B3 = (ushort*)p; p += (size_t)n * HID * 2;
  ushort* wb     = (ushort*)p; p += (size_t)WTOT * 2;
  ushort* wcb    = (ushort*)p; p += (size_t)48 * 256 * 2;
  float* stats = (float*)p; p += 8192 * 4;  // 4 sets x 8 replicas x 256 floats
  int* gcnt   = (int*)p; p += NBK_MAX * 4;
  int* rowptr = (int*)p; p += (size_t)n * 4;
  int* rowend = (int*)p; p += (size_t)n * 4;
  int* csr    = (int*)p; p += (size_t)nbk * cap * 4;
  ushort* xb   = B0;
  ushort* anb  = B1;                       // N*64
  ushort* ab   = B1 + (size_t)n * 64;      // N*64
  ushort* hgnn = B1;                       // SAGE L2 out (B1 dead by then)
  int*    ebuf = (int*)B2;                 // nbk*cap*4 <= n*256; dead after binC
  ushort* hproto = B3;
  ushort* Wlb = wb, *Wrb = wb + 49152, *W0b = wb + 98304, *W1b = wb + 106496, *W2b = wb + 122880;
  // stats sets (each 2048 floats: 8 replicas x 256)
  float* stSage0 = stats;
  float* stSage1 = stats + 2048;
  float* stPr0   = stats + 4096;
  float* stPr1   = stats + 6144;

  const int T = 256;

  const int gLin = (n + 127) / 128;        // 782
  const int gHalf = (gLin + 1) / 2;        // 391
  const int gLin2 = gLin - gHalf;          // 391
  const int gBn = 1024;
  const int gAgg = (n + 3) >> 2;           // 25000 (1 wave/node, 4/block)
  const int GW = WTOT / 4 / T;             // 136 blocks (exact)
  const int GC = (n * (HID / 4) + T - 1) / T;          // cvt blocks
  const int GA = (int)(((size_t)n * 16 + T - 1) / T);  // anorm2 blocks

  // 1: prep (weights cvt + x cvt + alpha norm + gcnt zero)
  prep_kernel<<<GW + GC + GA, T, 0, stream>>>(
      x, xb, n * (HID / 4), alpha, ab, anb, n,
      sage_Wl, sage_Wr, W0, W1, W2, Wc, wb, wcb, stats, gcnt, GW, GC);

  // 2: binAB (hist + atomic range reservation + scatter) || proto W0 GEMM
  k_binAB_w0<<<PB + gLin, T, 0, stream>>>(src, tgt, gcnt, ebuf, e, chunk, nbk, cap,
                                          ab, W0b, b0, hproto, stPr0, n);

  // 3: binC (per-bucket sort into csr; writes rowptr/rowend)
  binC_kernel<<<nbk, T, 0, stream>>>(ebuf, gcnt, rowptr, rowend, csr, n, cap, nbk);

  // 4: L0 aggregate + gate (pure, 16-deep, VGPR<=64)
  agg_gate_kernel<<<gAgg, T, 0, stream>>>(xb, anb, rowptr, rowend, csr, temp,
                                          out + (size_t)n * OUTC, B2, n);

  // 5: SAGE L0 GEMM || proto BN0 (sigmoid)
  k_mlin_bnb<2, true, false, 1><<<gLin + gBn, T, 0, stream>>>(
      B2, B0, 128, Wlb, Wrb, sage_bl, B1, stSage0,
      hproto, stPr0, mg, mb, n, gLin, gBn);

  // 6: proto W1 GEMM || SAGE BN0 (relu)
  k_mlin_bnb<1, true, false, 0><<<gLin + gBn, T, 0, stream>>>(
      hproto, nullptr, 128, W1b, nullptr, b1, hproto, stPr1,
      B1, stSage0, sage_g, sage_b, n, gLin, gBn);

  // 7: SAGE L1 aggregate (pure-footprint) || proto BN1 sigmoid (trailing)
  k_agg_bnb<1><<<gAgg + gBn, T, 0, stream>>>(B1, rowptr, rowend, csr, B2, n, gAgg,
                                             hproto, stPr1, mg + HID, mb + HID, gBn);

  // 8: SAGE L1 GEMM || proto W2 GEMM (relu fused)
  k_mlin_mlin<<<2 * gLin, T, 0, stream>>>(B2, B1, Wlb + 16384, Wrb + 16384,
                                          sage_bl + HID, B0, stSage1,
                                          hproto, W2b, b2, hproto, n, gLin);

  // 9: SAGE BN1 (relu)
  bnb_kernel<0><<<gBn, T, 0, stream>>>(B0, stSage1, sage_g + HID, sage_b + HID, n);

  // 10: SAGE L2 aggregate (pure, full)
  agg_b_kernel<<<gAgg, T, 0, stream>>>(B0, rowptr, rowend, csr, B2, 0, n);

  // 11: SAGE GEMM2 rows-half1
  mlin_kernel<2, false, true><<<gHalf, T, 0, stream>>>(B2, B0, 128, Wlb + 32768,
                                                       Wrb + 32768, sage_bl + 2 * HID,
                                                       hgnn, nullptr, n);

  // 12: SAGE GEMM2 rows-half2 || classifier rows-half1
  k_mlin_clsm<<<gLin2 + gHalf, T, 0, stream>>>(B2, B0, Wlb + 32768, Wrb + 32768,
                                               sage_bl + 2 * HID, hgnn, gHalf, gLin2,
                                               hgnn, hproto, wcb, bc, out, n);

  // 13: classifier rows-half2
  clsm_kernel<<<gLin - gHalf, T, 0, stream>>>(hgnn, hproto, wcb, bc, out, n, gHalf);
}

// Round 10
// 641.536 us; speedup vs baseline: 1.2477x; 1.0357x over previous
//
#include <hip/hip_runtime.h>
#include <cstdint>
#include <cstddef>

#define HID 128
#define OUTC 40
#define WTOT 139264  // Wl 49152 | Wr 49152 | W0 8192 | W1 16384 | W2 16384
#define PBB 1024     // blocks for the edge-binning scatter pass
#define NBK_MAX 256  // max buckets (512 nodes each)

typedef __attribute__((ext_vector_type(8))) short short8;
typedef __attribute__((ext_vector_type(4))) float floatx4;

__device__ __forceinline__ unsigned short f2b(float f) {
  unsigned int u = __float_as_uint(f);
  unsigned int r = u + 0x7FFFu + ((u >> 16) & 1u);
  return (unsigned short)(r >> 16);
}
__device__ __forceinline__ float blo(unsigned int u) { return __uint_as_float(u << 16); }
__device__ __forceinline__ float bhi(unsigned int u) { return __uint_as_float(u & 0xFFFF0000u); }
__device__ __forceinline__ unsigned int pack2(float a, float b) {
  return (unsigned int)f2b(a) | ((unsigned int)f2b(b) << 16);
}

__device__ __forceinline__ void async_cp16(const ushort* g, ushort* l) {
  __builtin_amdgcn_global_load_lds((const __attribute__((address_space(1))) void*)g,
                                   (__attribute__((address_space(3))) void*)l, 16, 0, 0);
}

// ================= device bodies =================

__device__ __forceinline__ void cvt_body(int bid, const float* __restrict__ in,
                                         ushort* __restrict__ out, int n4) {
  int i = bid * 256 + threadIdx.x;
  if (i >= n4) return;
  float4 v = ((const float4*)in)[i];
  ushort4 o;
  o.x = f2b(v.x); o.y = f2b(v.y); o.z = f2b(v.z); o.w = f2b(v.w);
  ((ushort4*)out)[i] = o;
}

__device__ __forceinline__ void cvtw_body(int bid, const float* __restrict__ Wl,
                                          const float* __restrict__ Wr, const float* __restrict__ W0,
                                          const float* __restrict__ W1, const float* __restrict__ W2,
                                          const float* __restrict__ Wc, ushort* __restrict__ wb,
                                          ushort* __restrict__ wcb, float* __restrict__ stats,
                                          int* __restrict__ gcnt) {
  int gid = bid * 256 + threadIdx.x;
  if (gid < 8192) stats[gid] = 0.0f;  // 4 sets x 8 replicas x 256
  if (gid < NBK_MAX) gcnt[gid] = 0;
  if (gid < 48 * 64) {  // wcb: 48x256 bf16, rows 40..47 zero
    int row = gid >> 6;
    ushort4 o;
    if (row < 40) {
      float4 v = *(const float4*)(Wc + (size_t)gid * 4);
      o.x = f2b(v.x); o.y = f2b(v.y); o.z = f2b(v.z); o.w = f2b(v.w);
    } else {
      o.x = 0; o.y = 0; o.z = 0; o.w = 0;
    }
    ((ushort4*)wcb)[gid] = o;
  }
  int e4 = gid * 4;
  if (e4 < WTOT) {
    const float* s; int off;
    if (e4 < 49152)       { s = Wl; off = 0; }
    else if (e4 < 98304)  { s = Wr; off = 49152; }
    else if (e4 < 106496) { s = W0; off = 98304; }
    else if (e4 < 122880) { s = W1; off = 106496; }
    else                  { s = W2; off = 122880; }
    float4 v = *(const float4*)(s + (e4 - off));
    ushort4 o;
    o.x = f2b(v.x); o.y = f2b(v.y); o.z = f2b(v.z); o.w = f2b(v.w);
    *(ushort4*)(wb + e4) = o;
  }
}

__device__ __forceinline__ void anorm2_body(int bid, const float* __restrict__ alpha,
                                            ushort* __restrict__ ab, ushort* __restrict__ anb,
                                            int n) {
  int g = (bid * 256 + threadIdx.x) >> 4;  // 16 lanes/node
  int lane = threadIdx.x & 15;
  if (g >= n) return;
  const float4 a = *(const float4*)(alpha + (size_t)g * 64 + lane * 4);
  ushort4 raw;
  raw.x = f2b(a.x); raw.y = f2b(a.y); raw.z = f2b(a.z); raw.w = f2b(a.w);
  *(ushort4*)(ab + (size_t)g * 64 + lane * 4) = raw;
  float d = a.x * a.x + a.y * a.y + a.z * a.z + a.w * a.w;
  d += __shfl_xor(d, 1); d += __shfl_xor(d, 2);
  d += __shfl_xor(d, 4); d += __shfl_xor(d, 8);
  float r = 1.0f / fmaxf(sqrtf(d), 1e-12f);
  ushort4 o;
  o.x = f2b(a.x * r); o.y = f2b(a.y * r); o.z = f2b(a.z * r); o.w = f2b(a.w * r);
  *(ushort4*)(anb + (size_t)g * 64 + lane * 4) = o;
}

// ---- fused layer-0 aggregate + gate (1 wave / node, 16 neighbors / iter) ----
__device__ __forceinline__ void agg_gate_body(int bid, const ushort* __restrict__ h,
                                              const ushort* __restrict__ anb,
                                              const int* __restrict__ rowptr,
                                              const int* __restrict__ rowend,
                                              const int* __restrict__ csr,
                                              const float* __restrict__ temp,
                                              float* __restrict__ gout,
                                              ushort* __restrict__ outb, int n) {
  int g = bid * 4 + (threadIdx.x >> 6);  // 1 wave per node
  if (g >= n) return;
  const int l = threadIdx.x & 63;
  const int js = l >> 4;   // neighbor slot 0..3
  const int c = l & 15;    // 16B chunk of the 256B h row / 8B chunk of anb row
  int beg = rowptr[g], end = rowend[g];
  int deg = end - beg;
  uint2 av = *(const uint2*)(anb + (size_t)g * 64 + c * 4);
  float av0 = blo(av.x), av1 = bhi(av.x), av2 = blo(av.y), av3 = bhi(av.y);
  float a0=0,a1=0,a2=0,a3=0,a4=0,a5=0,a6=0,a7=0;
  float dot = 0.f;
  int j = beg;
  int jend = beg + (deg & ~15);
  for (; j < jend; j += 16) {
    int u0 = csr[j + js];
    int u1 = csr[j + js + 4];
    int u2 = csr[j + js + 8];
    int u3 = csr[j + js + 12];
    uint4 v0 = *(const uint4*)(h + (size_t)u0 * HID + c * 8);
    uint4 v1 = *(const uint4*)(h + (size_t)u1 * HID + c * 8);
    uint4 v2 = *(const uint4*)(h + (size_t)u2 * HID + c * 8);
    uint4 v3 = *(const uint4*)(h + (size_t)u3 * HID + c * 8);
    uint2 w0 = *(const uint2*)(anb + (size_t)u0 * 64 + c * 4);
    uint2 w1 = *(const uint2*)(anb + (size_t)u1 * 64 + c * 4);
    uint2 w2 = *(const uint2*)(anb + (size_t)u2 * 64 + c * 4);
    uint2 w3 = *(const uint2*)(anb + (size_t)u3 * 64 + c * 4);
    a0 += (blo(v0.x) + blo(v1.x)) + (blo(v2.x) + blo(v3.x));
    a1 += (bhi(v0.x) + bhi(v1.x)) + (bhi(v2.x) + bhi(v3.x));
    a2 += (blo(v0.y) + blo(v1.y)) + (blo(v2.y) + blo(v3.y));
    a3 += (bhi(v0.y) + bhi(v1.y)) + (bhi(v2.y) + bhi(v3.y));
    a4 += (blo(v0.z) + blo(v1.z)) + (blo(v2.z) + blo(v3.z));
    a5 += (bhi(v0.z) + bhi(v1.z)) + (bhi(v2.z) + bhi(v3.z));
    a6 += (blo(v0.w) + blo(v1.w)) + (blo(v2.w) + blo(v3.w));
    a7 += (bhi(v0.w) + bhi(v1.w)) + (bhi(v2.w) + bhi(v3.w));
    dot += av0 * ((blo(w0.x) + blo(w1.x)) + (blo(w2.x) + blo(w3.x)))
         + av1 * ((bhi(w0.x) + bhi(w1.x)) + (bhi(w2.x) + bhi(w3.x)))
         + av2 * ((blo(w0.y) + blo(w1.y)) + (blo(w2.y) + blo(w3.y)))
         + av3 * ((bhi(w0.y) + bhi(w1.y)) + (bhi(w2.y) + bhi(w3.y)));
  }
  int rem = end - j;  // 0..15
  if (js < rem) {
    int u0 = csr[j + js];
    uint4 v0 = *(const uint4*)(h + (size_t)u0 * HID + c * 8);
    uint2 w0 = *(const uint2*)(anb + (size_t)u0 * 64 + c * 4);
    a0 += blo(v0.x); a1 += bhi(v0.x); a2 += blo(v0.y); a3 += bhi(v0.y);
    a4 += blo(v0.z); a5 += bhi(v0.z); a6 += blo(v0.w); a7 += bhi(v0.w);
    dot += av0 * blo(w0.x) + av1 * bhi(w0.x) + av2 * blo(w0.y) + av3 * bhi(w0.y);
  }
  if (js + 4 < rem) {
    int u0 = csr[j + js + 4];
    uint4 v0 = *(const uint4*)(h + (size_t)u0 * HID + c * 8);
    uint2 w0 = *(const uint2*)(anb + (size_t)u0 * 64 + c * 4);
    a0 += blo(v0.x); a1 += bhi(v0.x); a2 += blo(v0.y); a3 += bhi(v0.y);
    a4 += blo(v0.z); a5 += bhi(v0.z); a6 += blo(v0.w); a7 += bhi(v0.w);
    dot += av0 * blo(w0.x) + av1 * bhi(w0.x) + av2 * blo(w0.y) + av3 * bhi(w0.y);
  }
  if (js + 8 < rem) {
    int u0 = csr[j + js + 8];
    uint4 v0 = *(const uint4*)(h + (size_t)u0 * HID + c * 8);
    uint2 w0 = *(const uint2*)(anb + (size_t)u0 * 64 + c * 4);
    a0 += blo(v0.x); a1 += bhi(v0.x); a2 += blo(v0.y); a3 += bhi(v0.y);
    a4 += blo(v0.z); a5 += bhi(v0.z); a6 += blo(v0.w); a7 += bhi(v0.w);
    dot += av0 * blo(w0.x) + av1 * bhi(w0.x) + av2 * blo(w0.y) + av3 * bhi(w0.y);
  }
  if (js + 12 < rem) {
    int u0 = csr[j + js + 12];
    uint4 v0 = *(const uint4*)(h + (size_t)u0 * HID + c * 8);
    uint2 w0 = *(const uint2*)(anb + (size_t)u0 * 64 + c * 4);
    a0 += blo(v0.x); a1 += bhi(v0.x); a2 += blo(v0.y); a3 += bhi(v0.y);
    a4 += blo(v0.z); a5 += bhi(v0.z); a6 += blo(v0.w); a7 += bhi(v0.w);
    dot += av0 * blo(w0.x) + av1 * bhi(w0.x) + av2 * blo(w0.y) + av3 * bhi(w0.y);
  }
  a0 += __shfl_xor(a0, 16); a0 += __shfl_xor(a0, 32);
  a1 += __shfl_xor(a1, 16); a1 += __shfl_xor(a1, 32);
  a2 += __shfl_xor(a2, 16); a2 += __shfl_xor(a2, 32);
  a3 += __shfl_xor(a3, 16); a3 += __shfl_xor(a3, 32);
  a4 += __shfl_xor(a4, 16); a4 += __shfl_xor(a4, 32);
  a5 += __shfl_xor(a5, 16); a5 += __shfl_xor(a5, 32);
  a6 += __shfl_xor(a6, 16); a6 += __shfl_xor(a6, 32);
  a7 += __shfl_xor(a7, 16); a7 += __shfl_xor(a7, 32);
  dot += __shfl_xor(dot, 1); dot += __shfl_xor(dot, 2);
  dot += __shfl_xor(dot, 4); dot += __shfl_xor(dot, 8);
  dot += __shfl_xor(dot, 16); dot += __shfl_xor(dot, 32);
  if (l < 16) {
    float r = (deg > 0) ? 1.0f / (float)deg : 0.0f;
    uint4 o;
    o.x = pack2(a0 * r, a1 * r); o.y = pack2(a2 * r, a3 * r);
    o.z = pack2(a4 * r, a5 * r); o.w = pack2(a6 * r, a7 * r);
    *(uint4*)(outb + (size_t)g * HID + c * 8) = o;
  }
  if (l == 0) {
    float m = (1.0f + dot) / (float)(deg + 1);  // self-loop dot = 1
    gout[g] = 1.0f / (1.0f + expf(-temp[0] * m));
  }
}

// ---- SAGE mean aggregation (1 wave / node, 16 neighbors / iter) ----
__device__ __forceinline__ void agg_b_body(int bid, int goff, const ushort* __restrict__ h,
                                           const int* __restrict__ rowptr,
                                           const int* __restrict__ rowend,
                                           const int* __restrict__ csr,
                                           ushort* __restrict__ outb, int n) {
  int g = goff + bid * 4 + (threadIdx.x >> 6);
  if (g >= n) return;
  const int l = threadIdx.x & 63;
  const int js = l >> 4;
  const int c = l & 15;
  int beg = rowptr[g], end = rowend[g];
  int deg = end - beg;
  float a0=0,a1=0,a2=0,a3=0,a4=0,a5=0,a6=0,a7=0;
  int j = beg;
  int jend = beg + (deg & ~15);
  for (; j < jend; j += 16) {
    int u0 = csr[j + js];
    int u1 = csr[j + js + 4];
    int u2 = csr[j + js + 8];
    int u3 = csr[j + js + 12];
    uint4 v0 = *(const uint4*)(h + (size_t)u0 * HID + c * 8);
    uint4 v1 = *(const uint4*)(h + (size_t)u1 * HID + c * 8);
    uint4 v2 = *(const uint4*)(h + (size_t)u2 * HID + c * 8);
    uint4 v3 = *(const uint4*)(h + (size_t)u3 * HID + c * 8);
    a0 += (blo(v0.x) + blo(v1.x)) + (blo(v2.x) + blo(v3.x));
    a1 += (bhi(v0.x) + bhi(v1.x)) + (bhi(v2.x) + bhi(v3.x));
    a2 += (blo(v0.y) + blo(v1.y)) + (blo(v2.y) + blo(v3.y));
    a3 += (bhi(v0.y) + bhi(v1.y)) + (bhi(v2.y) + bhi(v3.y));
    a4 += (blo(v0.z) + blo(v1.z)) + (blo(v2.z) + blo(v3.z));
    a5 += (bhi(v0.z) + bhi(v1.z)) + (bhi(v2.z) + bhi(v3.z));
    a6 += (blo(v0.w) + blo(v1.w)) + (blo(v2.w) + blo(v3.w));
    a7 += (bhi(v0.w) + bhi(v1.w)) + (bhi(v2.w) + bhi(v3.w));
  }
  int rem = end - j;  // 0..15
  if (js < rem) {
    int u0 = csr[j + js];
    uint4 v0 = *(const uint4*)(h + (size_t)u0 * HID + c * 8);
    a0 += blo(v0.x); a1 += bhi(v0.x); a2 += blo(v0.y); a3 += bhi(v0.y);
    a4 += blo(v0.z); a5 += bhi(v0.z); a6 += blo(v0.w); a7 += bhi(v0.w);
  }
  if (js + 4 < rem) {
    int u0 = csr[j + js + 4];
    uint4 v0 = *(const uint4*)(h + (size_t)u0 * HID + c * 8);
    a0 += blo(v0.x); a1 += bhi(v0.x); a2 += blo(v0.y); a3 += bhi(v0.y);
    a4 += blo(v0.z); a5 += bhi(v0.z); a6 += blo(v0.w); a7 += bhi(v0.w);
  }
  if (js + 8 < rem) {
    int u0 = csr[j + js + 8];
    uint4 v0 = *(const uint4*)(h + (size_t)u0 * HID + c * 8);
    a0 += blo(v0.x); a1 += bhi(v0.x); a2 += blo(v0.y); a3 += bhi(v0.y);
    a4 += blo(v0.z); a5 += bhi(v0.z); a6 += blo(v0.w); a7 += bhi(v0.w);
  }
  if (js + 12 < rem) {
    int u0 = csr[j + js + 12];
    uint4 v0 = *(const uint4*)(h + (size_t)u0 * HID + c * 8);
    a0 += blo(v0.x); a1 += bhi(v0.x); a2 += blo(v0.y); a3 += bhi(v0.y);
    a4 += blo(v0.z); a5 += bhi(v0.z); a6 += blo(v0.w); a7 += bhi(v0.w);
  }
  a0 += __shfl_xor(a0, 16); a0 += __shfl_xor(a0, 32);
  a1 += __shfl_xor(a1, 16); a1 += __shfl_xor(a1, 32);
  a2 += __shfl_xor(a2, 16); a2 += __shfl_xor(a2, 32);
  a3 += __shfl_xor(a3, 16); a3 += __shfl_xor(a3, 32);
  a4 += __shfl_xor(a4, 16); a4 += __shfl_xor(a4, 32);
  a5 += __shfl_xor(a5, 16); a5 += __shfl_xor(a5, 32);
  a6 += __shfl_xor(a6, 16); a6 += __shfl_xor(a6, 32);
  a7 += __shfl_xor(a7, 16); a7 += __shfl_xor(a7, 32);
  if (l < 16) {
    float r = (deg > 0) ? 1.0f / (float)deg : 0.0f;
    uint4 o;
    o.x = pack2(a0 * r, a1 * r); o.y = pack2(a2 * r, a3 * r);
    o.z = pack2(a4 * r, a5 * r); o.w = pack2(a6 * r, a7 * r);
    *(uint4*)(outb + (size_t)g * HID + c * 8) = o;
  }
}

// ---- MFMA linear body: C = A1@W1^T (+ A2@W2^T) + bias, bf16 in/out ----
// K=64 staged per barrier pair (2 x 32-k-chunks in 16KB As + 16KB Bs);
// 32 consecutive MFMAs per wave between barriers (half the barrier count).
// stats buffer is 8-way replicated (bid&7).
template <int NPARTS, bool STATS, bool ORELU>
__device__ __forceinline__ void mlin_body(
    int bid, const ushort* __restrict__ A1, const ushort* __restrict__ A2, int K,
    const ushort* __restrict__ W1, const ushort* __restrict__ W2,
    const float* __restrict__ bias, ushort* __restrict__ C,
    float* __restrict__ stats, int M, ushort* As, ushort* Bs) {
  const int tid = threadIdx.x;
  const int w = tid >> 6, l = tid & 63;
  const int mbase = bid * 128;
  const int lm = l & 15, lq = l >> 4;
  floatx4 acc[2][8];
#pragma unroll
  for (int mt = 0; mt < 2; ++mt)
#pragma unroll
    for (int nt = 0; nt < 8; ++nt) {
      floatx4 z = {0.f, 0.f, 0.f, 0.f};
      acc[mt][nt] = z;
    }

  for (int part = 0; part < NPARTS; ++part) {
    const ushort* Ap = part ? A2 : A1;
    const ushort* Wp = part ? W2 : W1;
    for (int kh = 0; kh < K; kh += 64) {
      if (part || kh) __syncthreads();  // protect LDS overwrite
#pragma unroll
      for (int k4 = 0; k4 < 2; ++k4) {
        int k0 = kh + k4 * 32;
#pragma unroll
        for (int i = 0; i < 2; ++i) {
          int s = w * 2 + i;
          int rt = s * 16 + (l >> 2);
          int q = (l & 3) ^ ((rt >> 1) & 3);
          int grow = mbase + rt; grow = grow < M ? grow : M - 1;
          async_cp16(Ap + (size_t)grow * K + k0 + q * 8, &As[k4 * 4096 + s * 512]);
          async_cp16(Wp + (size_t)rt * K + k0 + q * 8, &Bs[k4 * 4096 + s * 512]);
        }
      }
      __syncthreads();
#pragma unroll
      for (int k4 = 0; k4 < 2; ++k4) {
        const ushort* Ak = &As[k4 * 4096];
        const ushort* Bk = &Bs[k4 * 4096];
        short8 b[8];
#pragma unroll
        for (int nt = 0; nt < 8; ++nt) {
          int row = nt * 16 + lm;
          int q = lq ^ ((row >> 1) & 3);
          b[nt] = *(const short8*)&Bk[row * 32 + q * 8];
        }
#pragma unroll
        for (int mt = 0; mt < 2; ++mt) {
          int row = (w * 2 + mt) * 16 + lm;
          int q = lq ^ ((row >> 1) & 3);
          short8 a = *(const short8*)&Ak[row * 32 + q * 8];
#pragma unroll
          for (int nt = 0; nt < 8; ++nt)
            acc[mt][nt] = __builtin_amdgcn_mfma_f32_16x16x32_bf16(a, b[nt], acc[mt][nt], 0, 0, 0);
        }
      }
    }
  }

  if (STATS) __syncthreads();  // all waves done reading As before sred reuse
  float ss[8], qq[8];
#pragma unroll
  for (int nt = 0; nt < 8; ++nt) { ss[nt] = 0.f; qq[nt] = 0.f; }
#pragma unroll
  for (int nt = 0; nt < 8; ++nt) {
    int col = nt * 16 + lm;
    float bv = bias[col];
#pragma unroll
    for (int mt = 0; mt < 2; ++mt) {
      int rbase = mbase + (w * 2 + mt) * 16 + lq * 4;
#pragma unroll
      for (int r = 0; r < 4; ++r) {
        int grow = rbase + r;
        if (grow < M) {
          float val = acc[mt][nt][r] + bv;
          if (ORELU) val = fmaxf(val, 0.f);
          C[(size_t)grow * 128 + col] = f2b(val);
          if (STATS) { ss[nt] += val; qq[nt] += val * val; }
        }
      }
    }
  }
  if (STATS) {
    float* sred = (float*)As;
    if (tid < 256) sred[tid] = 0.f;
    __syncthreads();
#pragma unroll
    for (int nt = 0; nt < 8; ++nt) {
      ss[nt] += __shfl_xor(ss[nt], 16); ss[nt] += __shfl_xor(ss[nt], 32);
      qq[nt] += __shfl_xor(qq[nt], 16); qq[nt] += __shfl_xor(qq[nt], 32);
    }
    if (lq == 0) {
#pragma unroll
      for (int nt = 0; nt < 8; ++nt) {
        int col = nt * 16 + lm;
        atomicAdd(&sred[col], ss[nt]);
        atomicAdd(&sred[128 + col], qq[nt]);
      }
    }
    __syncthreads();
    float* sbase = stats + ((bid & 7) << 8);
    if (tid < 256) atomicAdd(&sbase[tid], sred[tid]);
  }
}

// ---- BatchNorm apply body (bf16 in-place; sums 8 stats replicas) ----
template <int ACT, int TPB>  // ACT: 0=relu, 1=sigmoid
__device__ __forceinline__ void bnb_body(int bid, int gB, ushort* __restrict__ buf,
                                         const float* __restrict__ stats,
                                         const float* __restrict__ gamma,
                                         const float* __restrict__ beta, int n) {
  const int S = gB * TPB;
  int idx = bid * TPB + threadIdx.x;
  const int c0 = (idx & 15) * 8;
  const float inv_n = 1.0f / (float)n;
  float sc[8], sh[8];
#pragma unroll
  for (int d = 0; d < 8; ++d) {
    int c = c0 + d;
    float s0 = 0.f, s1 = 0.f;
#pragma unroll
    for (int r2 = 0; r2 < 8; ++r2) {
      s0 += stats[(r2 << 8) + c];
      s1 += stats[(r2 << 8) + 128 + c];
    }
    float mu = s0 * inv_n;
    float var = s1 * inv_n - mu * mu;
    float s = rsqrtf(var + 1e-5f) * gamma[c];
    sc[d] = s;
    sh[d] = beta[c] - mu * s;
  }
  const int n16 = n * 16;
  for (; idx < n16; idx += S) {
    uint4 v = ((const uint4*)buf)[idx];
    float x[8] = {blo(v.x), bhi(v.x), blo(v.y), bhi(v.y),
                  blo(v.z), bhi(v.z), blo(v.w), bhi(v.w)};
#pragma unroll
    for (int d = 0; d < 8; ++d) {
      float y = x[d] * sc[d] + sh[d];
      x[d] = (ACT == 0) ? fmaxf(y, 0.f) : 1.0f / (1.0f + expf(-y));
    }
    uint4 o;
    o.x = pack2(x[0], x[1]); o.y = pack2(x[2], x[3]);
    o.z = pack2(x[4], x[5]); o.w = pack2(x[6], x[7]);
    ((uint4*)buf)[idx] = o;
  }
}

// ---- classifier body: MFMA GEMM + fused log_softmax ----
__device__ __forceinline__ void clsm_body(
    int bid, const ushort* __restrict__ A1, const ushort* __restrict__ A2,
    const ushort* __restrict__ Wcb, const float* __restrict__ bias,
    float* __restrict__ C, int M, ushort* As, ushort* Bs) {
  const int tid = threadIdx.x;
  const int w = tid >> 6, l = tid & 63;
  const int mbase = bid * 128;
  const int lm = l & 15, lq = l >> 4;
  floatx4 acc[2][3];
#pragma unroll
  for (int mt = 0; mt < 2; ++mt)
#pragma unroll
    for (int nt = 0; nt < 3; ++nt) {
      floatx4 z = {0.f, 0.f, 0.f, 0.f};
      acc[mt][nt] = z;
    }

  for (int part = 0; part < 2; ++part) {
    const ushort* Ap = part ? A2 : A1;
    for (int k0 = 0; k0 < 128; k0 += 32) {
#pragma unroll
      for (int i = 0; i < 2; ++i) {
        int s = w * 2 + i;
        int rt = s * 16 + (l >> 2);
        int q = (l & 3) ^ ((rt >> 1) & 3);
        int grow = mbase + rt; grow = grow < M ? grow : M - 1;
        async_cp16(Ap + (size_t)grow * 128 + k0 + q * 8, &As[s * 512]);
      }
      if (w < 3) {
        int rt = w * 16 + (l >> 2);
        int q = (l & 3) ^ ((rt >> 1) & 3);
        async_cp16(Wcb + (size_t)rt * 256 + part * 128 + k0 + q * 8, &Bs[w * 512]);
      }
      __syncthreads();
      short8 b[3];
#pragma unroll
      for (int nt = 0; nt < 3; ++nt) {
        int row = nt * 16 + lm;
        int q = lq ^ ((row >> 1) & 3);
        b[nt] = *(const short8*)&Bs[row * 32 + q * 8];
      }
#pragma unroll
      for (int mt = 0; mt < 2; ++mt) {
        int row = (w * 2 + mt) * 16 + lm;
        int q = lq ^ ((row >> 1) & 3);
        short8 a = *(const short8*)&As[row * 32 + q * 8];
#pragma unroll
        for (int nt = 0; nt < 3; ++nt)
          acc[mt][nt] = __builtin_amdgcn_mfma_f32_16x16x32_bf16(a, b[nt], acc[mt][nt], 0, 0, 0);
      }
      __syncthreads();
    }
  }

  float b0v = bias[lm], b1v = bias[lm + 16];
  float b2v = (lm < 8) ? bias[lm + 32] : 0.f;
#pragma unroll
  for (int mt = 0; mt < 2; ++mt) {
#pragma unroll
    for (int r = 0; r < 4; ++r) {
      int grow = mbase + (w * 2 + mt) * 16 + lq * 4 + r;
      float v0 = acc[mt][0][r] + b0v;
      float v1 = acc[mt][1][r] + b1v;
      float v2 = (lm < 8) ? acc[mt][2][r] + b2v : -3.4e38f;
      float m = fmaxf(fmaxf(v0, v1), v2);
      m = fmaxf(m, __shfl_xor(m, 1)); m = fmaxf(m, __shfl_xor(m, 2));
      m = fmaxf(m, __shfl_xor(m, 4)); m = fmaxf(m, __shfl_xor(m, 8));
      float s = expf(v0 - m) + expf(v1 - m) + ((lm < 8) ? expf(v2 - m) : 0.f);
      s += __shfl_xor(s, 1); s += __shfl_xor(s, 2);
      s += __shfl_xor(s, 4); s += __shfl_xor(s, 8);
      float ls = m + logf(s);
      if (grow < M) {
        C[(size_t)grow * OUTC + lm] = v0 - ls;
        C[(size_t)grow * OUTC + lm + 16] = v1 - ls;
        if (lm < 8) C[(size_t)grow * OUTC + lm + 32] = v2 - ls;
      }
    }
  }
}

// ================= global kernels =================

// prep (cvtw | cvt | anorm2), one launch
__global__ void prep_kernel(
    const float* __restrict__ x, ushort* __restrict__ xb, int n4,
    const float* __restrict__ alpha, ushort* __restrict__ ab, ushort* __restrict__ anb, int n,
    const float* __restrict__ Wl, const float* __restrict__ Wr, const float* __restrict__ W0,
    const float* __restrict__ W1, const float* __restrict__ W2, const float* __restrict__ Wc,
    ushort* __restrict__ wb, ushort* __restrict__ wcb, float* __restrict__ stats,
    int* __restrict__ gcnt, int GW, int GC) {
  int b = blockIdx.x;
  if (b < GW) cvtw_body(b, Wl, Wr, W0, W1, W2, Wc, wb, wcb, stats, gcnt);
  else if (b < GW + GC) cvt_body(b - GW, x, xb, n4);
  else anorm2_body(b - GW - GC, alpha, ab, anb, n);
}

// ---------------- bucketed CSR build (atomic range reservation, no scans) ----
// ebuf/csr are bucketed with fixed capacity `cap` per 512-node bucket; per-node
// extents live in rowptr[] (begin) and rowend[] (end). Gaps between buckets.

__device__ __forceinline__ void binAB_body(int bid, const int* __restrict__ src,
                                           const int* __restrict__ tgt,
                                           int* __restrict__ gcnt,
                                           int* __restrict__ ebuf,
                                           int e, int chunk, int nbk, int cap,
                                           int* hist) {
  int tid = threadIdx.x;
  for (int b = tid; b < nbk; b += 256) hist[b] = 0;
  __syncthreads();
  int i0 = bid * chunk;
  int i1 = min(e, i0 + chunk);
  for (int j = i0 + tid; j < i1; j += 256) atomicAdd(&hist[tgt[j] >> 9], 1);
  __syncthreads();
  // reserve a contiguous range in each bucket for this block's edges
  for (int b = tid; b < nbk; b += 256) {
    int c = hist[b];
    hist[b] = c ? atomicAdd(&gcnt[b], c) : 0;
  }
  __syncthreads();
  for (int j = i0 + tid; j < i1; j += 256) {
    int t = tgt[j];
    int b = t >> 9;
    int pos = atomicAdd(&hist[b], 1);
    if (pos < cap) ebuf[(size_t)b * cap + pos] = ((t & 511) << 17) | src[j];
  }
}

// binAB (blocks [0,PBB)) || proto W0 GEMM (rest). Disjoint data.
__global__ __launch_bounds__(256) void k_binAB_w0(
    const int* __restrict__ src, const int* __restrict__ tgt,
    int* __restrict__ gcnt, int* __restrict__ ebuf, int e, int chunk, int nbk, int cap,
    const ushort* __restrict__ ab, const ushort* __restrict__ W0b,
    const float* __restrict__ b0, ushort* __restrict__ hproto,
    float* __restrict__ stats, int n) {
  __shared__ ushort As[8192];
  __shared__ ushort Bs[8192];
  if ((int)blockIdx.x < PBB)
    binAB_body(blockIdx.x, src, tgt, gcnt, ebuf, e, chunk, nbk, cap, (int*)As);
  else
    mlin_body<1, true, false>(blockIdx.x - PBB, ab, nullptr, 64, W0b, nullptr, b0,
                              hproto, stats, n, As, Bs);
}

// binC body (512 threads): per-bucket count + scan + scatter
__device__ __forceinline__ void binC_body(int b, const int* __restrict__ ebuf,
                                          const int* __restrict__ gcnt,
                                          int* __restrict__ rowptr, int* __restrict__ rowend,
                                          int* __restrict__ csr, int n, int cap,
                                          int* hist, int* scanbuf) {
  int tid = threadIdx.x;
  int seg0 = b * cap;
  int cnt = gcnt[b]; if (cnt > cap) cnt = cap;
  int seg1 = seg0 + cnt;
  hist[tid] = 0;
  __syncthreads();
  for (int j = seg0 + tid; j < seg1; j += 512)
    atomicAdd(&hist[ebuf[j] >> 17], 1);
  __syncthreads();
  int s = hist[tid];
  scanbuf[tid] = s;
  __syncthreads();
  for (int d = 1; d < 512; d <<= 1) {
    int add = (tid >= d) ? scanbuf[tid - d] : 0;
    __syncthreads();
    scanbuf[tid] += add;
    __syncthreads();
  }
  int ex = scanbuf[tid] - s;
  int node = b * 512 + tid;
  if (node < n) { rowptr[node] = seg0 + ex; rowend[node] = seg0 + ex + s; }
  hist[tid] = ex;
  __syncthreads();
  for (int j = seg0 + tid; j < seg1; j += 512) {
    int val = ebuf[j];
    int pos = atomicAdd(&hist[val >> 17], 1);
    csr[seg0 + pos] = val & 0x1FFFF;
  }
}

// binC (blocks [0,nbk), 512 thr) || proto BN0 sigmoid (rest, 512 thr)
__global__ __launch_bounds__(512) void k_binC_bnb(
    const int* __restrict__ ebuf, const int* __restrict__ gcnt,
    int* __restrict__ rowptr, int* __restrict__ rowend, int* __restrict__ csr,
    int n, int cap, int nbk,
    ushort* __restrict__ bnbuf, const float* __restrict__ bnstats,
    const float* __restrict__ gamma, const float* __restrict__ beta, int gB) {
  __shared__ int hist[512];
  __shared__ int scanbuf[512];
  if ((int)blockIdx.x < nbk)
    binC_body(blockIdx.x, ebuf, gcnt, rowptr, rowend, csr, n, cap, hist, scanbuf);
  else
    bnb_body<1, 512>(blockIdx.x - nbk, gB, bnbuf, bnstats, gamma, beta, n);
}

// ---------------- pure aggregation kernels (VGPR capped at 64) ----------------

__global__ __launch_bounds__(256, 8) void agg_gate_kernel(
    const ushort* __restrict__ h, const ushort* __restrict__ anb,
    const int* __restrict__ rowptr, const int* __restrict__ rowend,
    const int* __restrict__ csr,
    const float* __restrict__ temp, float* __restrict__ gout,
    ushort* __restrict__ outb, int n) {
  agg_gate_body(blockIdx.x, h, anb, rowptr, rowend, csr, temp, gout, outb, n);
}

__global__ __launch_bounds__(256, 8) void agg_b_kernel(
    const ushort* __restrict__ h, const int* __restrict__ rowptr,
    const int* __restrict__ rowend, const int* __restrict__ csr,
    ushort* __restrict__ outb, int goff, int n) {
  agg_b_body(blockIdx.x, goff, h, rowptr, rowend, csr, outb, n);
}

// agg_b (blocks [0,gAgg)) || bnb (trailing) — no mlin, footprint stays small
template <int ACT>
__global__ __launch_bounds__(256, 8) void k_agg_bnb(
    const ushort* __restrict__ h, const int* __restrict__ rowptr,
    const int* __restrict__ rowend, const int* __restrict__ csr,
    ushort* __restrict__ outb, int n, int gAgg,
    ushort* __restrict__ bnbuf, const float* __restrict__ bnstats,
    const float* __restrict__ gamma, const float* __restrict__ beta, int gBn) {
  if ((int)blockIdx.x < gAgg)
    agg_b_body(blockIdx.x, 0, h, rowptr, rowend, csr, outb, n);
  else
    bnb_body<ACT, 256>(blockIdx.x - gAgg, gBn, bnbuf, bnstats, gamma, beta, n);
}

// ---------------- combined launches (same-footprint roles only) --------------

// SAGE L0 GEMM w/ stats (blocks [0,gLin)) || proto W1 GEMM w/ stats (rest)
__global__ __launch_bounds__(256) void k_mlin_L0W1(
    const ushort* __restrict__ aggB, const ushort* __restrict__ hB,
    const ushort* __restrict__ Wl, const ushort* __restrict__ Wr,
    const float* __restrict__ bl, ushort* __restrict__ Cl, float* __restrict__ stl,
    const ushort* __restrict__ Ap, const ushort* __restrict__ Wp,
    const float* __restrict__ bp, ushort* __restrict__ Cp, float* __restrict__ stp,
    int M, int gLin) {
  __shared__ ushort As[8192];
  __shared__ ushort Bs[8192];
  if ((int)blockIdx.x < gLin)
    mlin_body<2, true, false>(blockIdx.x, aggB, hB, 128, Wl, Wr, bl, Cl, stl, M, As, Bs);
  else
    mlin_body<1, true, false>(blockIdx.x - gLin, Ap, nullptr, 128, Wp, nullptr, bp, Cp,
                              stp, M, As, Bs);
}

// SAGE mlin L1 w/ stats (blocks [0,gLin)) || proto W2 relu (rest)
__global__ __launch_bounds__(256) void k_mlin_mlin(
    const ushort* __restrict__ A1a, const ushort* __restrict__ A2a,
    const ushort* __restrict__ W1a, const ushort* __restrict__ W2a,
    const float* __restrict__ ba, ushort* __restrict__ Ca, float* __restrict__ statsa,
    const ushort* __restrict__ A1b, const ushort* __restrict__ W1b,
    const float* __restrict__ bb, ushort* __restrict__ Cb, int M, int gLin) {
  __shared__ ushort As[8192];
  __shared__ ushort Bs[8192];
  if ((int)blockIdx.x < gLin)
    mlin_body<2, true, false>(blockIdx.x, A1a, A2a, 128, W1a, W2a, ba, Ca, statsa, M, As, Bs);
  else
    mlin_body<1, false, true>(blockIdx.x - gLin, A1b, nullptr, 128, W1b, nullptr, bb, Cb,
                              nullptr, M, As, Bs);
}

// SAGE GEMM2 rows-half2 (blocks [0,nM), rows offset moff) || clsm rows-half1 (rest)
__global__ __launch_bounds__(256) void k_mlin_clsm(
    const ushort* __restrict__ A1, const ushort* __restrict__ A2,
    const ushort* __restrict__ W1, const ushort* __restrict__ W2,
    const float* __restrict__ bias, ushort* __restrict__ C, int moff, int nM,
    const ushort* __restrict__ cA1, const ushort* __restrict__ cA2,
    const ushort* __restrict__ Wcb, const float* __restrict__ cbias,
    float* __restrict__ Cout, int M) {
  __shared__ ushort As[8192];
  __shared__ ushort Bs[8192];
  if ((int)blockIdx.x < nM)
    mlin_body<2, false, true>(blockIdx.x + moff, A1, A2, 128, W1, W2, bias, C,
                              nullptr, M, As, Bs);
  else
    clsm_body(blockIdx.x - nM, cA1, cA2, Wcb, cbias, Cout, M, As, Bs);
}

// ---------------- standalone kernels ----------------

template <int NPARTS, bool STATS, bool ORELU>
__global__ __launch_bounds__(256) void mlin_kernel(
    const ushort* __restrict__ A1, const ushort* __restrict__ A2, int K,
    const ushort* __restrict__ W1, const ushort* __restrict__ W2,
    const float* __restrict__ bias, ushort* __restrict__ C,
    float* __restrict__ stats, int M) {
  __shared__ ushort As[8192];
  __shared__ ushort Bs[8192];
  mlin_body<NPARTS, STATS, ORELU>(blockIdx.x, A1, A2, K, W1, W2, bias, C, stats, M, As, Bs);
}

template <int ACT>
__global__ __launch_bounds__(256) void bnb_kernel(
    ushort* __restrict__ buf, const float* __restrict__ stats,
    const float* __restrict__ gamma, const float* __restrict__ beta, int n) {
  bnb_body<ACT, 256>(blockIdx.x, gridDim.x, buf, stats, gamma, beta, n);
}

__global__ __launch_bounds__(256) void clsm_kernel(
    const ushort* __restrict__ A1, const ushort* __restrict__ A2,
    const ushort* __restrict__ Wcb, const float* __restrict__ bias,
    float* __restrict__ C, int M, int boff) {
  __shared__ ushort As[8192];
  __shared__ ushort Bs[8192];
  clsm_body(blockIdx.x + boff, A1, A2, Wcb, bias, C, M, As, Bs);
}

// ---------------- launch ----------------

extern "C" void kernel_launch(void* const* d_in, const int* in_sizes, int n_in,
                              void* d_out, int out_size, void* d_ws, size_t ws_size,
                              hipStream_t stream) {
  const float* x       = (const float*)d_in[0];
  const float* alpha   = (const float*)d_in[1];
  const int*   eidx    = (const int*)d_in[2];
  const float* sage_Wl = (const float*)d_in[3];
  const float* sage_bl = (const float*)d_in[4];
  const float* sage_Wr = (const float*)d_in[5];
  const float* sage_g  = (const float*)d_in[6];
  const float* sage_b  = (const float*)d_in[7];
  const float* W0 = (const float*)d_in[8];
  const float* b0 = (const float*)d_in[9];
  const float* W1 = (const float*)d_in[10];
  const float* b1 = (const float*)d_in[11];
  const float* W2 = (const float*)d_in[12];
  const float* b2 = (const float*)d_in[13];
  const float* mg = (const float*)d_in[14];
  const float* mb = (const float*)d_in[15];
  const float* Wc = (const float*)d_in[16];
  const float* bc = (const float*)d_in[17];
  const float* temp = (const float*)d_in[18];
  float* out = (float*)d_out;

  const int n = in_sizes[0] / HID;  // 100000
  const int e = in_sizes[2] / 2;    // 1600000
  const int* src = eidx;
  const int* tgt = eidx + e;

  const int nbk = (n + 511) >> 9;
  const int chunkB = (e + PBB - 1) / PBB;
  // bucket capacity: 1.5x mean, rounded up to 64 (45-sigma slack for random graphs)
  const int cap = (int)((((long long)e * 512 / n) * 3 / 2 + 63) & ~63LL);

  // workspace layout: 4 N×128 bf16 regions (16B aligned)
  char* p = (char*)d_ws;
  ushort* B0 = (ushort*)p; p += (size_t)n * HID * 2;
  ushort* B1 = (ushort*)p; p += (size_t)n * HID * 2;
  ushort* B2 = (ushort*)p; p += (size_t)n * HID * 2;
  ushort* B3 = (ushort*)p; p += (size_t)n * HID * 2;
  ushort* wb     = (ushort*)p; p += (size_t)WTOT * 2;
  ushort* wcb    = (ushort*)p; p += (size_t)48 * 256 * 2;
  float* stats = (float*)p; p += 8192 * 4;  // 4 sets x 8 replicas x 256 floats
  int* gcnt   = (int*)p; p += NBK_MAX * 4;
  int* rowptr = (int*)p; p += (size_t)n * 4;
  int* rowend = (int*)p; p += (size_t)n * 4;
  int* csr    = (int*)p; p += (size_t)nbk * cap * 4;
  ushort* xb   = B0;
  ushort* anb  = B1;                       // N*64
  ushort* ab   = B1 + (size_t)n * 64;      // N*64
  ushort* hgnn = B1;                       // SAGE L2 out (B1 dead by then)
  int*    ebuf = (int*)B2;                 // nbk*cap*4 <= n*256; dead after binC
  ushort* hproto = B3;
  ushort* Wlb = wb, *Wrb = wb + 49152, *W0b = wb + 98304, *W1b = wb + 106496, *W2b = wb + 122880;
  // stats sets (each 2048 floats: 8 replicas x 256)
  float* stSage0 = stats;
  float* stSage1 = stats + 2048;
  float* stPr0   = stats + 4096;
  float* stPr1   = stats + 6144;

  const int T = 256;

  const int gLin = (n + 127) / 128;        // 782
  const int gHalf = (gLin + 1) / 2;        // 391
  const int gLin2 = gLin - gHalf;          // 391
  const int gBn = 1024;                    // 256-thr bnb blocks
  const int gBnH = 512;                    // 512-thr bnb blocks
  const int gAgg = (n + 3) >> 2;           // 25000 (1 wave/node, 4/block)
  const int GW = WTOT / 4 / T;             // 136 blocks (exact)
  const int GC = (n * (HID / 4) + T - 1) / T;          // cvt blocks
  const int GA = (int)(((size_t)n * 16 + T - 1) / T);  // anorm2 blocks

  // 1: prep (weights cvt + x cvt + alpha norm + stats/gcnt zero)
  prep_kernel<<<GW + GC + GA, T, 0, stream>>>(
      x, xb, n * (HID / 4), alpha, ab, anb, n,
      sage_Wl, sage_Wr, W0, W1, W2, Wc, wb, wcb, stats, gcnt, GW, GC);

  // 2: binAB (1024 blocks: hist + range reservation + scatter) || proto W0 GEMM
  k_binAB_w0<<<PBB + gLin, T, 0, stream>>>(src, tgt, gcnt, ebuf, e, chunkB, nbk, cap,
                                           ab, W0b, b0, hproto, stPr0, n);

  // 3: binC (512-thr per-bucket sort) || proto BN0 (sigmoid)
  k_binC_bnb<<<nbk + gBnH, 512, 0, stream>>>(ebuf, gcnt, rowptr, rowend, csr,
                                             n, cap, nbk,
                                             hproto, stPr0, mg, mb, gBnH);

  // 4: L0 aggregate + gate (pure)
  agg_gate_kernel<<<gAgg, T, 0, stream>>>(xb, anb, rowptr, rowend, csr, temp,
                                          out + (size_t)n * OUTC, B2, n);

  // 5: SAGE L0 GEMM || proto W1 GEMM (both with stats)
  k_mlin_L0W1<<<2 * gLin, T, 0, stream>>>(B2, B0, Wlb, Wrb, sage_bl, B1, stSage0,
                                          hproto, W1b, b1, hproto, stPr1, n, gLin);

  // 6: SAGE BN0 (relu)
  bnb_kernel<0><<<gBn, T, 0, stream>>>(B1, stSage0, sage_g, sage_b, n);

  // 7: SAGE L1 aggregate || proto BN1 sigmoid (trailing)
  k_agg_bnb<1><<<gAgg + gBn, T, 0, stream>>>(B1, rowptr, rowend, csr, B2, n, gAgg,
                                             hproto, stPr1, mg + HID, mb + HID, gBn);

  // 8: SAGE L1 GEMM || proto W2 GEMM (relu fused)
  k_mlin_mlin<<<2 * gLin, T, 0, stream>>>(B2, B1, Wlb + 16384, Wrb + 16384,
                                          sage_bl + HID, B0, stSage1,
                                          hproto, W2b, b2, hproto, n, gLin);

  // 9: SAGE BN1 (relu)
  bnb_kernel<0><<<gBn, T, 0, stream>>>(B0, stSage1, sage_g + HID, sage_b + HID, n);

  // 10: SAGE L2 aggregate (pure, full)
  agg_b_kernel<<<gAgg, T, 0, stream>>>(B0, rowptr, rowend, csr, B2, 0, n);

  // 11: SAGE GEMM2 rows-half1
  mlin_kernel<2, false, true><<<gHalf, T, 0, stream>>>(B2, B0, 128, Wlb + 32768,
                                                       Wrb + 32768, sage_bl + 2 * HID,
                                                       hgnn, nullptr, n);

  // 12: SAGE GEMM2 rows-half2 || classifier rows-half1
  k_mlin_clsm<<<gLin2 + gHalf, T, 0, stream>>>(B2, B0, Wlb + 32768, Wrb + 32768,
                                               sage_bl + 2 * HID, hgnn, gHalf, gLin2,
                                               hgnn, hproto, wcb, bc, out, n);

  // 13: classifier rows-half2
  clsm_kernel<<<gLin - gHalf, T, 0, stream>>>(hgnn, hproto, wcb, bc, out, n, gHalf);
}

// Round 11
// 626.285 us; speedup vs baseline: 1.2781x; 1.0244x over previous
//
#include <hip/hip_runtime.h>
#include <cstdint>
#include <cstddef>

#define HID 128
#define OUTC 40
#define WTOT 139264  // Wl 49152 | Wr 49152 | W0 8192 | W1 16384 | W2 16384
#define PBB 1024     // blocks for the edge-binning scatter pass
#define NBK_MAX 256  // max buckets (512 nodes each)
#define ZSTR 140     // zt LDS row stride (ushorts): odd word-stride => <=2-way banks

typedef __attribute__((ext_vector_type(8))) short short8;
typedef __attribute__((ext_vector_type(4))) float floatx4;

__device__ __forceinline__ unsigned short f2b(float f) {
  unsigned int u = __float_as_uint(f);
  unsigned int r = u + 0x7FFFu + ((u >> 16) & 1u);
  return (unsigned short)(r >> 16);
}
__device__ __forceinline__ float blo(unsigned int u) { return __uint_as_float(u << 16); }
__device__ __forceinline__ float bhi(unsigned int u) { return __uint_as_float(u & 0xFFFF0000u); }
__device__ __forceinline__ unsigned int pack2(float a, float b) {
  return (unsigned int)f2b(a) | ((unsigned int)f2b(b) << 16);
}

__device__ __forceinline__ void async_cp16(const ushort* g, ushort* l) {
  __builtin_amdgcn_global_load_lds((const __attribute__((address_space(1))) void*)g,
                                   (__attribute__((address_space(3))) void*)l, 16, 0, 0);
}

// ================= device bodies =================

__device__ __forceinline__ void cvt_body(int bid, const float* __restrict__ in,
                                         ushort* __restrict__ out, int n4) {
  int i = bid * 256 + threadIdx.x;
  if (i >= n4) return;
  float4 v = ((const float4*)in)[i];
  ushort4 o;
  o.x = f2b(v.x); o.y = f2b(v.y); o.z = f2b(v.z); o.w = f2b(v.w);
  ((ushort4*)out)[i] = o;
}

__device__ __forceinline__ void cvtw_body(int bid, const float* __restrict__ Wl,
                                          const float* __restrict__ Wr, const float* __restrict__ W0,
                                          const float* __restrict__ W1, const float* __restrict__ W2,
                                          const float* __restrict__ Wc, ushort* __restrict__ wb,
                                          ushort* __restrict__ wcb, float* __restrict__ stats,
                                          int* __restrict__ gcnt) {
  int gid = bid * 256 + threadIdx.x;
  if (gid < 8192) stats[gid] = 0.0f;  // 4 sets x 8 replicas x 256
  if (gid < NBK_MAX) gcnt[gid] = 0;
  if (gid < 48 * 64) {  // wcb: 48x256 bf16, rows 40..47 zero
    int row = gid >> 6;
    ushort4 o;
    if (row < 40) {
      float4 v = *(const float4*)(Wc + (size_t)gid * 4);
      o.x = f2b(v.x); o.y = f2b(v.y); o.z = f2b(v.z); o.w = f2b(v.w);
    } else {
      o.x = 0; o.y = 0; o.z = 0; o.w = 0;
    }
    ((ushort4*)wcb)[gid] = o;
  }
  int e4 = gid * 4;
  if (e4 < WTOT) {
    const float* s; int off;
    if (e4 < 49152)       { s = Wl; off = 0; }
    else if (e4 < 98304)  { s = Wr; off = 49152; }
    else if (e4 < 106496) { s = W0; off = 98304; }
    else if (e4 < 122880) { s = W1; off = 106496; }
    else                  { s = W2; off = 122880; }
    float4 v = *(const float4*)(s + (e4 - off));
    ushort4 o;
    o.x = f2b(v.x); o.y = f2b(v.y); o.z = f2b(v.z); o.w = f2b(v.w);
    *(ushort4*)(wb + e4) = o;
  }
}

__device__ __forceinline__ void anorm2_body(int bid, const float* __restrict__ alpha,
                                            ushort* __restrict__ ab, ushort* __restrict__ anb,
                                            int n) {
  int g = (bid * 256 + threadIdx.x) >> 4;  // 16 lanes/node
  int lane = threadIdx.x & 15;
  if (g >= n) return;
  const float4 a = *(const float4*)(alpha + (size_t)g * 64 + lane * 4);
  ushort4 raw;
  raw.x = f2b(a.x); raw.y = f2b(a.y); raw.z = f2b(a.z); raw.w = f2b(a.w);
  *(ushort4*)(ab + (size_t)g * 64 + lane * 4) = raw;
  float d = a.x * a.x + a.y * a.y + a.z * a.z + a.w * a.w;
  d += __shfl_xor(d, 1); d += __shfl_xor(d, 2);
  d += __shfl_xor(d, 4); d += __shfl_xor(d, 8);
  float r = 1.0f / fmaxf(sqrtf(d), 1e-12f);
  ushort4 o;
  o.x = f2b(a.x * r); o.y = f2b(a.y * r); o.z = f2b(a.z * r); o.w = f2b(a.w * r);
  *(ushort4*)(anb + (size_t)g * 64 + lane * 4) = o;
}

// ---- fused layer-0 aggregate + gate (1 wave / node, 16 neighbors / iter) ----
__device__ __forceinline__ void agg_gate_body(int bid, const ushort* __restrict__ h,
                                              const ushort* __restrict__ anb,
                                              const int* __restrict__ rowptr,
                                              const int* __restrict__ rowend,
                                              const int* __restrict__ csr,
                                              const float* __restrict__ temp,
                                              float* __restrict__ gout,
                                              ushort* __restrict__ outb, int n) {
  int g = bid * 4 + (threadIdx.x >> 6);  // 1 wave per node
  if (g >= n) return;
  const int l = threadIdx.x & 63;
  const int js = l >> 4;   // neighbor slot 0..3
  const int c = l & 15;    // 16B chunk of the 256B h row / 8B chunk of anb row
  int beg = rowptr[g], end = rowend[g];
  int deg = end - beg;
  uint2 av = *(const uint2*)(anb + (size_t)g * 64 + c * 4);
  float av0 = blo(av.x), av1 = bhi(av.x), av2 = blo(av.y), av3 = bhi(av.y);
  float a0=0,a1=0,a2=0,a3=0,a4=0,a5=0,a6=0,a7=0;
  float dot = 0.f;
  int j = beg;
  int jend = beg + (deg & ~15);
  for (; j < jend; j += 16) {
    int u0 = csr[j + js];
    int u1 = csr[j + js + 4];
    int u2 = csr[j + js + 8];
    int u3 = csr[j + js + 12];
    uint4 v0 = *(const uint4*)(h + (size_t)u0 * HID + c * 8);
    uint4 v1 = *(const uint4*)(h + (size_t)u1 * HID + c * 8);
    uint4 v2 = *(const uint4*)(h + (size_t)u2 * HID + c * 8);
    uint4 v3 = *(const uint4*)(h + (size_t)u3 * HID + c * 8);
    uint2 w0 = *(const uint2*)(anb + (size_t)u0 * 64 + c * 4);
    uint2 w1 = *(const uint2*)(anb + (size_t)u1 * 64 + c * 4);
    uint2 w2 = *(const uint2*)(anb + (size_t)u2 * 64 + c * 4);
    uint2 w3 = *(const uint2*)(anb + (size_t)u3 * 64 + c * 4);
    a0 += (blo(v0.x) + blo(v1.x)) + (blo(v2.x) + blo(v3.x));
    a1 += (bhi(v0.x) + bhi(v1.x)) + (bhi(v2.x) + bhi(v3.x));
    a2 += (blo(v0.y) + blo(v1.y)) + (blo(v2.y) + blo(v3.y));
    a3 += (bhi(v0.y) + bhi(v1.y)) + (bhi(v2.y) + bhi(v3.y));
    a4 += (blo(v0.z) + blo(v1.z)) + (blo(v2.z) + blo(v3.z));
    a5 += (bhi(v0.z) + bhi(v1.z)) + (bhi(v2.z) + bhi(v3.z));
    a6 += (blo(v0.w) + blo(v1.w)) + (blo(v2.w) + blo(v3.w));
    a7 += (bhi(v0.w) + bhi(v1.w)) + (bhi(v2.w) + bhi(v3.w));
    dot += av0 * ((blo(w0.x) + blo(w1.x)) + (blo(w2.x) + blo(w3.x)))
         + av1 * ((bhi(w0.x) + bhi(w1.x)) + (bhi(w2.x) + bhi(w3.x)))
         + av2 * ((blo(w0.y) + blo(w1.y)) + (blo(w2.y) + blo(w3.y)))
         + av3 * ((bhi(w0.y) + bhi(w1.y)) + (bhi(w2.y) + bhi(w3.y)));
  }
  int rem = end - j;  // 0..15
  if (js < rem) {
    int u0 = csr[j + js];
    uint4 v0 = *(const uint4*)(h + (size_t)u0 * HID + c * 8);
    uint2 w0 = *(const uint2*)(anb + (size_t)u0 * 64 + c * 4);
    a0 += blo(v0.x); a1 += bhi(v0.x); a2 += blo(v0.y); a3 += bhi(v0.y);
    a4 += blo(v0.z); a5 += bhi(v0.z); a6 += blo(v0.w); a7 += bhi(v0.w);
    dot += av0 * blo(w0.x) + av1 * bhi(w0.x) + av2 * blo(w0.y) + av3 * bhi(w0.y);
  }
  if (js + 4 < rem) {
    int u0 = csr[j + js + 4];
    uint4 v0 = *(const uint4*)(h + (size_t)u0 * HID + c * 8);
    uint2 w0 = *(const uint2*)(anb + (size_t)u0 * 64 + c * 4);
    a0 += blo(v0.x); a1 += bhi(v0.x); a2 += blo(v0.y); a3 += bhi(v0.y);
    a4 += blo(v0.z); a5 += bhi(v0.z); a6 += blo(v0.w); a7 += bhi(v0.w);
    dot += av0 * blo(w0.x) + av1 * bhi(w0.x) + av2 * blo(w0.y) + av3 * bhi(w0.y);
  }
  if (js + 8 < rem) {
    int u0 = csr[j + js + 8];
    uint4 v0 = *(const uint4*)(h + (size_t)u0 * HID + c * 8);
    uint2 w0 = *(const uint2*)(anb + (size_t)u0 * 64 + c * 4);
    a0 += blo(v0.x); a1 += bhi(v0.x); a2 += blo(v0.y); a3 += bhi(v0.y);
    a4 += blo(v0.z); a5 += bhi(v0.z); a6 += blo(v0.w); a7 += bhi(v0.w);
    dot += av0 * blo(w0.x) + av1 * bhi(w0.x) + av2 * blo(w0.y) + av3 * bhi(w0.y);
  }
  if (js + 12 < rem) {
    int u0 = csr[j + js + 12];
    uint4 v0 = *(const uint4*)(h + (size_t)u0 * HID + c * 8);
    uint2 w0 = *(const uint2*)(anb + (size_t)u0 * 64 + c * 4);
    a0 += blo(v0.x); a1 += bhi(v0.x); a2 += blo(v0.y); a3 += bhi(v0.y);
    a4 += blo(v0.z); a5 += bhi(v0.z); a6 += blo(v0.w); a7 += bhi(v0.w);
    dot += av0 * blo(w0.x) + av1 * bhi(w0.x) + av2 * blo(w0.y) + av3 * bhi(w0.y);
  }
  a0 += __shfl_xor(a0, 16); a0 += __shfl_xor(a0, 32);
  a1 += __shfl_xor(a1, 16); a1 += __shfl_xor(a1, 32);
  a2 += __shfl_xor(a2, 16); a2 += __shfl_xor(a2, 32);
  a3 += __shfl_xor(a3, 16); a3 += __shfl_xor(a3, 32);
  a4 += __shfl_xor(a4, 16); a4 += __shfl_xor(a4, 32);
  a5 += __shfl_xor(a5, 16); a5 += __shfl_xor(a5, 32);
  a6 += __shfl_xor(a6, 16); a6 += __shfl_xor(a6, 32);
  a7 += __shfl_xor(a7, 16); a7 += __shfl_xor(a7, 32);
  dot += __shfl_xor(dot, 1); dot += __shfl_xor(dot, 2);
  dot += __shfl_xor(dot, 4); dot += __shfl_xor(dot, 8);
  dot += __shfl_xor(dot, 16); dot += __shfl_xor(dot, 32);
  if (l < 16) {
    float r = (deg > 0) ? 1.0f / (float)deg : 0.0f;
    uint4 o;
    o.x = pack2(a0 * r, a1 * r); o.y = pack2(a2 * r, a3 * r);
    o.z = pack2(a4 * r, a5 * r); o.w = pack2(a6 * r, a7 * r);
    *(uint4*)(outb + (size_t)g * HID + c * 8) = o;
  }
  if (l == 0) {
    float m = (1.0f + dot) / (float)(deg + 1);  // self-loop dot = 1
    gout[g] = 1.0f / (1.0f + expf(-temp[0] * m));
  }
}

// ---- SAGE mean aggregation (1 wave / node, 16 neighbors / iter) ----
__device__ __forceinline__ void agg_b_body(int bid, int goff, const ushort* __restrict__ h,
                                           const int* __restrict__ rowptr,
                                           const int* __restrict__ rowend,
                                           const int* __restrict__ csr,
                                           ushort* __restrict__ outb, int n) {
  int g = goff + bid * 4 + (threadIdx.x >> 6);
  if (g >= n) return;
  const int l = threadIdx.x & 63;
  const int js = l >> 4;
  const int c = l & 15;
  int beg = rowptr[g], end = rowend[g];
  int deg = end - beg;
  float a0=0,a1=0,a2=0,a3=0,a4=0,a5=0,a6=0,a7=0;
  int j = beg;
  int jend = beg + (deg & ~15);
  for (; j < jend; j += 16) {
    int u0 = csr[j + js];
    int u1 = csr[j + js + 4];
    int u2 = csr[j + js + 8];
    int u3 = csr[j + js + 12];
    uint4 v0 = *(const uint4*)(h + (size_t)u0 * HID + c * 8);
    uint4 v1 = *(const uint4*)(h + (size_t)u1 * HID + c * 8);
    uint4 v2 = *(const uint4*)(h + (size_t)u2 * HID + c * 8);
    uint4 v3 = *(const uint4*)(h + (size_t)u3 * HID + c * 8);
    a0 += (blo(v0.x) + blo(v1.x)) + (blo(v2.x) + blo(v3.x));
    a1 += (bhi(v0.x) + bhi(v1.x)) + (bhi(v2.x) + bhi(v3.x));
    a2 += (blo(v0.y) + blo(v1.y)) + (blo(v2.y) + blo(v3.y));
    a3 += (bhi(v0.y) + bhi(v1.y)) + (bhi(v2.y) + bhi(v3.y));
    a4 += (blo(v0.z) + blo(v1.z)) + (blo(v2.z) + blo(v3.z));
    a5 += (bhi(v0.z) + bhi(v1.z)) + (bhi(v2.z) + bhi(v3.z));
    a6 += (blo(v0.w) + blo(v1.w)) + (blo(v2.w) + blo(v3.w));
    a7 += (bhi(v0.w) + bhi(v1.w)) + (bhi(v2.w) + bhi(v3.w));
  }
  int rem = end - j;  // 0..15
  if (js < rem) {
    int u0 = csr[j + js];
    uint4 v0 = *(const uint4*)(h + (size_t)u0 * HID + c * 8);
    a0 += blo(v0.x); a1 += bhi(v0.x); a2 += blo(v0.y); a3 += bhi(v0.y);
    a4 += blo(v0.z); a5 += bhi(v0.z); a6 += blo(v0.w); a7 += bhi(v0.w);
  }
  if (js + 4 < rem) {
    int u0 = csr[j + js + 4];
    uint4 v0 = *(const uint4*)(h + (size_t)u0 * HID + c * 8);
    a0 += blo(v0.x); a1 += bhi(v0.x); a2 += blo(v0.y); a3 += bhi(v0.y);
    a4 += blo(v0.z); a5 += bhi(v0.z); a6 += blo(v0.w); a7 += bhi(v0.w);
  }
  if (js + 8 < rem) {
    int u0 = csr[j + js + 8];
    uint4 v0 = *(const uint4*)(h + (size_t)u0 * HID + c * 8);
    a0 += blo(v0.x); a1 += bhi(v0.x); a2 += blo(v0.y); a3 += bhi(v0.y);
    a4 += blo(v0.z); a5 += bhi(v0.z); a6 += blo(v0.w); a7 += bhi(v0.w);
  }
  if (js + 12 < rem) {
    int u0 = csr[j + js + 12];
    uint4 v0 = *(const uint4*)(h + (size_t)u0 * HID + c * 8);
    a0 += blo(v0.x); a1 += bhi(v0.x); a2 += blo(v0.y); a3 += bhi(v0.y);
    a4 += blo(v0.z); a5 += bhi(v0.z); a6 += blo(v0.w); a7 += bhi(v0.w);
  }
  a0 += __shfl_xor(a0, 16); a0 += __shfl_xor(a0, 32);
  a1 += __shfl_xor(a1, 16); a1 += __shfl_xor(a1, 32);
  a2 += __shfl_xor(a2, 16); a2 += __shfl_xor(a2, 32);
  a3 += __shfl_xor(a3, 16); a3 += __shfl_xor(a3, 32);
  a4 += __shfl_xor(a4, 16); a4 += __shfl_xor(a4, 32);
  a5 += __shfl_xor(a5, 16); a5 += __shfl_xor(a5, 32);
  a6 += __shfl_xor(a6, 16); a6 += __shfl_xor(a6, 32);
  a7 += __shfl_xor(a7, 16); a7 += __shfl_xor(a7, 32);
  if (l < 16) {
    float r = (deg > 0) ? 1.0f / (float)deg : 0.0f;
    uint4 o;
    o.x = pack2(a0 * r, a1 * r); o.y = pack2(a2 * r, a3 * r);
    o.z = pack2(a4 * r, a5 * r); o.w = pack2(a6 * r, a7 * r);
    *(uint4*)(outb + (size_t)g * HID + c * 8) = o;
  }
}

// ---- MFMA linear body: C = A1@W1^T (+ A2@W2^T) + bias, bf16 in/out ----
// K=64 staged per barrier pair; stats buffer is 8-way replicated (bid&7).
template <int NPARTS, bool STATS, bool ORELU>
__device__ __forceinline__ void mlin_body(
    int bid, const ushort* __restrict__ A1, const ushort* __restrict__ A2, int K,
    const ushort* __restrict__ W1, const ushort* __restrict__ W2,
    const float* __restrict__ bias, ushort* __restrict__ C,
    float* __restrict__ stats, int M, ushort* As, ushort* Bs) {
  const int tid = threadIdx.x;
  const int w = tid >> 6, l = tid & 63;
  const int mbase = bid * 128;
  const int lm = l & 15, lq = l >> 4;
  floatx4 acc[2][8];
#pragma unroll
  for (int mt = 0; mt < 2; ++mt)
#pragma unroll
    for (int nt = 0; nt < 8; ++nt) {
      floatx4 z = {0.f, 0.f, 0.f, 0.f};
      acc[mt][nt] = z;
    }

  for (int part = 0; part < NPARTS; ++part) {
    const ushort* Ap = part ? A2 : A1;
    const ushort* Wp = part ? W2 : W1;
    for (int kh = 0; kh < K; kh += 64) {
      if (part || kh) __syncthreads();  // protect LDS overwrite
#pragma unroll
      for (int k4 = 0; k4 < 2; ++k4) {
        int k0 = kh + k4 * 32;
#pragma unroll
        for (int i = 0; i < 2; ++i) {
          int s = w * 2 + i;
          int rt = s * 16 + (l >> 2);
          int q = (l & 3) ^ ((rt >> 1) & 3);
          int grow = mbase + rt; grow = grow < M ? grow : M - 1;
          async_cp16(Ap + (size_t)grow * K + k0 + q * 8, &As[k4 * 4096 + s * 512]);
          async_cp16(Wp + (size_t)rt * K + k0 + q * 8, &Bs[k4 * 4096 + s * 512]);
        }
      }
      __syncthreads();
#pragma unroll
      for (int k4 = 0; k4 < 2; ++k4) {
        const ushort* Ak = &As[k4 * 4096];
        const ushort* Bk = &Bs[k4 * 4096];
        short8 b[8];
#pragma unroll
        for (int nt = 0; nt < 8; ++nt) {
          int row = nt * 16 + lm;
          int q = lq ^ ((row >> 1) & 3);
          b[nt] = *(const short8*)&Bk[row * 32 + q * 8];
        }
#pragma unroll
        for (int mt = 0; mt < 2; ++mt) {
          int row = (w * 2 + mt) * 16 + lm;
          int q = lq ^ ((row >> 1) & 3);
          short8 a = *(const short8*)&Ak[row * 32 + q * 8];
#pragma unroll
          for (int nt = 0; nt < 8; ++nt)
            acc[mt][nt] = __builtin_amdgcn_mfma_f32_16x16x32_bf16(a, b[nt], acc[mt][nt], 0, 0, 0);
        }
      }
    }
  }

  if (STATS) __syncthreads();  // all waves done reading As before sred reuse
  float ss[8], qq[8];
#pragma unroll
  for (int nt = 0; nt < 8; ++nt) { ss[nt] = 0.f; qq[nt] = 0.f; }
#pragma unroll
  for (int nt = 0; nt < 8; ++nt) {
    int col = nt * 16 + lm;
    float bv = bias[col];
#pragma unroll
    for (int mt = 0; mt < 2; ++mt) {
      int rbase = mbase + (w * 2 + mt) * 16 + lq * 4;
#pragma unroll
      for (int r = 0; r < 4; ++r) {
        int grow = rbase + r;
        if (grow < M) {
          float val = acc[mt][nt][r] + bv;
          if (ORELU) val = fmaxf(val, 0.f);
          C[(size_t)grow * 128 + col] = f2b(val);
          if (STATS) { ss[nt] += val; qq[nt] += val * val; }
        }
      }
    }
  }
  if (STATS) {
    float* sred = (float*)As;
    if (tid < 256) sred[tid] = 0.f;
    __syncthreads();
#pragma unroll
    for (int nt = 0; nt < 8; ++nt) {
      ss[nt] += __shfl_xor(ss[nt], 16); ss[nt] += __shfl_xor(ss[nt], 32);
      qq[nt] += __shfl_xor(qq[nt], 16); qq[nt] += __shfl_xor(qq[nt], 32);
    }
    if (lq == 0) {
#pragma unroll
      for (int nt = 0; nt < 8; ++nt) {
        int col = nt * 16 + lm;
        atomicAdd(&sred[col], ss[nt]);
        atomicAdd(&sred[128 + col], qq[nt]);
      }
    }
    __syncthreads();
    float* sbase = stats + ((bid & 7) << 8);
    if (tid < 256) atomicAdd(&sbase[tid], sred[tid]);
  }
}

// ---- BatchNorm apply body (bf16 in-place; sums 8 stats replicas) ----
template <int ACT, int TPB>  // ACT: 0=relu, 1=sigmoid
__device__ __forceinline__ void bnb_body(int bid, int gB, ushort* __restrict__ buf,
                                         const float* __restrict__ stats,
                                         const float* __restrict__ gamma,
                                         const float* __restrict__ beta, int n) {
  const int S = gB * TPB;
  int idx = bid * TPB + threadIdx.x;
  const int c0 = (idx & 15) * 8;
  const float inv_n = 1.0f / (float)n;
  float sc[8], sh[8];
#pragma unroll
  for (int d = 0; d < 8; ++d) {
    int c = c0 + d;
    float s0 = 0.f, s1 = 0.f;
#pragma unroll
    for (int r2 = 0; r2 < 8; ++r2) {
      s0 += stats[(r2 << 8) + c];
      s1 += stats[(r2 << 8) + 128 + c];
    }
    float mu = s0 * inv_n;
    float var = s1 * inv_n - mu * mu;
    float s = rsqrtf(var + 1e-5f) * gamma[c];
    sc[d] = s;
    sh[d] = beta[c] - mu * s;
  }
  const int n16 = n * 16;
  for (; idx < n16; idx += S) {
    uint4 v = ((const uint4*)buf)[idx];
    float x[8] = {blo(v.x), bhi(v.x), blo(v.y), bhi(v.y),
                  blo(v.z), bhi(v.z), blo(v.w), bhi(v.w)};
#pragma unroll
    for (int d = 0; d < 8; ++d) {
      float y = x[d] * sc[d] + sh[d];
      x[d] = (ACT == 0) ? fmaxf(y, 0.f) : 1.0f / (1.0f + expf(-y));
    }
    uint4 o;
    o.x = pack2(x[0], x[1]); o.y = pack2(x[2], x[3]);
    o.z = pack2(x[4], x[5]); o.w = pack2(x[6], x[7]);
    ((uint4*)buf)[idx] = o;
  }
}

// ================= global kernels =================

// prep (cvtw | cvt | anorm2), one launch
__global__ void prep_kernel(
    const float* __restrict__ x, ushort* __restrict__ xb, int n4,
    const float* __restrict__ alpha, ushort* __restrict__ ab, ushort* __restrict__ anb, int n,
    const float* __restrict__ Wl, const float* __restrict__ Wr, const float* __restrict__ W0,
    const float* __restrict__ W1, const float* __restrict__ W2, const float* __restrict__ Wc,
    ushort* __restrict__ wb, ushort* __restrict__ wcb, float* __restrict__ stats,
    int* __restrict__ gcnt, int GW, int GC) {
  int b = blockIdx.x;
  if (b < GW) cvtw_body(b, Wl, Wr, W0, W1, W2, Wc, wb, wcb, stats, gcnt);
  else if (b < GW + GC) cvt_body(b - GW, x, xb, n4);
  else anorm2_body(b - GW - GC, alpha, ab, anb, n);
}

// ---------------- bucketed CSR build (atomic range reservation, no scans) ----

__device__ __forceinline__ void binAB_body(int bid, const int* __restrict__ src,
                                           const int* __restrict__ tgt,
                                           int* __restrict__ gcnt,
                                           int* __restrict__ ebuf,
                                           int e, int chunk, int nbk, int cap,
                                           int* hist) {
  int tid = threadIdx.x;
  for (int b = tid; b < nbk; b += 256) hist[b] = 0;
  __syncthreads();
  int i0 = bid * chunk;
  int i1 = min(e, i0 + chunk);
  for (int j = i0 + tid; j < i1; j += 256) atomicAdd(&hist[tgt[j] >> 9], 1);
  __syncthreads();
  for (int b = tid; b < nbk; b += 256) {
    int c = hist[b];
    hist[b] = c ? atomicAdd(&gcnt[b], c) : 0;
  }
  __syncthreads();
  for (int j = i0 + tid; j < i1; j += 256) {
    int t = tgt[j];
    int b = t >> 9;
    int pos = atomicAdd(&hist[b], 1);
    if (pos < cap) ebuf[(size_t)b * cap + pos] = ((t & 511) << 17) | src[j];
  }
}

// binAB (blocks [0,PBB)) || proto W0 GEMM (rest). Disjoint data.
__global__ __launch_bounds__(256) void k_binAB_w0(
    const int* __restrict__ src, const int* __restrict__ tgt,
    int* __restrict__ gcnt, int* __restrict__ ebuf, int e, int chunk, int nbk, int cap,
    const ushort* __restrict__ ab, const ushort* __restrict__ W0b,
    const float* __restrict__ b0, ushort* __restrict__ hproto,
    float* __restrict__ stats, int n) {
  __shared__ ushort As[8192];
  __shared__ ushort Bs[8192];
  if ((int)blockIdx.x < PBB)
    binAB_body(blockIdx.x, src, tgt, gcnt, ebuf, e, chunk, nbk, cap, (int*)As);
  else
    mlin_body<1, true, false>(blockIdx.x - PBB, ab, nullptr, 64, W0b, nullptr, b0,
                              hproto, stats, n, As, Bs);
}

// binC body (512 threads): per-bucket count + scan + scatter
__device__ __forceinline__ void binC_body(int b, const int* __restrict__ ebuf,
                                          const int* __restrict__ gcnt,
                                          int* __restrict__ rowptr, int* __restrict__ rowend,
                                          int* __restrict__ csr, int n, int cap,
                                          int* hist, int* scanbuf) {
  int tid = threadIdx.x;
  int seg0 = b * cap;
  int cnt = gcnt[b]; if (cnt > cap) cnt = cap;
  int seg1 = seg0 + cnt;
  hist[tid] = 0;
  __syncthreads();
  for (int j = seg0 + tid; j < seg1; j += 512)
    atomicAdd(&hist[ebuf[j] >> 17], 1);
  __syncthreads();
  int s = hist[tid];
  scanbuf[tid] = s;
  __syncthreads();
  for (int d = 1; d < 512; d <<= 1) {
    int add = (tid >= d) ? scanbuf[tid - d] : 0;
    __syncthreads();
    scanbuf[tid] += add;
    __syncthreads();
  }
  int ex = scanbuf[tid] - s;
  int node = b * 512 + tid;
  if (node < n) { rowptr[node] = seg0 + ex; rowend[node] = seg0 + ex + s; }
  hist[tid] = ex;
  __syncthreads();
  for (int j = seg0 + tid; j < seg1; j += 512) {
    int val = ebuf[j];
    int pos = atomicAdd(&hist[val >> 17], 1);
    csr[seg0 + pos] = val & 0x1FFFF;
  }
}

// binC (blocks [0,nbk), 512 thr) || proto BN0 sigmoid (rest, 512 thr)
__global__ __launch_bounds__(512) void k_binC_bnb(
    const int* __restrict__ ebuf, const int* __restrict__ gcnt,
    int* __restrict__ rowptr, int* __restrict__ rowend, int* __restrict__ csr,
    int n, int cap, int nbk,
    ushort* __restrict__ bnbuf, const float* __restrict__ bnstats,
    const float* __restrict__ gamma, const float* __restrict__ beta, int gB) {
  __shared__ int hist[512];
  __shared__ int scanbuf[512];
  if ((int)blockIdx.x < nbk)
    binC_body(blockIdx.x, ebuf, gcnt, rowptr, rowend, csr, n, cap, hist, scanbuf);
  else
    bnb_body<1, 512>(blockIdx.x - nbk, gB, bnbuf, bnstats, gamma, beta, n);
}

// ---------------- pure aggregation kernels (VGPR capped at 64) ----------------

__global__ __launch_bounds__(256, 8) void agg_gate_kernel(
    const ushort* __restrict__ h, const ushort* __restrict__ anb,
    const int* __restrict__ rowptr, const int* __restrict__ rowend,
    const int* __restrict__ csr,
    const float* __restrict__ temp, float* __restrict__ gout,
    ushort* __restrict__ outb, int n) {
  agg_gate_body(blockIdx.x, h, anb, rowptr, rowend, csr, temp, gout, outb, n);
}

__global__ __launch_bounds__(256, 8) void agg_b_kernel(
    const ushort* __restrict__ h, const int* __restrict__ rowptr,
    const int* __restrict__ rowend, const int* __restrict__ csr,
    ushort* __restrict__ outb, int goff, int n) {
  agg_b_body(blockIdx.x, goff, h, rowptr, rowend, csr, outb, n);
}

// agg_b (blocks [0,gAgg)) || bnb (trailing) — no mlin, footprint stays small
template <int ACT>
__global__ __launch_bounds__(256, 8) void k_agg_bnb(
    const ushort* __restrict__ h, const int* __restrict__ rowptr,
    const int* __restrict__ rowend, const int* __restrict__ csr,
    ushort* __restrict__ outb, int n, int gAgg,
    ushort* __restrict__ bnbuf, const float* __restrict__ bnstats,
    const float* __restrict__ gamma, const float* __restrict__ beta, int gBn) {
  if ((int)blockIdx.x < gAgg)
    agg_b_body(blockIdx.x, 0, h, rowptr, rowend, csr, outb, n);
  else
    bnb_body<ACT, 256>(blockIdx.x - gAgg, gBn, bnbuf, bnstats, gamma, beta, n);
}

// ---------------- combined launches (same-footprint roles only) --------------

// SAGE L0 GEMM w/ stats (blocks [0,gLin)) || proto W1 GEMM w/ stats (rest)
__global__ __launch_bounds__(256) void k_mlin_L0W1(
    const ushort* __restrict__ aggB, const ushort* __restrict__ hB,
    const ushort* __restrict__ Wl, const ushort* __restrict__ Wr,
    const float* __restrict__ bl, ushort* __restrict__ Cl, float* __restrict__ stl,
    const ushort* __restrict__ Ap, const ushort* __restrict__ Wp,
    const float* __restrict__ bp, ushort* __restrict__ Cp, float* __restrict__ stp,
    int M, int gLin) {
  __shared__ ushort As[8192];
  __shared__ ushort Bs[8192];
  if ((int)blockIdx.x < gLin)
    mlin_body<2, true, false>(blockIdx.x, aggB, hB, 128, Wl, Wr, bl, Cl, stl, M, As, Bs);
  else
    mlin_body<1, true, false>(blockIdx.x - gLin, Ap, nullptr, 128, Wp, nullptr, bp, Cp,
                              stp, M, As, Bs);
}

// SAGE mlin L1 w/ stats (blocks [0,gLin)) || proto W2 relu (rest)
__global__ __launch_bounds__(256) void k_mlin_mlin(
    const ushort* __restrict__ A1a, const ushort* __restrict__ A2a,
    const ushort* __restrict__ W1a, const ushort* __restrict__ W2a,
    const float* __restrict__ ba, ushort* __restrict__ Ca, float* __restrict__ statsa,
    const ushort* __restrict__ A1b, const ushort* __restrict__ W1b,
    const float* __restrict__ bb, ushort* __restrict__ Cb, int M, int gLin) {
  __shared__ ushort As[8192];
  __shared__ ushort Bs[8192];
  if ((int)blockIdx.x < gLin)
    mlin_body<2, true, false>(blockIdx.x, A1a, A2a, 128, W1a, W2a, ba, Ca, statsa, M, As, Bs);
  else
    mlin_body<1, false, true>(blockIdx.x - gLin, A1b, nullptr, 128, W1b, nullptr, bb, Cb,
                              nullptr, M, As, Bs);
}

// ---------------- fused SAGE GEMM2 + classifier (z stays in LDS) ------------
// Computes z = relu(agg@Wl2^T + h@Wr2^T + bl2) for 128 rows, stores the z-tile
// in LDS (bf16, stride ZSTR), then runs the classifier: part 0 A-frags read
// straight from the LDS z-tile, part 1 stages hproto; fused log_softmax -> out.
// Eliminates the hgnn global buffer entirely.
__global__ __launch_bounds__(256) void k_gemm2_cls(
    const ushort* __restrict__ aggB, const ushort* __restrict__ hB,
    const ushort* __restrict__ Wl2, const ushort* __restrict__ Wr2,
    const float* __restrict__ bl2,
    const ushort* __restrict__ hproto, const ushort* __restrict__ Wcb,
    const float* __restrict__ bc, float* __restrict__ Cout, int M) {
  __shared__ ushort smem[128 * ZSTR + 4096 + 1536];
  ushort* zt = smem;                       // 128 x ZSTR (z tile)
  ushort* Ah = smem + 128 * ZSTR;          // 128 x 32 hproto tile
  ushort* Bw = smem + 128 * ZSTR + 4096;   // 48 x 32 Wcb tile
  ushort* As = smem;                       // overlay for main GEMM (8192)
  ushort* Bs = smem + 8192;                // overlay (8192)
  const int tid = threadIdx.x;
  const int w = tid >> 6, l = tid & 63;
  const int mbase = blockIdx.x * 128;
  const int lm = l & 15, lq = l >> 4;
  floatx4 acc[2][8];
#pragma unroll
  for (int mt = 0; mt < 2; ++mt)
#pragma unroll
    for (int nt = 0; nt < 8; ++nt) {
      floatx4 z = {0.f, 0.f, 0.f, 0.f};
      acc[mt][nt] = z;
    }

  // main 2-part GEMM (K=128, staged K=64 per barrier pair)
  for (int part = 0; part < 2; ++part) {
    const ushort* Ap = part ? hB : aggB;
    const ushort* Wp = part ? Wr2 : Wl2;
    for (int kh = 0; kh < 128; kh += 64) {
      if (part || kh) __syncthreads();
#pragma unroll
      for (int k4 = 0; k4 < 2; ++k4) {
        int k0 = kh + k4 * 32;
#pragma unroll
        for (int i = 0; i < 2; ++i) {
          int s = w * 2 + i;
          int rt = s * 16 + (l >> 2);
          int q = (l & 3) ^ ((rt >> 1) & 3);
          int grow = mbase + rt; grow = grow < M ? grow : M - 1;
          async_cp16(Ap + (size_t)grow * 128 + k0 + q * 8, &As[k4 * 4096 + s * 512]);
          async_cp16(Wp + (size_t)rt * 128 + k0 + q * 8, &Bs[k4 * 4096 + s * 512]);
        }
      }
      __syncthreads();
#pragma unroll
      for (int k4 = 0; k4 < 2; ++k4) {
        const ushort* Ak = &As[k4 * 4096];
        const ushort* Bk = &Bs[k4 * 4096];
        short8 b[8];
#pragma unroll
        for (int nt = 0; nt < 8; ++nt) {
          int row = nt * 16 + lm;
          int q = lq ^ ((row >> 1) & 3);
          b[nt] = *(const short8*)&Bk[row * 32 + q * 8];
        }
#pragma unroll
        for (int mt = 0; mt < 2; ++mt) {
          int row = (w * 2 + mt) * 16 + lm;
          int q = lq ^ ((row >> 1) & 3);
          short8 a = *(const short8*)&Ak[row * 32 + q * 8];
#pragma unroll
          for (int nt = 0; nt < 8; ++nt)
            acc[mt][nt] = __builtin_amdgcn_mfma_f32_16x16x32_bf16(a, b[nt], acc[mt][nt], 0, 0, 0);
        }
      }
    }
  }
  __syncthreads();  // all As/Bs reads done before zt overwrite

  // epilogue: z = relu(acc + bias) -> zt (bf16)
#pragma unroll
  for (int nt = 0; nt < 8; ++nt) {
    int col = nt * 16 + lm;
    float bv = bl2[col];
#pragma unroll
    for (int mt = 0; mt < 2; ++mt) {
      int rloc = (w * 2 + mt) * 16 + lq * 4;
#pragma unroll
      for (int r = 0; r < 4; ++r) {
        float val = fmaxf(acc[mt][nt][r] + bv, 0.f);
        zt[(rloc + r) * ZSTR + col] = f2b(val);
      }
    }
  }
  __syncthreads();

  // classifier: acc2 = z @ Wc[:, :128]^T + hproto @ Wc[:, 128:]^T
  floatx4 acc2[2][3];
#pragma unroll
  for (int mt = 0; mt < 2; ++mt)
#pragma unroll
    for (int nt = 0; nt < 3; ++nt) {
      floatx4 z = {0.f, 0.f, 0.f, 0.f};
      acc2[mt][nt] = z;
    }

  // part 0: A from LDS z-tile (linear layout: lane lq reads cols k0+lq*8)
  for (int k0 = 0; k0 < 128; k0 += 32) {
    if (k0) __syncthreads();  // protect Bw overwrite
    if (w < 3) {
      int rt = w * 16 + (l >> 2);
      int q = (l & 3) ^ ((rt >> 1) & 3);
      async_cp16(Wcb + (size_t)rt * 256 + k0 + q * 8, &Bw[w * 512]);
    }
    __syncthreads();
    short8 b[3];
#pragma unroll
    for (int nt = 0; nt < 3; ++nt) {
      int row = nt * 16 + lm;
      int q = lq ^ ((row >> 1) & 3);
      b[nt] = *(const short8*)&Bw[row * 32 + q * 8];
    }
#pragma unroll
    for (int mt = 0; mt < 2; ++mt) {
      int row = (w * 2 + mt) * 16 + lm;
      short8 a = *(const short8*)&zt[row * ZSTR + k0 + lq * 8];
#pragma unroll
      for (int nt = 0; nt < 3; ++nt)
        acc2[mt][nt] = __builtin_amdgcn_mfma_f32_16x16x32_bf16(a, b[nt], acc2[mt][nt], 0, 0, 0);
    }
  }
  // part 1: A = hproto (staged), B = Wcb cols 128..255
  for (int k0 = 0; k0 < 128; k0 += 32) {
    __syncthreads();  // protect Ah/Bw overwrite
#pragma unroll
    for (int i = 0; i < 2; ++i) {
      int s = w * 2 + i;
      int rt = s * 16 + (l >> 2);
      int q = (l & 3) ^ ((rt >> 1) & 3);
      int grow = mbase + rt; grow = grow < M ? grow : M - 1;
      async_cp16(hproto + (size_t)grow * 128 + k0 + q * 8, &Ah[s * 512]);
    }
    if (w < 3) {
      int rt = w * 16 + (l >> 2);
      int q = (l & 3) ^ ((rt >> 1) & 3);
      async_cp16(Wcb + (size_t)rt * 256 + 128 + k0 + q * 8, &Bw[w * 512]);
    }
    __syncthreads();
    short8 b[3];
#pragma unroll
    for (int nt = 0; nt < 3; ++nt) {
      int row = nt * 16 + lm;
      int q = lq ^ ((row >> 1) & 3);
      b[nt] = *(const short8*)&Bw[row * 32 + q * 8];
    }
#pragma unroll
    for (int mt = 0; mt < 2; ++mt) {
      int row = (w * 2 + mt) * 16 + lm;
      int q = lq ^ ((row >> 1) & 3);
      short8 a = *(const short8*)&Ah[row * 32 + q * 8];
#pragma unroll
      for (int nt = 0; nt < 3; ++nt)
        acc2[mt][nt] = __builtin_amdgcn_mfma_f32_16x16x32_bf16(a, b[nt], acc2[mt][nt], 0, 0, 0);
    }
  }

  // fused log_softmax epilogue
  float b0v = bc[lm], b1v = bc[lm + 16];
  float b2v = (lm < 8) ? bc[lm + 32] : 0.f;
#pragma unroll
  for (int mt = 0; mt < 2; ++mt) {
#pragma unroll
    for (int r = 0; r < 4; ++r) {
      int grow = mbase + (w * 2 + mt) * 16 + lq * 4 + r;
      float v0 = acc2[mt][0][r] + b0v;
      float v1 = acc2[mt][1][r] + b1v;
      float v2 = (lm < 8) ? acc2[mt][2][r] + b2v : -3.4e38f;
      float m = fmaxf(fmaxf(v0, v1), v2);
      m = fmaxf(m, __shfl_xor(m, 1)); m = fmaxf(m, __shfl_xor(m, 2));
      m = fmaxf(m, __shfl_xor(m, 4)); m = fmaxf(m, __shfl_xor(m, 8));
      float s = expf(v0 - m) + expf(v1 - m) + ((lm < 8) ? expf(v2 - m) : 0.f);
      s += __shfl_xor(s, 1); s += __shfl_xor(s, 2);
      s += __shfl_xor(s, 4); s += __shfl_xor(s, 8);
      float ls = m + logf(s);
      if (grow < M) {
        Cout[(size_t)grow * OUTC + lm] = v0 - ls;
        Cout[(size_t)grow * OUTC + lm + 16] = v1 - ls;
        if (lm < 8) Cout[(size_t)grow * OUTC + lm + 32] = v2 - ls;
      }
    }
  }
}

// ---------------- standalone kernels ----------------

template <int ACT>
__global__ __launch_bounds__(256) void bnb_kernel(
    ushort* __restrict__ buf, const float* __restrict__ stats,
    const float* __restrict__ gamma, const float* __restrict__ beta, int n) {
  bnb_body<ACT, 256>(blockIdx.x, gridDim.x, buf, stats, gamma, beta, n);
}

// ---------------- launch ----------------

extern "C" void kernel_launch(void* const* d_in, const int* in_sizes, int n_in,
                              void* d_out, int out_size, void* d_ws, size_t ws_size,
                              hipStream_t stream) {
  const float* x       = (const float*)d_in[0];
  const float* alpha   = (const float*)d_in[1];
  const int*   eidx    = (const int*)d_in[2];
  const float* sage_Wl = (const float*)d_in[3];
  const float* sage_bl = (const float*)d_in[4];
  const float* sage_Wr = (const float*)d_in[5];
  const float* sage_g  = (const float*)d_in[6];
  const float* sage_b  = (const float*)d_in[7];
  const float* W0 = (const float*)d_in[8];
  const float* b0 = (const float*)d_in[9];
  const float* W1 = (const float*)d_in[10];
  const float* b1 = (const float*)d_in[11];
  const float* W2 = (const float*)d_in[12];
  const float* b2 = (const float*)d_in[13];
  const float* mg = (const float*)d_in[14];
  const float* mb = (const float*)d_in[15];
  const float* Wc = (const float*)d_in[16];
  const float* bc = (const float*)d_in[17];
  const float* temp = (const float*)d_in[18];
  float* out = (float*)d_out;

  const int n = in_sizes[0] / HID;  // 100000
  const int e = in_sizes[2] / 2;    // 1600000
  const int* src = eidx;
  const int* tgt = eidx + e;

  const int nbk = (n + 511) >> 9;
  const int chunkB = (e + PBB - 1) / PBB;
  // bucket capacity: 1.5x mean, rounded up to 64 (45-sigma slack for random graphs)
  const int cap = (int)((((long long)e * 512 / n) * 3 / 2 + 63) & ~63LL);

  // workspace layout: 4 N×128 bf16 regions (16B aligned)
  char* p = (char*)d_ws;
  ushort* B0 = (ushort*)p; p += (size_t)n * HID * 2;
  ushort* B1 = (ushort*)p; p += (size_t)n * HID * 2;
  ushort* B2 = (ushort*)p; p += (size_t)n * HID * 2;
  ushort* B3 = (ushort*)p; p += (size_t)n * HID * 2;
  ushort* wb     = (ushort*)p; p += (size_t)WTOT * 2;
  ushort* wcb    = (ushort*)p; p += (size_t)48 * 256 * 2;
  float* stats = (float*)p; p += 8192 * 4;  // 4 sets x 8 replicas x 256 floats
  int* gcnt   = (int*)p; p += NBK_MAX * 4;
  int* rowptr = (int*)p; p += (size_t)n * 4;
  int* rowend = (int*)p; p += (size_t)n * 4;
  int* csr    = (int*)p; p += (size_t)nbk * cap * 4;
  ushort* xb   = B0;
  ushort* anb  = B1;                       // N*64
  ushort* ab   = B1 + (size_t)n * 64;      // N*64
  int*    ebuf = (int*)B2;                 // nbk*cap*4 <= n*256; dead after binC
  ushort* hproto = B3;
  ushort* Wlb = wb, *Wrb = wb + 49152, *W0b = wb + 98304, *W1b = wb + 106496, *W2b = wb + 122880;
  // stats sets (each 2048 floats: 8 replicas x 256)
  float* stSage0 = stats;
  float* stSage1 = stats + 2048;
  float* stPr0   = stats + 4096;
  float* stPr1   = stats + 6144;

  const int T = 256;

  const int gLin = (n + 127) / 128;        // 782
  const int gBn = 1024;                    // 256-thr bnb blocks
  const int gBnH = 512;                    // 512-thr bnb blocks
  const int gAgg = (n + 3) >> 2;           // 25000 (1 wave/node, 4/block)
  const int GW = WTOT / 4 / T;             // 136 blocks (exact)
  const int GC = (n * (HID / 4) + T - 1) / T;          // cvt blocks
  const int GA = (int)(((size_t)n * 16 + T - 1) / T);  // anorm2 blocks

  // 1: prep (weights cvt + x cvt + alpha norm + stats/gcnt zero)
  prep_kernel<<<GW + GC + GA, T, 0, stream>>>(
      x, xb, n * (HID / 4), alpha, ab, anb, n,
      sage_Wl, sage_Wr, W0, W1, W2, Wc, wb, wcb, stats, gcnt, GW, GC);

  // 2: binAB (1024 blocks: hist + range reservation + scatter) || proto W0 GEMM
  k_binAB_w0<<<PBB + gLin, T, 0, stream>>>(src, tgt, gcnt, ebuf, e, chunkB, nbk, cap,
                                           ab, W0b, b0, hproto, stPr0, n);

  // 3: binC (512-thr per-bucket sort) || proto BN0 (sigmoid)
  k_binC_bnb<<<nbk + gBnH, 512, 0, stream>>>(ebuf, gcnt, rowptr, rowend, csr,
                                             n, cap, nbk,
                                             hproto, stPr0, mg, mb, gBnH);

  // 4: L0 aggregate + gate (pure)
  agg_gate_kernel<<<gAgg, T, 0, stream>>>(xb, anb, rowptr, rowend, csr, temp,
                                          out + (size_t)n * OUTC, B2, n);

  // 5: SAGE L0 GEMM || proto W1 GEMM (both with stats)
  k_mlin_L0W1<<<2 * gLin, T, 0, stream>>>(B2, B0, Wlb, Wrb, sage_bl, B1, stSage0,
                                          hproto, W1b, b1, hproto, stPr1, n, gLin);

  // 6: SAGE BN0 (relu)
  bnb_kernel<0><<<gBn, T, 0, stream>>>(B1, stSage0, sage_g, sage_b, n);

  // 7: SAGE L1 aggregate || proto BN1 sigmoid (trailing)
  k_agg_bnb<1><<<gAgg + gBn, T, 0, stream>>>(B1, rowptr, rowend, csr, B2, n, gAgg,
                                             hproto, stPr1, mg + HID, mb + HID, gBn);

  // 8: SAGE L1 GEMM || proto W2 GEMM (relu fused)
  k_mlin_mlin<<<2 * gLin, T, 0, stream>>>(B2, B1, Wlb + 16384, Wrb + 16384,
                                          sage_bl + HID, B0, stSage1,
                                          hproto, W2b, b2, hproto, n, gLin);

  // 9: SAGE BN1 (relu)
  bnb_kernel<0><<<gBn, T, 0, stream>>>(B0, stSage1, sage_g + HID, sage_b + HID, n);

  // 10: SAGE L2 aggregate (pure, full)
  agg_b_kernel<<<gAgg, T, 0, stream>>>(B0, rowptr, rowend, csr, B2, 0, n);

  // 11: fused SAGE GEMM2 + classifier (z-tile in LDS; no hgnn buffer)
  k_gemm2_cls<<<gLin, T, 0, stream>>>(B2, B0, Wlb + 32768, Wrb + 32768,
                                      sage_bl + 2 * HID, hproto, wcb, bc, out, n);
}

// Round 13
// 614.088 us; speedup vs baseline: 1.3034x; 1.0199x over previous
//
#include <hip/hip_runtime.h>
#include <cstdint>
#include <cstddef>

#define HID 128
#define OUTC 40
#define WTOT 139264  // Wl 49152 | Wr 49152 | W0 8192 | W1 16384 | W2 16384
#define PBB 1024     // blocks for the edge-binning scatter pass
#define NBK_MAX 256  // max buckets (512 nodes each)
#define ZSTR 140     // zt LDS row stride (ushorts): odd word-stride => <=2-way banks

typedef __attribute__((ext_vector_type(8))) short short8;
typedef __attribute__((ext_vector_type(4))) float floatx4;

__device__ __forceinline__ unsigned short f2b(float f) {
  unsigned int u = __float_as_uint(f);
  unsigned int r = u + 0x7FFFu + ((u >> 16) & 1u);
  return (unsigned short)(r >> 16);
}
__device__ __forceinline__ float blo(unsigned int u) { return __uint_as_float(u << 16); }
__device__ __forceinline__ float bhi(unsigned int u) { return __uint_as_float(u & 0xFFFF0000u); }
__device__ __forceinline__ unsigned int pack2(float a, float b) {
  return (unsigned int)f2b(a) | ((unsigned int)f2b(b) << 16);
}

__device__ __forceinline__ void async_cp16(const ushort* g, ushort* l) {
  __builtin_amdgcn_global_load_lds((const __attribute__((address_space(1))) void*)g,
                                   (__attribute__((address_space(3))) void*)l, 16, 0, 0);
}

// ================= device bodies =================

__device__ __forceinline__ void cvt_body(int bid, const float* __restrict__ in,
                                         ushort* __restrict__ out, int n4) {
  int i = bid * 256 + threadIdx.x;
  if (i >= n4) return;
  float4 v = ((const float4*)in)[i];
  ushort4 o;
  o.x = f2b(v.x); o.y = f2b(v.y); o.z = f2b(v.z); o.w = f2b(v.w);
  ((ushort4*)out)[i] = o;
}

__device__ __forceinline__ void cvtw_body(int bid, const float* __restrict__ Wl,
                                          const float* __restrict__ Wr, const float* __restrict__ W0,
                                          const float* __restrict__ W1, const float* __restrict__ W2,
                                          const float* __restrict__ Wc, ushort* __restrict__ wb,
                                          ushort* __restrict__ wcb, float* __restrict__ stats,
                                          int* __restrict__ gcnt) {
  int gid = bid * 256 + threadIdx.x;
  if (gid < 8192) stats[gid] = 0.0f;  // 4 sets x 8 replicas x 256
  if (gid < NBK_MAX) gcnt[gid] = 0;
  if (gid < 48 * 64) {  // wcb: 48x256 bf16, rows 40..47 zero
    int row = gid >> 6;
    ushort4 o;
    if (row < 40) {
      float4 v = *(const float4*)(Wc + (size_t)gid * 4);
      o.x = f2b(v.x); o.y = f2b(v.y); o.z = f2b(v.z); o.w = f2b(v.w);
    } else {
      o.x = 0; o.y = 0; o.z = 0; o.w = 0;
    }
    ((ushort4*)wcb)[gid] = o;
  }
  int e4 = gid * 4;
  if (e4 < WTOT) {
    const float* s; int off;
    if (e4 < 49152)       { s = Wl; off = 0; }
    else if (e4 < 98304)  { s = Wr; off = 49152; }
    else if (e4 < 106496) { s = W0; off = 98304; }
    else if (e4 < 122880) { s = W1; off = 106496; }
    else                  { s = W2; off = 122880; }
    float4 v = *(const float4*)(s + (e4 - off));
    ushort4 o;
    o.x = f2b(v.x); o.y = f2b(v.y); o.z = f2b(v.z); o.w = f2b(v.w);
    *(ushort4*)(wb + e4) = o;
  }
}

__device__ __forceinline__ void anorm2_body(int bid, const float* __restrict__ alpha,
                                            ushort* __restrict__ ab, ushort* __restrict__ anb,
                                            int n) {
  int g = (bid * 256 + threadIdx.x) >> 4;  // 16 lanes/node
  int lane = threadIdx.x & 15;
  if (g >= n) return;
  const float4 a = *(const float4*)(alpha + (size_t)g * 64 + lane * 4);
  ushort4 raw;
  raw.x = f2b(a.x); raw.y = f2b(a.y); raw.z = f2b(a.z); raw.w = f2b(a.w);
  *(ushort4*)(ab + (size_t)g * 64 + lane * 4) = raw;
  float d = a.x * a.x + a.y * a.y + a.z * a.z + a.w * a.w;
  d += __shfl_xor(d, 1); d += __shfl_xor(d, 2);
  d += __shfl_xor(d, 4); d += __shfl_xor(d, 8);
  float r = 1.0f / fmaxf(sqrtf(d), 1e-12f);
  ushort4 o;
  o.x = f2b(a.x * r); o.y = f2b(a.y * r); o.z = f2b(a.z * r); o.w = f2b(a.w * r);
  *(ushort4*)(anb + (size_t)g * 64 + lane * 4) = o;
}

// ---- fused layer-0 aggregate + gate (1 wave / node, 16 neighbors / iter) ----
__device__ __forceinline__ void agg_gate_body(int bid, const ushort* __restrict__ h,
                                              const ushort* __restrict__ anb,
                                              const int* __restrict__ rowptr,
                                              const int* __restrict__ rowend,
                                              const int* __restrict__ csr,
                                              const float* __restrict__ temp,
                                              float* __restrict__ gout,
                                              ushort* __restrict__ outb, int n) {
  int g = bid * 4 + (threadIdx.x >> 6);  // 1 wave per node
  if (g >= n) return;
  const int l = threadIdx.x & 63;
  const int js = l >> 4;   // neighbor slot 0..3
  const int c = l & 15;    // 16B chunk of the 256B h row / 8B chunk of anb row
  int beg = rowptr[g], end = rowend[g];
  int deg = end - beg;
  uint2 av = *(const uint2*)(anb + (size_t)g * 64 + c * 4);
  float av0 = blo(av.x), av1 = bhi(av.x), av2 = blo(av.y), av3 = bhi(av.y);
  float a0=0,a1=0,a2=0,a3=0,a4=0,a5=0,a6=0,a7=0;
  float dot = 0.f;
  int j = beg;
  int jend = beg + (deg & ~15);
  for (; j < jend; j += 16) {
    int u0 = csr[j + js];
    int u1 = csr[j + js + 4];
    int u2 = csr[j + js + 8];
    int u3 = csr[j + js + 12];
    uint4 v0 = *(const uint4*)(h + (size_t)u0 * HID + c * 8);
    uint4 v1 = *(const uint4*)(h + (size_t)u1 * HID + c * 8);
    uint4 v2 = *(const uint4*)(h + (size_t)u2 * HID + c * 8);
    uint4 v3 = *(const uint4*)(h + (size_t)u3 * HID + c * 8);
    uint2 w0 = *(const uint2*)(anb + (size_t)u0 * 64 + c * 4);
    uint2 w1 = *(const uint2*)(anb + (size_t)u1 * 64 + c * 4);
    uint2 w2 = *(const uint2*)(anb + (size_t)u2 * 64 + c * 4);
    uint2 w3 = *(const uint2*)(anb + (size_t)u3 * 64 + c * 4);
    a0 += (blo(v0.x) + blo(v1.x)) + (blo(v2.x) + blo(v3.x));
    a1 += (bhi(v0.x) + bhi(v1.x)) + (bhi(v2.x) + bhi(v3.x));
    a2 += (blo(v0.y) + blo(v1.y)) + (blo(v2.y) + blo(v3.y));
    a3 += (bhi(v0.y) + bhi(v1.y)) + (bhi(v2.y) + bhi(v3.y));
    a4 += (blo(v0.z) + blo(v1.z)) + (blo(v2.z) + blo(v3.z));
    a5 += (bhi(v0.z) + bhi(v1.z)) + (bhi(v2.z) + bhi(v3.z));
    a6 += (blo(v0.w) + blo(v1.w)) + (blo(v2.w) + blo(v3.w));
    a7 += (bhi(v0.w) + bhi(v1.w)) + (bhi(v2.w) + bhi(v3.w));
    dot += av0 * ((blo(w0.x) + blo(w1.x)) + (blo(w2.x) + blo(w3.x)))
         + av1 * ((bhi(w0.x) + bhi(w1.x)) + (bhi(w2.x) + bhi(w3.x)))
         + av2 * ((blo(w0.y) + blo(w1.y)) + (blo(w2.y) + blo(w3.y)))
         + av3 * ((bhi(w0.y) + bhi(w1.y)) + (bhi(w2.y) + bhi(w3.y)));
  }
  int rem = end - j;  // 0..15
  if (js < rem) {
    int u0 = csr[j + js];
    uint4 v0 = *(const uint4*)(h + (size_t)u0 * HID + c * 8);
    uint2 w0 = *(const uint2*)(anb + (size_t)u0 * 64 + c * 4);
    a0 += blo(v0.x); a1 += bhi(v0.x); a2 += blo(v0.y); a3 += bhi(v0.y);
    a4 += blo(v0.z); a5 += bhi(v0.z); a6 += blo(v0.w); a7 += bhi(v0.w);
    dot += av0 * blo(w0.x) + av1 * bhi(w0.x) + av2 * blo(w0.y) + av3 * bhi(w0.y);
  }
  if (js + 4 < rem) {
    int u0 = csr[j + js + 4];
    uint4 v0 = *(const uint4*)(h + (size_t)u0 * HID + c * 8);
    uint2 w0 = *(const uint2*)(anb + (size_t)u0 * 64 + c * 4);
    a0 += blo(v0.x); a1 += bhi(v0.x); a2 += blo(v0.y); a3 += bhi(v0.y);
    a4 += blo(v0.z); a5 += bhi(v0.z); a6 += blo(v0.w); a7 += bhi(v0.w);
    dot += av0 * blo(w0.x) + av1 * bhi(w0.x) + av2 * blo(w0.y) + av3 * bhi(w0.y);
  }
  if (js + 8 < rem) {
    int u0 = csr[j + js + 8];
    uint4 v0 = *(const uint4*)(h + (size_t)u0 * HID + c * 8);
    uint2 w0 = *(const uint2*)(anb + (size_t)u0 * 64 + c * 4);
    a0 += blo(v0.x); a1 += bhi(v0.x); a2 += blo(v0.y); a3 += bhi(v0.y);
    a4 += blo(v0.z); a5 += bhi(v0.z); a6 += blo(v0.w); a7 += bhi(v0.w);
    dot += av0 * blo(w0.x) + av1 * bhi(w0.x) + av2 * blo(w0.y) + av3 * bhi(w0.y);
  }
  if (js + 12 < rem) {
    int u0 = csr[j + js + 12];
    uint4 v0 = *(const uint4*)(h + (size_t)u0 * HID + c * 8);
    uint2 w0 = *(const uint2*)(anb + (size_t)u0 * 64 + c * 4);
    a0 += blo(v0.x); a1 += bhi(v0.x); a2 += blo(v0.y); a3 += bhi(v0.y);
    a4 += blo(v0.z); a5 += bhi(v0.z); a6 += blo(v0.w); a7 += bhi(v0.w);
    dot += av0 * blo(w0.x) + av1 * bhi(w0.x) + av2 * blo(w0.y) + av3 * bhi(w0.y);
  }
  a0 += __shfl_xor(a0, 16); a0 += __shfl_xor(a0, 32);
  a1 += __shfl_xor(a1, 16); a1 += __shfl_xor(a1, 32);
  a2 += __shfl_xor(a2, 16); a2 += __shfl_xor(a2, 32);
  a3 += __shfl_xor(a3, 16); a3 += __shfl_xor(a3, 32);
  a4 += __shfl_xor(a4, 16); a4 += __shfl_xor(a4, 32);
  a5 += __shfl_xor(a5, 16); a5 += __shfl_xor(a5, 32);
  a6 += __shfl_xor(a6, 16); a6 += __shfl_xor(a6, 32);
  a7 += __shfl_xor(a7, 16); a7 += __shfl_xor(a7, 32);
  dot += __shfl_xor(dot, 1); dot += __shfl_xor(dot, 2);
  dot += __shfl_xor(dot, 4); dot += __shfl_xor(dot, 8);
  dot += __shfl_xor(dot, 16); dot += __shfl_xor(dot, 32);
  if (l < 16) {
    float r = (deg > 0) ? 1.0f / (float)deg : 0.0f;
    uint4 o;
    o.x = pack2(a0 * r, a1 * r); o.y = pack2(a2 * r, a3 * r);
    o.z = pack2(a4 * r, a5 * r); o.w = pack2(a6 * r, a7 * r);
    *(uint4*)(outb + (size_t)g * HID + c * 8) = o;
  }
  if (l == 0) {
    float m = (1.0f + dot) / (float)(deg + 1);  // self-loop dot = 1
    gout[g] = 1.0f / (1.0f + expf(-temp[0] * m));
  }
}

// ---- SAGE aggregation with fused BN-affine+relu on gathered elements ----
// Reads PRE-BN y; per element computes relu(y*sc+sh) using the baked sc/sh
// table (256 floats: sc[128] | sh[128]). Mean over neighbors as before.
__device__ __forceinline__ void agg_bf_body(int bid, const ushort* __restrict__ y,
                                            const int* __restrict__ rowptr,
                                            const int* __restrict__ rowend,
                                            const int* __restrict__ csr,
                                            const float* __restrict__ tbl,
                                            ushort* __restrict__ outb, int n) {
  int g = bid * 4 + (threadIdx.x >> 6);
  if (g >= n) return;
  const int l = threadIdx.x & 63;
  const int js = l >> 4;
  const int c = l & 15;
  const float4 scA = *(const float4*)(tbl + (c << 3));
  const float4 scB = *(const float4*)(tbl + (c << 3) + 4);
  const float4 shA = *(const float4*)(tbl + 128 + (c << 3));
  const float4 shB = *(const float4*)(tbl + 128 + (c << 3) + 4);
  int beg = rowptr[g], end = rowend[g];
  int deg = end - beg;
  float a0=0,a1=0,a2=0,a3=0,a4=0,a5=0,a6=0,a7=0;
#define ACCV(v)                                              \
  a0 += fmaxf(fmaf(blo((v).x), scA.x, shA.x), 0.f);          \
  a1 += fmaxf(fmaf(bhi((v).x), scA.y, shA.y), 0.f);          \
  a2 += fmaxf(fmaf(blo((v).y), scA.z, shA.z), 0.f);          \
  a3 += fmaxf(fmaf(bhi((v).y), scA.w, shA.w), 0.f);          \
  a4 += fmaxf(fmaf(blo((v).z), scB.x, shB.x), 0.f);          \
  a5 += fmaxf(fmaf(bhi((v).z), scB.y, shB.y), 0.f);          \
  a6 += fmaxf(fmaf(blo((v).w), scB.z, shB.z), 0.f);          \
  a7 += fmaxf(fmaf(bhi((v).w), scB.w, shB.w), 0.f);
  int j = beg;
  int jend = beg + (deg & ~15);
  for (; j < jend; j += 16) {
    int u0 = csr[j + js];
    int u1 = csr[j + js + 4];
    int u2 = csr[j + js + 8];
    int u3 = csr[j + js + 12];
    uint4 v0 = *(const uint4*)(y + (size_t)u0 * HID + c * 8);
    uint4 v1 = *(const uint4*)(y + (size_t)u1 * HID + c * 8);
    uint4 v2 = *(const uint4*)(y + (size_t)u2 * HID + c * 8);
    uint4 v3 = *(const uint4*)(y + (size_t)u3 * HID + c * 8);
    ACCV(v0) ACCV(v1) ACCV(v2) ACCV(v3)
  }
  int rem = end - j;  // 0..15
  if (js < rem) {
    uint4 v0 = *(const uint4*)(y + (size_t)csr[j + js] * HID + c * 8);
    ACCV(v0)
  }
  if (js + 4 < rem) {
    uint4 v0 = *(const uint4*)(y + (size_t)csr[j + js + 4] * HID + c * 8);
    ACCV(v0)
  }
  if (js + 8 < rem) {
    uint4 v0 = *(const uint4*)(y + (size_t)csr[j + js + 8] * HID + c * 8);
    ACCV(v0)
  }
  if (js + 12 < rem) {
    uint4 v0 = *(const uint4*)(y + (size_t)csr[j + js + 12] * HID + c * 8);
    ACCV(v0)
  }
#undef ACCV
  a0 += __shfl_xor(a0, 16); a0 += __shfl_xor(a0, 32);
  a1 += __shfl_xor(a1, 16); a1 += __shfl_xor(a1, 32);
  a2 += __shfl_xor(a2, 16); a2 += __shfl_xor(a2, 32);
  a3 += __shfl_xor(a3, 16); a3 += __shfl_xor(a3, 32);
  a4 += __shfl_xor(a4, 16); a4 += __shfl_xor(a4, 32);
  a5 += __shfl_xor(a5, 16); a5 += __shfl_xor(a5, 32);
  a6 += __shfl_xor(a6, 16); a6 += __shfl_xor(a6, 32);
  a7 += __shfl_xor(a7, 16); a7 += __shfl_xor(a7, 32);
  if (l < 16) {
    float r = (deg > 0) ? 1.0f / (float)deg : 0.0f;
    uint4 o;
    o.x = pack2(a0 * r, a1 * r); o.y = pack2(a2 * r, a3 * r);
    o.z = pack2(a4 * r, a5 * r); o.w = pack2(a6 * r, a7 * r);
    *(uint4*)(outb + (size_t)g * HID + c * 8) = o;
  }
}

// ---- MFMA linear body: C = A1@W1^T (+ A2@W2^T) + bias, bf16 in/out ----
// K=64 staged per barrier pair; stats buffer is 8-way replicated (bid&7).
template <int NPARTS, bool STATS, bool ORELU>
__device__ __forceinline__ void mlin_body(
    int bid, const ushort* __restrict__ A1, const ushort* __restrict__ A2, int K,
    const ushort* __restrict__ W1, const ushort* __restrict__ W2,
    const float* __restrict__ bias, ushort* __restrict__ C,
    float* __restrict__ stats, int M, ushort* As, ushort* Bs) {
  const int tid = threadIdx.x;
  const int w = tid >> 6, l = tid & 63;
  const int mbase = bid * 128;
  const int lm = l & 15, lq = l >> 4;
  floatx4 acc[2][8];
#pragma unroll
  for (int mt = 0; mt < 2; ++mt)
#pragma unroll
    for (int nt = 0; nt < 8; ++nt) {
      floatx4 z = {0.f, 0.f, 0.f, 0.f};
      acc[mt][nt] = z;
    }

  for (int part = 0; part < NPARTS; ++part) {
    const ushort* Ap = part ? A2 : A1;
    const ushort* Wp = part ? W2 : W1;
    for (int kh = 0; kh < K; kh += 64) {
      if (part || kh) __syncthreads();  // protect LDS overwrite
#pragma unroll
      for (int k4 = 0; k4 < 2; ++k4) {
        int k0 = kh + k4 * 32;
#pragma unroll
        for (int i = 0; i < 2; ++i) {
          int s = w * 2 + i;
          int rt = s * 16 + (l >> 2);
          int q = (l & 3) ^ ((rt >> 1) & 3);
          int grow = mbase + rt; grow = grow < M ? grow : M - 1;
          async_cp16(Ap + (size_t)grow * K + k0 + q * 8, &As[k4 * 4096 + s * 512]);
          async_cp16(Wp + (size_t)rt * K + k0 + q * 8, &Bs[k4 * 4096 + s * 512]);
        }
      }
      __syncthreads();
#pragma unroll
      for (int k4 = 0; k4 < 2; ++k4) {
        const ushort* Ak = &As[k4 * 4096];
        const ushort* Bk = &Bs[k4 * 4096];
        short8 b[8];
#pragma unroll
        for (int nt = 0; nt < 8; ++nt) {
          int row = nt * 16 + lm;
          int q = lq ^ ((row >> 1) & 3);
          b[nt] = *(const short8*)&Bk[row * 32 + q * 8];
        }
#pragma unroll
        for (int mt = 0; mt < 2; ++mt) {
          int row = (w * 2 + mt) * 16 + lm;
          int q = lq ^ ((row >> 1) & 3);
          short8 a = *(const short8*)&Ak[row * 32 + q * 8];
#pragma unroll
          for (int nt = 0; nt < 8; ++nt)
            acc[mt][nt] = __builtin_amdgcn_mfma_f32_16x16x32_bf16(a, b[nt], acc[mt][nt], 0, 0, 0);
        }
      }
    }
  }

  if (STATS) __syncthreads();  // all waves done reading As before sred reuse
  float ss[8], qq[8];
#pragma unroll
  for (int nt = 0; nt < 8; ++nt) { ss[nt] = 0.f; qq[nt] = 0.f; }
#pragma unroll
  for (int nt = 0; nt < 8; ++nt) {
    int col = nt * 16 + lm;
    float bv = bias[col];
#pragma unroll
    for (int mt = 0; mt < 2; ++mt) {
      int rbase = mbase + (w * 2 + mt) * 16 + lq * 4;
#pragma unroll
      for (int r = 0; r < 4; ++r) {
        int grow = rbase + r;
        if (grow < M) {
          float val = acc[mt][nt][r] + bv;
          if (ORELU) val = fmaxf(val, 0.f);
          C[(size_t)grow * 128 + col] = f2b(val);
          if (STATS) { ss[nt] += val; qq[nt] += val * val; }
        }
      }
    }
  }
  if (STATS) {
    float* sred = (float*)As;
    if (tid < 256) sred[tid] = 0.f;
    __syncthreads();
#pragma unroll
    for (int nt = 0; nt < 8; ++nt) {
      ss[nt] += __shfl_xor(ss[nt], 16); ss[nt] += __shfl_xor(ss[nt], 32);
      qq[nt] += __shfl_xor(qq[nt], 16); qq[nt] += __shfl_xor(qq[nt], 32);
    }
    if (lq == 0) {
#pragma unroll
      for (int nt = 0; nt < 8; ++nt) {
        int col = nt * 16 + lm;
        atomicAdd(&sred[col], ss[nt]);
        atomicAdd(&sred[128 + col], qq[nt]);
      }
    }
    __syncthreads();
    float* sbase = stats + ((bid & 7) << 8);
    if (tid < 256) atomicAdd(&sbase[tid], sred[tid]);
  }
}

// ---- BatchNorm apply body (stats-summing variant; sigmoid for proto) ----
template <int ACT, int TPB>  // ACT: 0=relu, 1=sigmoid
__device__ __forceinline__ void bnb_body(int bid, int gB, ushort* __restrict__ buf,
                                         const float* __restrict__ stats,
                                         const float* __restrict__ gamma,
                                         const float* __restrict__ beta, int n) {
  const int S = gB * TPB;
  int idx = bid * TPB + threadIdx.x;
  const int c0 = (idx & 15) * 8;
  const float inv_n = 1.0f / (float)n;
  float sc[8], sh[8];
#pragma unroll
  for (int d = 0; d < 8; ++d) {
    int c = c0 + d;
    float s0 = 0.f, s1 = 0.f;
#pragma unroll
    for (int r2 = 0; r2 < 8; ++r2) {
      s0 += stats[(r2 << 8) + c];
      s1 += stats[(r2 << 8) + 128 + c];
    }
    float mu = s0 * inv_n;
    float var = s1 * inv_n - mu * mu;
    float s = rsqrtf(var + 1e-5f) * gamma[c];
    sc[d] = s;
    sh[d] = beta[c] - mu * s;
  }
  const int n16 = n * 16;
  for (; idx < n16; idx += S) {
    uint4 v = ((const uint4*)buf)[idx];
    float x[8] = {blo(v.x), bhi(v.x), blo(v.y), bhi(v.y),
                  blo(v.z), bhi(v.z), blo(v.w), bhi(v.w)};
#pragma unroll
    for (int d = 0; d < 8; ++d) {
      float y = x[d] * sc[d] + sh[d];
      x[d] = (ACT == 0) ? fmaxf(y, 0.f) : 1.0f / (1.0f + expf(-y));
    }
    uint4 o;
    o.x = pack2(x[0], x[1]); o.y = pack2(x[2], x[3]);
    o.z = pack2(x[4], x[5]); o.w = pack2(x[6], x[7]);
    ((uint4*)buf)[idx] = o;
  }
}

// ---- table-driven BN apply (relu), out-of-place src->dst ----
template <int TPB>
__device__ __forceinline__ void bnb2_body(int bid, int gB, const ushort* __restrict__ src,
                                          ushort* __restrict__ dst,
                                          const float* __restrict__ tbl, int n) {
  const int S = gB * TPB;
  int idx = bid * TPB + threadIdx.x;
  const int c0 = (idx & 15) * 8;
  const float4 scA = *(const float4*)(tbl + c0);
  const float4 scB = *(const float4*)(tbl + c0 + 4);
  const float4 shA = *(const float4*)(tbl + 128 + c0);
  const float4 shB = *(const float4*)(tbl + 128 + c0 + 4);
  const int n16 = n * 16;
  for (; idx < n16; idx += S) {
    uint4 v = ((const uint4*)src)[idx];
    float x0 = fmaxf(fmaf(blo(v.x), scA.x, shA.x), 0.f);
    float x1 = fmaxf(fmaf(bhi(v.x), scA.y, shA.y), 0.f);
    float x2 = fmaxf(fmaf(blo(v.y), scA.z, shA.z), 0.f);
    float x3 = fmaxf(fmaf(bhi(v.y), scA.w, shA.w), 0.f);
    float x4 = fmaxf(fmaf(blo(v.z), scB.x, shB.x), 0.f);
    float x5 = fmaxf(fmaf(bhi(v.z), scB.y, shB.y), 0.f);
    float x6 = fmaxf(fmaf(blo(v.w), scB.z, shB.z), 0.f);
    float x7 = fmaxf(fmaf(bhi(v.w), scB.w, shB.w), 0.f);
    uint4 o;
    o.x = pack2(x0, x1); o.y = pack2(x2, x3);
    o.z = pack2(x4, x5); o.w = pack2(x6, x7);
    ((uint4*)dst)[idx] = o;
  }
}

// ================= global kernels =================

// prep (cvtw | cvt | anorm2), one launch
__global__ void prep_kernel(
    const float* __restrict__ x, ushort* __restrict__ xb, int n4,
    const float* __restrict__ alpha, ushort* __restrict__ ab, ushort* __restrict__ anb, int n,
    const float* __restrict__ Wl, const float* __restrict__ Wr, const float* __restrict__ W0,
    const float* __restrict__ W1, const float* __restrict__ W2, const float* __restrict__ Wc,
    ushort* __restrict__ wb, ushort* __restrict__ wcb, float* __restrict__ stats,
    int* __restrict__ gcnt, int GW, int GC) {
  int b = blockIdx.x;
  if (b < GW) cvtw_body(b, Wl, Wr, W0, W1, W2, Wc, wb, wcb, stats, gcnt);
  else if (b < GW + GC) cvt_body(b - GW, x, xb, n4);
  else anorm2_body(b - GW - GC, alpha, ab, anb, n);
}

// bake sc/sh table from 8-replica stats (1 block x 128 threads)
__global__ void scsh_kernel(const float* __restrict__ stats,
                            const float* __restrict__ gamma,
                            const float* __restrict__ beta, int n,
                            float* __restrict__ tbl) {
  int t = threadIdx.x;
  if (t >= 128) return;
  float s0 = 0.f, s1 = 0.f;
#pragma unroll
  for (int r = 0; r < 8; ++r) {
    s0 += stats[(r << 8) + t];
    s1 += stats[(r << 8) + 128 + t];
  }
  float inv_n = 1.0f / (float)n;
  float mu = s0 * inv_n;
  float var = s1 * inv_n - mu * mu;
  float sc = rsqrtf(var + 1e-5f) * gamma[t];
  tbl[t] = sc;
  tbl[128 + t] = beta[t] - mu * sc;
}

// ---------------- bucketed CSR build (atomic range reservation, no scans) ----

__device__ __forceinline__ void binAB_body(int bid, const int* __restrict__ src,
                                           const int* __restrict__ tgt,
                                           int* __restrict__ gcnt,
                                           int* __restrict__ ebuf,
                                           int e, int chunk, int nbk, int cap,
                                           int* hist) {
  int tid = threadIdx.x;
  for (int b = tid; b < nbk; b += 256) hist[b] = 0;
  __syncthreads();
  int i0 = bid * chunk;
  int i1 = min(e, i0 + chunk);
  for (int j = i0 + tid; j < i1; j += 256) atomicAdd(&hist[tgt[j] >> 9], 1);
  __syncthreads();
  for (int b = tid; b < nbk; b += 256) {
    int c = hist[b];
    hist[b] = c ? atomicAdd(&gcnt[b], c) : 0;
  }
  __syncthreads();
  for (int j = i0 + tid; j < i1; j += 256) {
    int t = tgt[j];
    int b = t >> 9;
    int pos = atomicAdd(&hist[b], 1);
    if (pos < cap) ebuf[(size_t)b * cap + pos] = ((t & 511) << 17) | src[j];
  }
}

// binAB (blocks [0,PBB)) || proto W0 GEMM (rest). Disjoint data.
__global__ __launch_bounds__(256) void k_binAB_w0(
    const int* __restrict__ src, const int* __restrict__ tgt,
    int* __restrict__ gcnt, int* __restrict__ ebuf, int e, int chunk, int nbk, int cap,
    const ushort* __restrict__ ab, const ushort* __restrict__ W0b,
    const float* __restrict__ b0, ushort* __restrict__ hproto,
    float* __restrict__ stats, int n) {
  __shared__ ushort As[8192];
  __shared__ ushort Bs[8192];
  if ((int)blockIdx.x < PBB)
    binAB_body(blockIdx.x, src, tgt, gcnt, ebuf, e, chunk, nbk, cap, (int*)As);
  else
    mlin_body<1, true, false>(blockIdx.x - PBB, ab, nullptr, 64, W0b, nullptr, b0,
                              hproto, stats, n, As, Bs);
}

// binC body (512 threads): per-bucket count + scan + scatter
__device__ __forceinline__ void binC_body(int b, const int* __restrict__ ebuf,
                                          const int* __restrict__ gcnt,
                                          int* __restrict__ rowptr, int* __restrict__ rowend,
                                          int* __restrict__ csr, int n, int cap,
                                          int* hist, int* scanbuf) {
  int tid = threadIdx.x;
  int seg0 = b * cap;
  int cnt = gcnt[b]; if (cnt > cap) cnt = cap;
  int seg1 = seg0 + cnt;
  hist[tid] = 0;
  __syncthreads();
  for (int j = seg0 + tid; j < seg1; j += 512)
    atomicAdd(&hist[ebuf[j] >> 17], 1);
  __syncthreads();
  int s = hist[tid];
  scanbuf[tid] = s;
  __syncthreads();
  for (int d = 1; d < 512; d <<= 1) {
    int add = (tid >= d) ? scanbuf[tid - d] : 0;
    __syncthreads();
    scanbuf[tid] += add;
    __syncthreads();
  }
  int ex = scanbuf[tid] - s;
  int node = b * 512 + tid;
  if (node < n) { rowptr[node] = seg0 + ex; rowend[node] = seg0 + ex + s; }
  hist[tid] = ex;
  __syncthreads();
  for (int j = seg0 + tid; j < seg1; j += 512) {
    int val = ebuf[j];
    int pos = atomicAdd(&hist[val >> 17], 1);
    csr[seg0 + pos] = val & 0x1FFFF;
  }
}

// binC (blocks [0,nbk), 512 thr) || proto BN0 sigmoid (rest, 512 thr)
__global__ __launch_bounds__(512) void k_binC_bnb(
    const int* __restrict__ ebuf, const int* __restrict__ gcnt,
    int* __restrict__ rowptr, int* __restrict__ rowend, int* __restrict__ csr,
    int n, int cap, int nbk,
    ushort* __restrict__ bnbuf, const float* __restrict__ bnstats,
    const float* __restrict__ gamma, const float* __restrict__ beta, int gB) {
  __shared__ int hist[512];
  __shared__ int scanbuf[512];
  if ((int)blockIdx.x < nbk)
    binC_body(blockIdx.x, ebuf, gcnt, rowptr, rowend, csr, n, cap, hist, scanbuf);
  else
    bnb_body<1, 512>(blockIdx.x - nbk, gB, bnbuf, bnstats, gamma, beta, n);
}

// ---------------- pure / small-footprint combined agg kernels ----------------

__global__ __launch_bounds__(256, 8) void agg_gate_kernel(
    const ushort* __restrict__ h, const ushort* __restrict__ anb,
    const int* __restrict__ rowptr, const int* __restrict__ rowend,
    const int* __restrict__ csr,
    const float* __restrict__ temp, float* __restrict__ gout,
    ushort* __restrict__ outb, int n) {
  agg_gate_body(blockIdx.x, h, anb, rowptr, rowend, csr, temp, gout, outb, n);
}

// agg-with-BN-fold (majority) || table-BN relu src->dst || optional proto BN
template <bool PROTO>
__global__ __launch_bounds__(256, 8) void k_aggf(
    const ushort* __restrict__ y, const int* __restrict__ rowptr,
    const int* __restrict__ rowend, const int* __restrict__ csr,
    const float* __restrict__ tbl, ushort* __restrict__ aggout,
    ushort* __restrict__ hdst, int n, int gAgg, int gB2,
    ushort* __restrict__ pbuf, const float* __restrict__ pstats,
    const float* __restrict__ pg, const float* __restrict__ pb, int gBP) {
  int b = blockIdx.x;
  if (b < gAgg)
    agg_bf_body(b, y, rowptr, rowend, csr, tbl, aggout, n);
  else if (b < gAgg + gB2)
    bnb2_body<256>(b - gAgg, gB2, y, hdst, tbl, n);
  else if (PROTO)
    bnb_body<1, 256>(b - gAgg - gB2, gBP, pbuf, pstats, pg, pb, n);
}

// ---------------- combined GEMM launches (same-footprint roles only) ---------

// SAGE L0 GEMM w/ stats (blocks [0,gLin)) || proto W1 GEMM w/ stats (rest)
__global__ __launch_bounds__(256) void k_mlin_L0W1(
    const ushort* __restrict__ aggB, const ushort* __restrict__ hB,
    const ushort* __restrict__ Wl, const ushort* __restrict__ Wr,
    const float* __restrict__ bl, ushort* __restrict__ Cl, float* __restrict__ stl,
    const ushort* __restrict__ Ap, const ushort* __restrict__ Wp,
    const float* __restrict__ bp, ushort* __restrict__ Cp, float* __restrict__ stp,
    int M, int gLin) {
  __shared__ ushort As[8192];
  __shared__ ushort Bs[8192];
  if ((int)blockIdx.x < gLin)
    mlin_body<2, true, false>(blockIdx.x, aggB, hB, 128, Wl, Wr, bl, Cl, stl, M, As, Bs);
  else
    mlin_body<1, true, false>(blockIdx.x - gLin, Ap, nullptr, 128, Wp, nullptr, bp, Cp,
                              stp, M, As, Bs);
}

// SAGE mlin L1 w/ stats (blocks [0,gLin)) || proto W2 relu (rest)
__global__ __launch_bounds__(256) void k_mlin_mlin(
    const ushort* __restrict__ A1a, const ushort* __restrict__ A2a,
    const ushort* __restrict__ W1a, const ushort* __restrict__ W2a,
    const float* __restrict__ ba, ushort* __restrict__ Ca, float* __restrict__ statsa,
    const ushort* __restrict__ A1b, const ushort* __restrict__ W1b,
    const float* __restrict__ bb, ushort* __restrict__ Cb, int M, int gLin) {
  __shared__ ushort As[8192];
  __shared__ ushort Bs[8192];
  if ((int)blockIdx.x < gLin)
    mlin_body<2, true, false>(blockIdx.x, A1a, A2a, 128, W1a, W2a, ba, Ca, statsa, M, As, Bs);
  else
    mlin_body<1, false, true>(blockIdx.x - gLin, A1b, nullptr, 128, W1b, nullptr, bb, Cb,
                              nullptr, M, As, Bs);
}

// ---------------- fused SAGE GEMM2 + classifier (z stays in LDS) ------------
__global__ __launch_bounds__(256) void k_gemm2_cls(
    const ushort* __restrict__ aggB, const ushort* __restrict__ hB,
    const ushort* __restrict__ Wl2, const ushort* __restrict__ Wr2,
    const float* __restrict__ bl2,
    const ushort* __restrict__ hproto, const ushort* __restrict__ Wcb,
    const float* __restrict__ bc, float* __restrict__ Cout, int M) {
  __shared__ ushort smem[128 * ZSTR + 4096 + 1536];
  ushort* zt = smem;                       // 128 x ZSTR (z tile)
  ushort* Ah = smem + 128 * ZSTR;          // 128 x 32 hproto tile
  ushort* Bw = smem + 128 * ZSTR + 4096;   // 48 x 32 Wcb tile
  ushort* As = smem;                       // overlay for main GEMM (8192)
  ushort* Bs = smem + 8192;                // overlay (8192)
  const int tid = threadIdx.x;
  const int w = tid >> 6, l = tid & 63;
  const int mbase = blockIdx.x * 128;
  const int lm = l & 15, lq = l >> 4;
  floatx4 acc[2][8];
#pragma unroll
  for (int mt = 0; mt < 2; ++mt)
#pragma unroll
    for (int nt = 0; nt < 8; ++nt) {
      floatx4 z = {0.f, 0.f, 0.f, 0.f};
      acc[mt][nt] = z;
    }

  for (int part = 0; part < 2; ++part) {
    const ushort* Ap = part ? hB : aggB;
    const ushort* Wp = part ? Wr2 : Wl2;
    for (int kh = 0; kh < 128; kh += 64) {
      if (part || kh) __syncthreads();
#pragma unroll
      for (int k4 = 0; k4 < 2; ++k4) {
        int k0 = kh + k4 * 32;
#pragma unroll
        for (int i = 0; i < 2; ++i) {
          int s = w * 2 + i;
          int rt = s * 16 + (l >> 2);
          int q = (l & 3) ^ ((rt >> 1) & 3);
          int grow = mbase + rt; grow = grow < M ? grow : M - 1;
          async_cp16(Ap + (size_t)grow * 128 + k0 + q * 8, &As[k4 * 4096 + s * 512]);
          async_cp16(Wp + (size_t)rt * 128 + k0 + q * 8, &Bs[k4 * 4096 + s * 512]);
        }
      }
      __syncthreads();
#pragma unroll
      for (int k4 = 0; k4 < 2; ++k4) {
        const ushort* Ak = &As[k4 * 4096];
        const ushort* Bk = &Bs[k4 * 4096];
        short8 b[8];
#pragma unroll
        for (int nt = 0; nt < 8; ++nt) {
          int row = nt * 16 + lm;
          int q = lq ^ ((row >> 1) & 3);
          b[nt] = *(const short8*)&Bk[row * 32 + q * 8];
        }
#pragma unroll
        for (int mt = 0; mt < 2; ++mt) {
          int row = (w * 2 + mt) * 16 + lm;
          int q = lq ^ ((row >> 1) & 3);
          short8 a = *(const short8*)&Ak[row * 32 + q * 8];
#pragma unroll
          for (int nt = 0; nt < 8; ++nt)
            acc[mt][nt] = __builtin_amdgcn_mfma_f32_16x16x32_bf16(a, b[nt], acc[mt][nt], 0, 0, 0);
        }
      }
    }
  }
  __syncthreads();  // all As/Bs reads done before zt overwrite

#pragma unroll
  for (int nt = 0; nt < 8; ++nt) {
    int col = nt * 16 + lm;
    float bv = bl2[col];
#pragma unroll
    for (int mt = 0; mt < 2; ++mt) {
      int rloc = (w * 2 + mt) * 16 + lq * 4;
#pragma unroll
      for (int r = 0; r < 4; ++r) {
        float val = fmaxf(acc[mt][nt][r] + bv, 0.f);
        zt[(rloc + r) * ZSTR + col] = f2b(val);
      }
    }
  }
  __syncthreads();

  floatx4 acc2[2][3];
#pragma unroll
  for (int mt = 0; mt < 2; ++mt)
#pragma unroll
    for (int nt = 0; nt < 3; ++nt) {
      floatx4 z = {0.f, 0.f, 0.f, 0.f};
      acc2[mt][nt] = z;
    }

  for (int k0 = 0; k0 < 128; k0 += 32) {
    if (k0) __syncthreads();
    if (w < 3) {
      int rt = w * 16 + (l >> 2);
      int q = (l & 3) ^ ((rt >> 1) & 3);
      async_cp16(Wcb + (size_t)rt * 256 + k0 + q * 8, &Bw[w * 512]);
    }
    __syncthreads();
    short8 b[3];
#pragma unroll
    for (int nt = 0; nt < 3; ++nt) {
      int row = nt * 16 + lm;
      int q = lq ^ ((row >> 1) & 3);
      b[nt] = *(const short8*)&Bw[row * 32 + q * 8];
    }
#pragma unroll
    for (int mt = 0; mt < 2; ++mt) {
      int row = (w * 2 + mt) * 16 + lm;
      short8 a = *(const short8*)&zt[row * ZSTR + k0 + lq * 8];
#pragma unroll
      for (int nt = 0; nt < 3; ++nt)
        acc2[mt][nt] = __builtin_amdgcn_mfma_f32_16x16x32_bf16(a, b[nt], acc2[mt][nt], 0, 0, 0);
    }
  }
  for (int k0 = 0; k0 < 128; k0 += 32) {
    __syncthreads();
#pragma unroll
    for (int i = 0; i < 2; ++i) {
      int s = w * 2 + i;
      int rt = s * 16 + (l >> 2);
      int q = (l & 3) ^ ((rt >> 1) & 3);
      int grow = mbase + rt; grow = grow < M ? grow : M - 1;
      async_cp16(hproto + (size_t)grow * 128 + k0 + q * 8, &Ah[s * 512]);
    }
    if (w < 3) {
      int rt = w * 16 + (l >> 2);
      int q = (l & 3) ^ ((rt >> 1) & 3);
      async_cp16(Wcb + (size_t)rt * 256 + 128 + k0 + q * 8, &Bw[w * 512]);
    }
    __syncthreads();
    short8 b[3];
#pragma unroll
    for (int nt = 0; nt < 3; ++nt) {
      int row = nt * 16 + lm;
      int q = lq ^ ((row >> 1) & 3);
      b[nt] = *(const short8*)&Bw[row * 32 + q * 8];
    }
#pragma unroll
    for (int mt = 0; mt < 2; ++mt) {
      int row = (w * 2 + mt) * 16 + lm;
      int q = lq ^ ((row >> 1) & 3);
      short8 a = *(const short8*)&Ah[row * 32 + q * 8];
#pragma unroll
      for (int nt = 0; nt < 3; ++nt)
        acc2[mt][nt] = __builtin_amdgcn_mfma_f32_16x16x32_bf16(a, b[nt], acc2[mt][nt], 0, 0, 0);
    }
  }

  float b0v = bc[lm], b1v = bc[lm + 16];
  float b2v = (lm < 8) ? bc[lm + 32] : 0.f;
#pragma unroll
  for (int mt = 0; mt < 2; ++mt) {
#pragma unroll
    for (int r = 0; r < 4; ++r) {
      int grow = mbase + (w * 2 + mt) * 16 + lq * 4 + r;
      float v0 = acc2[mt][0][r] + b0v;
      float v1 = acc2[mt][1][r] + b1v;
      float v2 = (lm < 8) ? acc2[mt][2][r] + b2v : -3.4e38f;
      float m = fmaxf(fmaxf(v0, v1), v2);
      m = fmaxf(m, __shfl_xor(m, 1)); m = fmaxf(m, __shfl_xor(m, 2));
      m = fmaxf(m, __shfl_xor(m, 4)); m = fmaxf(m, __shfl_xor(m, 8));
      float s = expf(v0 - m) + expf(v1 - m) + ((lm < 8) ? expf(v2 - m) : 0.f);
      s += __shfl_xor(s, 1); s += __shfl_xor(s, 2);
      s += __shfl_xor(s, 4); s += __shfl_xor(s, 8);
      float ls = m + logf(s);
      if (grow < M) {
        Cout[(size_t)grow * OUTC + lm] = v0 - ls;
        Cout[(size_t)grow * OUTC + lm + 16] = v1 - ls;
        if (lm < 8) Cout[(size_t)grow * OUTC + lm + 32] = v2 - ls;
      }
    }
  }
}

// ---------------- launch ----------------

extern "C" void kernel_launch(void* const* d_in, const int* in_sizes, int n_in,
                              void* d_out, int out_size, void* d_ws, size_t ws_size,
                              hipStream_t stream) {
  const float* x       = (const float*)d_in[0];
  const float* alpha   = (const float*)d_in[1];
  const int*   eidx    = (const int*)d_in[2];
  const float* sage_Wl = (const float*)d_in[3];
  const float* sage_bl = (const float*)d_in[4];
  const float* sage_Wr = (const float*)d_in[5];
  const float* sage_g  = (const float*)d_in[6];
  const float* sage_b  = (const float*)d_in[7];
  const float* W0 = (const float*)d_in[8];
  const float* b0 = (const float*)d_in[9];
  const float* W1 = (const float*)d_in[10];
  const float* b1 = (const float*)d_in[11];
  const float* W2 = (const float*)d_in[12];
  const float* b2 = (const float*)d_in[13];
  const float* mg = (const float*)d_in[14];
  const float* mb = (const float*)d_in[15];
  const float* Wc = (const float*)d_in[16];
  const float* bc = (const float*)d_in[17];
  const float* temp = (const float*)d_in[18];
  float* out = (float*)d_out;

  const int n = in_sizes[0] / HID;  // 100000
  const int e = in_sizes[2] / 2;    // 1600000
  const int* src = eidx;
  const int* tgt = eidx + e;

  const int nbk = (n + 511) >> 9;
  const int chunkB = (e + PBB - 1) / PBB;
  const int cap = (int)((((long long)e * 512 / n) * 3 / 2 + 63) & ~63LL);

  // workspace layout: 4 N×128 bf16 regions (16B aligned)
  char* p = (char*)d_ws;
  ushort* B0 = (ushort*)p; p += (size_t)n * HID * 2;
  ushort* B1 = (ushort*)p; p += (size_t)n * HID * 2;
  ushort* B2 = (ushort*)p; p += (size_t)n * HID * 2;
  ushort* B3 = (ushort*)p; p += (size_t)n * HID * 2;
  ushort* wb     = (ushort*)p; p += (size_t)WTOT * 2;
  ushort* wcb    = (ushort*)p; p += (size_t)48 * 256 * 2;
  float* stats = (float*)p; p += 8192 * 4;  // 4 sets x 8 replicas x 256 floats
  float* tbl0  = (float*)p; p += 256 * 4;
  float* tbl1  = (float*)p; p += 256 * 4;
  int* gcnt   = (int*)p; p += NBK_MAX * 4;
  int* rowptr = (int*)p; p += (size_t)n * 4;
  int* rowend = (int*)p; p += (size_t)n * 4;
  int* csr    = (int*)p; p += (size_t)nbk * cap * 4;
  ushort* xb   = B0;
  ushort* anb  = B1;                       // N*64
  ushort* ab   = B1 + (size_t)n * 64;      // N*64
  int*    ebuf = (int*)B2;                 // nbk*cap*4 <= n*256; dead after binC
  ushort* hproto = B3;
  ushort* Wlb = wb, *Wrb = wb + 49152, *W0b = wb + 98304, *W1b = wb + 106496, *W2b = wb + 122880;
  float* stSage0 = stats;
  float* stSage1 = stats + 2048;
  float* stPr0   = stats + 4096;
  float* stPr1   = stats + 6144;

  const int T = 256;

  const int gLin = (n + 127) / 128;        // 782
  const int gBn = 1024;
  const int gBnH = 512;                    // 512-thr bnb blocks
  const int gAgg = (n + 3) >> 2;           // 25000 (1 wave/node, 4/block)
  const int GW = WTOT / 4 / T;             // 136 blocks (exact)
  const int GC = (n * (HID / 4) + T - 1) / T;          // cvt blocks
  const int GA = (int)(((size_t)n * 16 + T - 1) / T);  // anorm2 blocks

  // 1: prep (weights cvt + x cvt + alpha norm + stats/gcnt zero)
  prep_kernel<<<GW + GC + GA, T, 0, stream>>>(
      x, xb, n * (HID / 4), alpha, ab, anb, n,
      sage_Wl, sage_Wr, W0, W1, W2, Wc, wb, wcb, stats, gcnt, GW, GC);

  // 2: binAB || proto W0 GEMM
  k_binAB_w0<<<PBB + gLin, T, 0, stream>>>(src, tgt, gcnt, ebuf, e, chunkB, nbk, cap,
                                           ab, W0b, b0, hproto, stPr0, n);

  // 3: binC || proto BN0 (sigmoid, stats-summing, in-place)
  k_binC_bnb<<<nbk + gBnH, 512, 0, stream>>>(ebuf, gcnt, rowptr, rowend, csr,
                                             n, cap, nbk,
                                             hproto, stPr0, mg, mb, gBnH);

  // 4: L0 aggregate + gate (pure; reads raw xb)
  agg_gate_kernel<<<gAgg, T, 0, stream>>>(xb, anb, rowptr, rowend, csr, temp,
                                          out + (size_t)n * OUTC, B2, n);

  // 5: SAGE L0 GEMM (y1 -> B1, pre-BN, stSage0) || proto W1 GEMM (stPr1)
  k_mlin_L0W1<<<2 * gLin, T, 0, stream>>>(B2, B0, Wlb, Wrb, sage_bl, B1, stSage0,
                                          hproto, W1b, b1, hproto, stPr1, n, gLin);

  // 6: bake sc/sh table for SAGE BN0
  scsh_kernel<<<1, 128, 0, stream>>>(stSage0, sage_g, sage_b, n, tbl0);

  // 7: agg1 w/ BN-fold (B1 pre-BN -> B2) || table-BN relu (B1 -> B0 = h1)
  //    || proto BN1 sigmoid (hproto in-place, stPr1)
  k_aggf<true><<<gAgg + gBn + gBn, T, 0, stream>>>(
      B1, rowptr, rowend, csr, tbl0, B2, B0, n, gAgg, gBn,
      hproto, stPr1, mg + HID, mb + HID, gBn);

  // 8: SAGE L1 GEMM (B2, B0=h1 -> B1 = y2, stSage1) || proto W2 relu
  k_mlin_mlin<<<2 * gLin, T, 0, stream>>>(B2, B0, Wlb + 16384, Wrb + 16384,
                                          sage_bl + HID, B1, stSage1,
                                          hproto, W2b, b2, hproto, n, gLin);

  // 9: bake sc/sh table for SAGE BN1
  scsh_kernel<<<1, 128, 0, stream>>>(stSage1, sage_g + HID, sage_b + HID, n, tbl1);

  // 10: agg2 w/ BN-fold (B1 -> B2) || table-BN relu (B1 -> B0 = h2)
  k_aggf<false><<<gAgg + gBn, T, 0, stream>>>(
      B1, rowptr, rowend, csr, tbl1, B2, B0, n, gAgg, gBn,
      nullptr, nullptr, nullptr, nullptr, 0);

  // 11: fused SAGE GEMM2 + classifier (B2, B0=h2, hproto -> out)
  k_gemm2_cls<<<gLin, T, 0, stream>>>(B2, B0, Wlb + 32768, Wrb + 32768,
                                      sage_bl + 2 * HID, hproto, wcb, bc, out, n);
}